// Round 3
// baseline (5072.090 us; speedup 1.0000x reference)
//
#include <hip/hip_runtime.h>
#include <math.h>
#include <stdint.h>

// ---- problem constants ----
#define B_      64
#define S_      128
#define H_      768
#define L_      6
#define NH_     12
#define DH_     64
#define FF_     3072
#define INTENT_ 22
#define TAGS_   122
#define NT_     (B_*S_)          // 8192 tokens
#define LN_EPS  1e-12f
#define INV_SQRT_DH 0.125f

#define GF_RELU_OUT 2
#define GF_GELU_OUT 4
#define GF_ADDRES   16   // add residual from Rh/Rl halves
#define GF_ACCH     32   // accumulate from current OH/OL contents

typedef _Float16 half8 __attribute__((ext_vector_type(8)));
typedef float    f32x4 __attribute__((ext_vector_type(4)));

// ===================== async global->LDS 16B =====================
__device__ __forceinline__ void gld16(const _Float16* g, _Float16* l) {
    __builtin_amdgcn_global_load_lds(
        (const __attribute__((address_space(1))) unsigned int*)(uintptr_t)g,
        (__attribute__((address_space(3))) unsigned int*)(unsigned int)(uintptr_t)l,
        16, 0, 0);
}

__device__ inline float wave_max(float v){
    #pragma unroll
    for (int d = 32; d; d >>= 1) v = fmaxf(v, __shfl_xor(v, d));
    return v;
}
__device__ inline float wave_sum(float v){
    #pragma unroll
    for (int d = 32; d; d >>= 1) v += __shfl_xor(v, d);
    return v;
}

// ===================== embedding + LN -> split halves =====================
__global__ __launch_bounds__(256) void embed_ln_kernel(
    const int* __restrict__ ids, const float* __restrict__ we,
    const float* __restrict__ pe, const float* __restrict__ gs,
    const float* __restrict__ gb, _Float16* __restrict__ Xh,
    _Float16* __restrict__ Xl)
{
    __shared__ float red[256];
    int bs = blockIdx.x;
    int sq = bs % S_;
    int id = ids[bs];
    int tid = threadIdx.x;
    const float* wrow = we + (size_t)id * H_;
    const float* prow = pe + (size_t)sq * H_;
    float z[3];
    #pragma unroll
    for (int r = 0; r < 3; r++) {
        int h = tid + 256*r;
        z[r] = wrow[h] + prow[h];
    }
    float sum = z[0]+z[1]+z[2];
    red[tid] = sum; __syncthreads();
    for (int off = 128; off > 0; off >>= 1) {
        if (tid < off) red[tid] += red[tid+off];
        __syncthreads();
    }
    float m = red[0] * (1.0f/H_); __syncthreads();
    float vs = 0.f;
    #pragma unroll
    for (int r = 0; r < 3; r++) { float d = z[r]-m; vs += d*d; }
    red[tid] = vs; __syncthreads();
    for (int off = 128; off > 0; off >>= 1) {
        if (tid < off) red[tid] += red[tid+off];
        __syncthreads();
    }
    float rstd = 1.0f / sqrtf(red[0]*(1.0f/H_) + LN_EPS);
    #pragma unroll
    for (int r = 0; r < 3; r++) {
        int h = tid + 256*r;
        float val = (z[r]-m)*rstd*gs[h] + gb[h];
        _Float16 hv = (_Float16)val;
        Xh[(size_t)bs*H_ + h] = hv;
        Xl[(size_t)bs*H_ + h] = (_Float16)(val - (float)hv);
    }
}

// ===================== LN over sum-halves -> split halves (+relu copy) ====
__global__ __launch_bounds__(384) void ln2_kernel(
    const _Float16* __restrict__ Sh, const _Float16* __restrict__ Sl,
    const float* __restrict__ gs, const float* __restrict__ gb,
    _Float16* __restrict__ Xh, _Float16* __restrict__ Xl,
    _Float16* __restrict__ Rh, _Float16* __restrict__ Rl)
{
    __shared__ float red[512];
    int bs = blockIdx.x, tid = threadIdx.x;
    size_t base = (size_t)bs*H_ + tid*2;
    union UU { _Float16 h[2]; unsigned u; };
    UU uh, ul;
    uh.u = *(const unsigned*)(Sh + base);
    ul.u = *(const unsigned*)(Sl + base);
    float z0 = (float)uh.h[0] + (float)ul.h[0];
    float z1 = (float)uh.h[1] + (float)ul.h[1];
    red[tid] = z0 + z1;
    if (tid < 128) red[384+tid] = 0.f;
    __syncthreads();
    for (int off = 256; off > 0; off >>= 1) {
        if (tid < off) red[tid] += red[tid+off];
        __syncthreads();
    }
    float m = red[0] * (1.0f/H_);
    __syncthreads();
    float d0 = z0-m, d1 = z1-m;
    red[tid] = d0*d0 + d1*d1;
    if (tid < 128) red[384+tid] = 0.f;
    __syncthreads();
    for (int off = 256; off > 0; off >>= 1) {
        if (tid < off) red[tid] += red[tid+off];
        __syncthreads();
    }
    float rstd = 1.0f / sqrtf(red[0]*(1.0f/H_) + LN_EPS);
    float2 gv = *(const float2*)(gs + tid*2);
    float2 bv = *(const float2*)(gb + tid*2);
    float v0 = d0*rstd*gv.x + bv.x;
    float v1 = d1*rstd*gv.y + bv.y;
    UU oh, ol;
    oh.h[0] = (_Float16)v0; ol.h[0] = (_Float16)(v0 - (float)oh.h[0]);
    oh.h[1] = (_Float16)v1; ol.h[1] = (_Float16)(v1 - (float)oh.h[1]);
    *(unsigned*)(Xh + base) = oh.u;
    *(unsigned*)(Xl + base) = ol.u;
    if (Rh) {
        float r0 = fmaxf(v0, 0.f), r1 = fmaxf(v1, 0.f);
        UU rh, rl;
        rh.h[0] = (_Float16)r0; rl.h[0] = (_Float16)(r0 - (float)rh.h[0]);
        rh.h[1] = (_Float16)r1; rl.h[1] = (_Float16)(r1 - (float)rh.h[1]);
        *(unsigned*)(Rh + base) = rh.u;
        *(unsigned*)(Rl + base) = rl.u;
    }
}

// ===================== weight transpose + fp16 hi/lo split =====================
// W [K][N] fp32 row-major -> Wt hi/lo [N][K] halves. grid (K/64, N/64, nz)
__global__ __launch_bounds__(256) void wconv_kernel(
    const float* __restrict__ W0, const float* __restrict__ W1,
    const float* __restrict__ W2, const float* __restrict__ W3,
    int K, int N, _Float16* __restrict__ OH, _Float16* __restrict__ OL, long zoff)
{
    __shared__ float t[64][65];
    int z = blockIdx.z;
    const float* W = (z==0) ? W0 : ((z==1) ? W1 : ((z==2) ? W2 : W3));
    OH += (long)z*zoff; OL += (long)z*zoff;
    int k0 = blockIdx.x*64, n0 = blockIdx.y*64;
    int tid = threadIdx.x;
    int lr = tid>>4, lc = (tid&15)*4;
    #pragma unroll
    for (int p = 0; p < 4; p++) {
        float4 v = *(const float4*)&W[(size_t)(k0+lr+16*p)*N + n0 + lc];
        t[lr+16*p][lc]   = v.x; t[lr+16*p][lc+1] = v.y;
        t[lr+16*p][lc+2] = v.z; t[lr+16*p][lc+3] = v.w;
    }
    __syncthreads();
    int n = tid>>2, kb = (tid&3)*16;
    union U { _Float16 h[8]; uint4 u; } h0, h1, l0, l1;
    #pragma unroll
    for (int e = 0; e < 8; e++) {
        float x = t[kb+e][n];
        _Float16 hv = (_Float16)x;
        h0.h[e] = hv; l0.h[e] = (_Float16)(x - (float)hv);
    }
    #pragma unroll
    for (int e = 0; e < 8; e++) {
        float x = t[kb+8+e][n];
        _Float16 hv = (_Float16)x;
        h1.h[e] = hv; l1.h[e] = (_Float16)(x - (float)hv);
    }
    size_t ob = (size_t)(n0+n)*K + k0 + kb;
    *(uint4*)&OH[ob]   = h0.u;
    *(uint4*)&OH[ob+8] = h1.u;
    *(uint4*)&OL[ob]   = l0.u;
    *(uint4*)&OL[ob+8] = l1.u;
}

// ===================== MFMA fp16-split GEMM v3 (global_load_lds staging) ====
// All inputs pre-split halves. M fixed by grid.x*128, N by grid.y*128, K param.
// Staging keeps the COALESCED global pattern (4 consecutive lanes cover one
// contiguous 64B row segment) but XOR-permutes the 16B k-chunk WITHIN each
// row: slot = kchunk ^ ((row>>1)&3). global_load_lds writes LDS linearly
// (rule #21), so the LDS layout inherits the permutation; the fragment
// ds_read_b128 applies the same XOR and lands 2 lanes/bank (free).
__global__ __launch_bounds__(256) void gemm3_kernel(
    const _Float16* __restrict__ AhG, const _Float16* __restrict__ AlG, int lda,
    const _Float16* __restrict__ WtHb, const _Float16* __restrict__ WtLb,
    int ldw, long wz,
    float* __restrict__ C, _Float16* __restrict__ OHb, _Float16* __restrict__ OLb,
    int ldc, long oz,
    const _Float16* __restrict__ Rh, const _Float16* __restrict__ Rl, int ldr,
    const float* __restrict__ bias0, const float* __restrict__ bias1,
    const float* __restrict__ bias2,
    int K, int flags)
{
    __shared__ __align__(16) _Float16 Ah[128*32], Al[128*32];
    __shared__ __align__(16) _Float16 Bh[128*32], Bl[128*32];
    const int z = blockIdx.z;
    const _Float16* WtH = WtHb + (long)z*wz;
    const _Float16* WtL = WtLb + (long)z*wz;
    _Float16* oh = OHb ? OHb + (long)z*oz : (_Float16*)0;
    _Float16* ol = OLb ? OLb + (long)z*oz : (_Float16*)0;
    const float* bias = (z==0) ? bias0 : ((z==1) ? bias1 : bias2);
    const int tid = threadIdx.x, lane = tid&63, wid = tid>>6;
    const int wm = wid&1, wn = wid>>1;
    const int l15 = lane&15, quad = lane>>4;
    const int m0 = blockIdx.x*128, n0 = blockIdx.y*128;

    // staging assignment: wave 0->Ah, 1->Al, 2->Bh, 3->Bl
    const _Float16* gsrc; _Float16* lbuf; int ld_s; int r0;
    if (wid == 0)      { gsrc = AhG; lbuf = Ah; ld_s = lda; r0 = m0; }
    else if (wid == 1) { gsrc = AlG; lbuf = Al; ld_s = lda; r0 = m0; }
    else if (wid == 2) { gsrc = WtH; lbuf = Bh; ld_s = ldw; r0 = n0; }
    else               { gsrc = WtL; lbuf = Bl; ld_s = ldw; r0 = n0; }
    // coalesced rows (lane>>2) with per-row k-chunk XOR swizzle.
    const int kch = (lane&3) ^ ((lane>>3)&3);
    const _Float16* gbase = gsrc + (size_t)(r0 + (lane>>2))*ld_s + kch*8;

    // fragment-read slot: stored slot = quad ^ ((l15>>1)&3)
    const int slot = quad ^ ((l15>>1)&3);

    f32x4 acc[4][4];
    #pragma unroll
    for (int i = 0; i < 4; i++)
        #pragma unroll
        for (int j = 0; j < 4; j++)
            acc[i][j] = (f32x4){0.f,0.f,0.f,0.f};

    for (int k0 = 0; k0 < K; k0 += 32) {
        #pragma unroll
        for (int q = 0; q < 8; q++)
            gld16(gbase + (size_t)(q*16)*ld_s + k0, lbuf + q*512);
        __syncthreads();
        half8 afh[4], afl[4], bfh[4], bfl[4];
        #pragma unroll
        for (int i = 0; i < 4; i++) {
            int m = wm*64 + i*16 + l15;
            afh[i] = *(const half8*)&Ah[m*32 + slot*8];
            afl[i] = *(const half8*)&Al[m*32 + slot*8];
            int n = wn*64 + i*16 + l15;
            bfh[i] = *(const half8*)&Bh[n*32 + slot*8];
            bfl[i] = *(const half8*)&Bl[n*32 + slot*8];
        }
        #pragma unroll
        for (int i = 0; i < 4; i++)
            #pragma unroll
            for (int j = 0; j < 4; j++) {
                acc[i][j] = __builtin_amdgcn_mfma_f32_16x16x32_f16(afh[i], bfh[j], acc[i][j], 0,0,0);
                acc[i][j] = __builtin_amdgcn_mfma_f32_16x16x32_f16(afh[i], bfl[j], acc[i][j], 0,0,0);
                acc[i][j] = __builtin_amdgcn_mfma_f32_16x16x32_f16(afl[i], bfh[j], acc[i][j], 0,0,0);
            }
        __syncthreads();
    }
    // ---- epilogue: C/D layout col=lane&15, row=quad*4+reg ----
    #pragma unroll
    for (int i = 0; i < 4; i++)
        #pragma unroll
        for (int j = 0; j < 4; j++)
            #pragma unroll
            for (int r = 0; r < 4; r++) {
                int gm = m0 + wm*64 + i*16 + quad*4 + r;
                int gn = n0 + wn*64 + j*16 + l15;
                float v = acc[i][j][r];
                if (bias) v += bias[gn];
                size_t ox = (size_t)gm*ldc + gn;
                if (flags & GF_ADDRES) {
                    size_t rx = (size_t)gm*ldr + gn;
                    v += (float)Rh[rx] + (float)Rl[rx];
                }
                if (flags & GF_ACCH)
                    v += (float)oh[ox] + (float)ol[ox];
                if (flags & GF_RELU_OUT) v = fmaxf(v, 0.f);
                if (flags & GF_GELU_OUT) v = 0.5f*v*(1.0f + erff(v*0.70710678118654752f));
                if (oh) {
                    _Float16 hv = (_Float16)v;
                    oh[ox] = hv;
                    ol[ox] = (_Float16)(v - (float)hv);
                } else {
                    C[ox] = v;
                }
            }
}

// ===================== fp32 GEMM (small head GEMM, N=122) =====================
#define BM 64
#define BN 64
#define BK 16
__global__ __launch_bounds__(256) void gemm_kernel(
    const float* __restrict__ A, int lda,
    const float* __restrict__ W, int ldb,
    float* __restrict__ C, int ldc,
    const float* __restrict__ bias,
    int M, int N, int K)
{
    __shared__ __align__(16) float As[BK][BM+4];
    __shared__ __align__(16) float Bs[BK][BN+4];
    int tid = threadIdx.x;
    int tx = tid & 15, ty = tid >> 4;
    int m0 = blockIdx.x * BM;
    int n0 = blockIdx.y * BN;
    float acc[4][4] = {};
    for (int k0 = 0; k0 < K; k0 += BK) {
        #pragma unroll
        for (int r = 0; r < 4; r++) {
            int li = tid + 256*r;
            int m  = li >> 4;
            int kk = li & 15;
            int gm = m0 + m, gk = k0 + kk;
            As[kk][m] = (gm < M && gk < K) ? A[(size_t)gm*lda + gk] : 0.f;
        }
        #pragma unroll
        for (int r = 0; r < 4; r++) {
            int li = tid + 256*r;
            int kk = li >> 6;
            int n  = li & 63;
            int gk = k0 + kk, gn = n0 + n;
            Bs[kk][n] = (gk < K && gn < N) ? W[(size_t)gk*ldb + gn] : 0.f;
        }
        __syncthreads();
        #pragma unroll
        for (int kk = 0; kk < BK; kk++) {
            float4 a  = *(const float4*)&As[kk][ty*4];
            float4 bb = *(const float4*)&Bs[kk][tx*4];
            float av[4] = {a.x, a.y, a.z, a.w};
            float bv[4] = {bb.x, bb.y, bb.z, bb.w};
            #pragma unroll
            for (int i = 0; i < 4; i++)
                #pragma unroll
                for (int j = 0; j < 4; j++)
                    acc[i][j] += av[i] * bv[j];
        }
        __syncthreads();
    }
    #pragma unroll
    for (int i = 0; i < 4; i++) {
        int gm = m0 + ty*4 + i;
        if (gm >= M) continue;
        #pragma unroll
        for (int j = 0; j < 4; j++) {
            int gn = n0 + tx*4 + j;
            if (gn >= N) continue;
            float v = acc[i][j];
            if (bias) v += bias[gn];
            C[(size_t)gm*ldc + gn] = v;
        }
    }
}

// ===================== MFMA attention =====================
__device__ inline int scidx(int row, int col) {
    return row*128 + (((col>>2) ^ (row&7))<<2) + (col&3);
}
__global__ __launch_bounds__(256) void attn2_kernel(
    const _Float16* __restrict__ QhG, const _Float16* __restrict__ QlG,
    const _Float16* __restrict__ KhG, const _Float16* __restrict__ KlG,
    const _Float16* __restrict__ VhG, const _Float16* __restrict__ VlG,
    const int* __restrict__ amask,
    _Float16* __restrict__ Ch, _Float16* __restrict__ Cl)
{
    __shared__ __align__(16) char smem[65536];
    _Float16* Qh_s = (_Float16*)smem;            // [64][72]
    _Float16* Ql_s = Qh_s + 64*72;
    _Float16* Kh_s = Ql_s + 64*72;               // [128][72]
    _Float16* Kl_s = Kh_s + 128*72;
    float*    Sc   = (float*)smem;               // [64][128] swizzled (phase 2)
    _Float16* Vth  = (_Float16*)(smem + 32768);  // [64][128] swizzled
    _Float16* Vtl  = Vth + 64*128;

    int blk = blockIdx.x;
    int qh2 = blk & 1;
    int bh  = blk >> 1;
    int b = bh / NH_, hh = bh % NH_;
    const int tid = threadIdx.x, lane = tid&63, wid = tid>>6;
    const int l15 = lane&15, quad = lane>>4;
    const int qr = wid*16;
    size_t tokb = (size_t)b*S_*H_ + (size_t)hh*DH_;

    float nmask[8];
    #pragma unroll
    for (int j = 0; j < 8; j++)
        nmask[j] = (amask[b*S_ + j*16 + l15] > 0) ? 0.f : -1e9f;

    {
        int row = tid>>2, part = (tid&3)*16;
        size_t qg = tokb + (size_t)(qh2*64 + row)*H_ + part;
        *(uint4*)&Qh_s[row*72 + part] = *(const uint4*)(QhG + qg);
        *(uint4*)&Ql_s[row*72 + part] = *(const uint4*)(QlG + qg);
        #pragma unroll
        for (int p = 0; p < 2; p++) {
            int krow = row + p*64;
            size_t kg = tokb + (size_t)krow*H_ + part;
            *(uint4*)&Kh_s[krow*72 + part] = *(const uint4*)(KhG + kg);
            *(uint4*)&Kl_s[krow*72 + part] = *(const uint4*)(KlG + kg);
        }
    }
    __syncthreads();

    f32x4 acc1[8];
    #pragma unroll
    for (int j = 0; j < 8; j++) acc1[j] = (f32x4){0.f,0.f,0.f,0.f};
    half8 aqh[2], aql[2];
    #pragma unroll
    for (int kc = 0; kc < 2; kc++) {
        aqh[kc] = *(const half8*)&Qh_s[(qr + l15)*72 + kc*32 + quad*8];
        aql[kc] = *(const half8*)&Ql_s[(qr + l15)*72 + kc*32 + quad*8];
    }
    #pragma unroll
    for (int j = 0; j < 8; j++) {
        #pragma unroll
        for (int kc = 0; kc < 2; kc++) {
            half8 bkh = *(const half8*)&Kh_s[(j*16 + l15)*72 + kc*32 + quad*8];
            half8 bkl = *(const half8*)&Kl_s[(j*16 + l15)*72 + kc*32 + quad*8];
            acc1[j] = __builtin_amdgcn_mfma_f32_16x16x32_f16(aqh[kc], bkh, acc1[j], 0,0,0);
            acc1[j] = __builtin_amdgcn_mfma_f32_16x16x32_f16(aqh[kc], bkl, acc1[j], 0,0,0);
            acc1[j] = __builtin_amdgcn_mfma_f32_16x16x32_f16(aql[kc], bkh, acc1[j], 0,0,0);
        }
    }
    __syncthreads();

    #pragma unroll
    for (int j = 0; j < 8; j++)
        #pragma unroll
        for (int r = 0; r < 4; r++) {
            int row = qr + quad*4 + r;
            int col = j*16 + l15;
            Sc[scidx(row, col)] = acc1[j][r]*INV_SQRT_DH + nmask[j];
        }
    {
        int key = tid>>1, dh = (tid&1)*32;
        union V32 { _Float16 h[32]; uint4 u[4]; } bufh, bufl;
        #pragma unroll
        for (int e = 0; e < 4; e++) {
            bufh.u[e] = *(const uint4*)(VhG + tokb + (size_t)key*H_ + dh + e*8);
            bufl.u[e] = *(const uint4*)(VlG + tokb + (size_t)key*H_ + dh + e*8);
        }
        int kg = key>>3, kr = key&7;
        #pragma unroll
        for (int e = 0; e < 32; e++) {
            int d = dh + e;
            int pos = kg ^ (d & 7);
            Vth[d*128 + pos*8 + kr] = bufh.h[e];
            Vtl[d*128 + pos*8 + kr] = bufl.h[e];
        }
    }
    __syncthreads();

    {
        int row = tid>>2, part = (tid&3)*32;
        float mx = -INFINITY;
        #pragma unroll 8
        for (int e = 0; e < 32; e++)
            mx = fmaxf(mx, Sc[scidx(row, part+e)]);
        mx = fmaxf(mx, __shfl_xor(mx, 1));
        mx = fmaxf(mx, __shfl_xor(mx, 2));
        float s = 0.f;
        #pragma unroll 8
        for (int e = 0; e < 32; e++) {
            int idx = scidx(row, part+e);
            float ev = expf(Sc[idx] - mx);
            Sc[idx] = ev; s += ev;
        }
        s += __shfl_xor(s, 1);
        s += __shfl_xor(s, 2);
        float inv = 1.0f / s;
        #pragma unroll 8
        for (int e = 0; e < 32; e++)
            Sc[scidx(row, part+e)] *= inv;
    }
    __syncthreads();

    f32x4 acc2[4];
    #pragma unroll
    for (int jd = 0; jd < 4; jd++) acc2[jd] = (f32x4){0.f,0.f,0.f,0.f};
    #pragma unroll
    for (int kc = 0; kc < 4; kc++) {
        int q = qr + l15;
        int g16 = kc*8 + quad*2;
        float4 p0 = *(const float4*)&Sc[q*128 + ((g16   ^ (q&7))<<2)];
        float4 p1 = *(const float4*)&Sc[q*128 + (((g16+1) ^ (q&7))<<2)];
        float pv[8] = {p0.x,p0.y,p0.z,p0.w, p1.x,p1.y,p1.z,p1.w};
        union U { _Float16 h[8]; half8 v; } ph, pl;
        #pragma unroll
        for (int e = 0; e < 8; e++) {
            _Float16 hv = (_Float16)pv[e];
            ph.h[e] = hv; pl.h[e] = (_Float16)(pv[e] - (float)hv);
        }
        #pragma unroll
        for (int jd = 0; jd < 4; jd++) {
            int n = jd*16 + l15;
            int pos = (kc*4 + quad) ^ (n & 7);
            half8 vh = *(const half8*)&Vth[n*128 + pos*8];
            half8 vl = *(const half8*)&Vtl[n*128 + pos*8];
            acc2[jd] = __builtin_amdgcn_mfma_f32_16x16x32_f16(ph.v, vh, acc2[jd], 0,0,0);
            acc2[jd] = __builtin_amdgcn_mfma_f32_16x16x32_f16(ph.v, vl, acc2[jd], 0,0,0);
            acc2[jd] = __builtin_amdgcn_mfma_f32_16x16x32_f16(pl.v, vh, acc2[jd], 0,0,0);
        }
    }
    #pragma unroll
    for (int jd = 0; jd < 4; jd++)
        #pragma unroll
        for (int r = 0; r < 4; r++) {
            int row = qr + quad*4 + r;
            int token = b*S_ + qh2*64 + row;
            int d = jd*16 + l15;
            float v = acc2[jd][r];
            _Float16 hv = (_Float16)v;
            Ch[(size_t)token*H_ + hh*DH_ + d] = hv;
            Cl[(size_t)token*H_ + hh*DH_ + d] = (_Float16)(v - (float)hv);
        }
}

// ===================== intent head =====================
__global__ __launch_bounds__(64) void intent_kernel(
    const _Float16* __restrict__ Xh, const _Float16* __restrict__ Xl,
    const float* __restrict__ iW1,
    const float* __restrict__ ib1, const float* __restrict__ iW2,
    const float* __restrict__ ib2, const int* __restrict__ tgt,
    float* __restrict__ iloss, float* __restrict__ outf)
{
    int b = blockIdx.x; int j = threadIdx.x;
    __shared__ float h1[64];
    __shared__ float lg[32];
    const _Float16* x0h = Xh + (size_t)b*S_*H_;
    const _Float16* x0l = Xl + (size_t)b*S_*H_;
    float acc = ib1[j];
    for (int h = 0; h < H_; h++) {
        float x = (float)x0h[h] + (float)x0l[h];
        acc += fmaxf(x, 0.f) * iW1[(size_t)h*64 + j];
    }
    h1[j] = fmaxf(acc, 0.f);
    __syncthreads();
    if (j < INTENT_) {
        float l = ib2[j];
        for (int k = 0; k < 64; k++) l += h1[k]*iW2[k*INTENT_ + j];
        lg[j] = l;
    }
    __syncthreads();
    if (j == 0) {
        float mx = -INFINITY; int bi = 0;
        for (int c = 0; c < INTENT_; c++) if (lg[c] > mx) { mx = lg[c]; bi = c; }
        float sm = 0.f;
        for (int c = 0; c < INTENT_; c++) sm += expf(lg[c]-mx);
        float lse = mx + logf(sm);
        iloss[b] = lse - lg[tgt[b]];
        outf[1 + (size_t)NT_ + b] = (float)bi;
    }
}

// ===================== fused CRF-llh + Viterbi (single-wave blocks) ========
// grid (64, 2): y=0 -> CRF llh for batch x ; y=1 -> Viterbi for batch x.
// ONE wave (64 threads) per block; lane owns tags j0=2*lane, j1=2*lane+1.
// alpha lives in registers; per-step all-to-all via one ds_write_b64 +
// broadcast b64 reads (within-wave ordering: no barriers in the scan loop).
// Transition matrix in LDS, interleaved [i/2][j(pad128)][i&1]: lane's
// fragment read is float4 at (i2*256 + 4*lane) -> 64 lanes x 16B contiguous
// = conflict-free ds_read_b128.
__global__ __launch_bounds__(64) void crf_vit_kernel(
    const float* __restrict__ E_, const int* __restrict__ tags,
    const int* __restrict__ mask, const float* __restrict__ start,
    const float* __restrict__ endv, const float* __restrict__ trans,
    float* __restrict__ crfv, unsigned char* __restrict__ BPg,
    float* __restrict__ outf)
{
    __shared__ __align__(16) float Ti[61*256];   // 62464 B: [i2][j:128][p:2]
    __shared__ __align__(16) float eab[128];     // alpha/ealpha pairs (float2[64])
    int b = blockIdx.x, mode = blockIdx.y;
    int lane = threadIdx.x;
    const float* E = E_ + (size_t)b*S_*TAGS_;
    int j0 = 2*lane, j1 = 2*lane+1;
    bool vj0 = (j0 < TAGS_), vj1 = (j1 < TAGS_);

    // load transition matrix (exp-domain for llh, raw for viterbi)
    for (int o = lane; o < 61*256; o += 64) {
        int i2 = o >> 8, r = o & 255, j = r >> 1, p = r & 1;
        int i = 2*i2 + p;              // i <= 121 always
        float tv = (j < TAGS_) ? trans[i*TAGS_ + j] : 0.f;
        Ti[o] = mode ? tv : expf(tv);
    }
    __syncthreads();

    float a0 = vj0 ? (start[j0] + E[j0]) : -3e38f;
    float a1 = vj1 ? (start[j1] + E[j1]) : -3e38f;

    if (mode == 0) {
        // ---------- CRF log-likelihood ----------
        for (int t = 1; t < S_; t++) {
            float e0 = vj0 ? E[(size_t)t*TAGS_ + j0] : 0.f;
            float e1 = vj1 ? E[(size_t)t*TAGS_ + j1] : 0.f;
            int m_t = mask[b*S_ + t];
            float mx = wave_max(fmaxf(a0, a1));
            float2 ea;
            ea.x = vj0 ? expf(a0 - mx) : 0.f;
            ea.y = vj1 ? expf(a1 - mx) : 0.f;
            *(float2*)&eab[2*lane] = ea;
            float s0 = 0.f, s1 = 0.f;
            #pragma unroll
            for (int i2 = 0; i2 < 61; i2++) {
                float2 av = *(const float2*)&eab[2*i2];           // broadcast
                float4 tv = *(const float4*)&Ti[i2*256 + 4*lane]; // conflict-free
                s0 += av.x*tv.x + av.y*tv.y;
                s1 += av.x*tv.z + av.y*tv.w;
            }
            if (m_t) {
                if (vj0) a0 = mx + logf(s0) + e0;
                if (vj1) a1 = mx + logf(s1) + e1;
            }
        }
        // numerator: lane handles t = lane and lane+64
        float term = 0.f, mkf = 0.f;
        #pragma unroll
        for (int rr = 0; rr < 2; rr++) {
            int t = lane + 64*rr;
            int mk = mask[b*S_ + t];
            mkf += (float)mk;
            if (t >= 1 && mk) {
                int tg = tags[b*S_ + t], tgp = tags[b*S_ + t - 1];
                term += trans[tgp*TAGS_ + tg] + E[(size_t)t*TAGS_ + tg];
            }
        }
        float ts = wave_sum(term);
        float ms = wave_sum(mkf);
        float w0 = vj0 ? a0 + endv[j0] : -3e38f;
        float w1 = vj1 ? a1 + endv[j1] : -3e38f;
        float m2 = wave_max(fmaxf(w0, w1));
        float sd = (vj0 ? expf(w0 - m2) : 0.f) + (vj1 ? expf(w1 - m2) : 0.f);
        sd = wave_sum(sd);
        if (lane == 0) {
            float denom = m2 + logf(sd);
            int msum = (int)ms;
            int tag0 = tags[b*S_];
            int last_tag = tags[b*S_ + (msum - 1)];
            crfv[b] = start[tag0] + E[tag0] + ts + endv[last_tag] - denom;
        }
    } else {
        // ---------- Viterbi ----------
        size_t bpb = (size_t)b*(S_-1)*TAGS_;
        for (int t = 1; t < S_; t++) {
            float e0 = vj0 ? E[(size_t)t*TAGS_ + j0] : 0.f;
            float e1 = vj1 ? E[(size_t)t*TAGS_ + j1] : 0.f;
            int m_t = mask[b*S_ + t];
            float2 ap; ap.x = a0; ap.y = a1;
            *(float2*)&eab[2*lane] = ap;
            float b0 = -3e38f, b1 = -3e38f; int i0 = 0, i1 = 0;
            #pragma unroll
            for (int i2 = 0; i2 < 61; i2++) {
                float2 av = *(const float2*)&eab[2*i2];           // broadcast
                float4 tv = *(const float4*)&Ti[i2*256 + 4*lane]; // conflict-free
                float c0 = av.x + tv.x;
                if (c0 > b0) { b0 = c0; i0 = 2*i2; }
                float c1 = av.y + tv.y;
                if (c1 > b0) { b0 = c1; i0 = 2*i2+1; }
                float c2 = av.x + tv.z;
                if (c2 > b1) { b1 = c2; i1 = 2*i2; }
                float c3 = av.y + tv.w;
                if (c3 > b1) { b1 = c3; i1 = 2*i2+1; }
            }
            float n0, n1; int nb0, nb1;
            if (m_t) { n0 = b0 + e0; nb0 = i0; n1 = b1 + e1; nb1 = i1; }
            else     { n0 = a0; nb0 = j0; n1 = a1; nb1 = j1; }
            if (vj0) a0 = n0;
            if (vj1) a1 = n1;
            if (vj0) {
                size_t bx = bpb + (size_t)(t-1)*TAGS_ + j0;
                if (vj1) {
                    unsigned short pk = (unsigned short)(((nb1 & 0xff) << 8) | (nb0 & 0xff));
                    *(unsigned short*)&BPg[bx] = pk;
                } else {
                    BPg[bx] = (unsigned char)nb0;
                }
            }
        }
        // last tag = argmax(alpha + endv), first index on ties
        float w0 = vj0 ? a0 + endv[j0] : -3e38f;
        float w1 = vj1 ? a1 + endv[j1] : -3e38f;
        float v = w0; int idx = j0;
        if (w1 > v) { v = w1; idx = j1; }
        #pragma unroll
        for (int d = 32; d; d >>= 1) {
            float ov = __shfl_xor(v, d); int oi = __shfl_xor(idx, d);
            if (ov > v || (ov == v && oi < idx)) { v = ov; idx = oi; }
        }
        // backtrace: copy BP into LDS (reuse Ti), serial walk on lane 0
        unsigned char* bpl = (unsigned char*)Ti;
        for (int o = lane; o < (S_-1)*TAGS_; o += 64)
            bpl[o] = BPg[bpb + o];
        __syncthreads();
        if (lane == 0) {
            int tag = idx;
            outf[1 + (size_t)b*S_ + (S_-1)] = (float)tag;
            for (int t = S_-1; t >= 1; t--) {
                tag = bpl[(t-1)*TAGS_ + tag];
                outf[1 + (size_t)b*S_ + (t-1)] = (float)tag;
            }
        }
    }
}

// ===================== final joint loss =====================
__global__ void combine_kernel(const float* __restrict__ iloss,
                               const float* __restrict__ crfv,
                               const float* __restrict__ lv,
                               float* __restrict__ outf)
{
    if (threadIdx.x == 0 && blockIdx.x == 0) {
        float si = 0.f, sc = 0.f;
        for (int b = 0; b < B_; b++) { si += iloss[b]; sc += crfv[b]; }
        float p1 = expf(-lv[0]), p2 = expf(-lv[1]);
        float slots_loss = -sc;
        outf[0] = p1*si + (float)B_*lv[0] + p2*slots_loss + lv[1];
    }
}

// ===================== host launch =====================
extern "C" void kernel_launch(void* const* d_in, const int* in_sizes, int n_in,
                              void* d_out, int out_size, void* d_ws, size_t ws_size,
                              hipStream_t stream) {
    const int*   ids   = (const int*)  d_in[0];
    const int*   amask = (const int*)  d_in[1];
    const int*   itgt  = (const int*)  d_in[2];
    const int*   stgt  = (const int*)  d_in[3];
    const int*   smask = (const int*)  d_in[4];
    const float* we    = (const float*)d_in[5];
    const float* pe    = (const float*)d_in[6];
    const float* embs  = (const float*)d_in[7];
    const float* embb  = (const float*)d_in[8];
    const float* Wq    = (const float*)d_in[9];
    const float* bq    = (const float*)d_in[10];
    const float* Wk    = (const float*)d_in[11];
    const float* bk    = (const float*)d_in[12];
    const float* Wv    = (const float*)d_in[13];
    const float* bv    = (const float*)d_in[14];
    const float* Wo    = (const float*)d_in[15];
    const float* bo    = (const float*)d_in[16];
    const float* sas   = (const float*)d_in[17];
    const float* sab   = (const float*)d_in[18];
    const float* W1f   = (const float*)d_in[19];
    const float* b1f   = (const float*)d_in[20];
    const float* W2f   = (const float*)d_in[21];
    const float* b2f   = (const float*)d_in[22];
    const float* ols   = (const float*)d_in[23];
    const float* olb   = (const float*)d_in[24];
    const float* iW1   = (const float*)d_in[25];
    const float* ib1   = (const float*)d_in[26];
    const float* iW2   = (const float*)d_in[27];
    const float* ib2   = (const float*)d_in[28];
    const float* sW1   = (const float*)d_in[29];
    const float* sb1   = (const float*)d_in[30];
    const float* sW2   = (const float*)d_in[31];
    const float* sb2   = (const float*)d_in[32];
    const float* crfs  = (const float*)d_in[33];
    const float* crfe  = (const float*)d_in[34];
    const float* crft  = (const float*)d_in[35];
    const float* lv    = (const float*)d_in[36];

    float* outf = (float*)d_out;
    float* wsf  = (float*)d_ws;
    const long NTHh = (long)NT_ * H_;        // 6,291,456 (halves per tensor)
    const long NBf  = NTHh;                  // floats per fp32-equivalent tensor
    const long HH   = (long)H_ * H_;         // 589,824

    // layout (floats): [XhXl: NBf][P: 3*NBf][ChCl: NBf][WA][WB1][WB2][misc]
    _Float16* Xh = (_Float16*)wsf;
    _Float16* Xl = Xh + NTHh;
    float*    Pf = wsf + NBf;
    _Float16* Ph = (_Float16*)Pf;
    _Float16 *Qh = Ph, *Ql = Ph + NTHh, *Kh = Ph + 2*NTHh, *Kl = Ph + 3*NTHh,
             *Vh = Ph + 4*NTHh, *Vl = Ph + 5*NTHh;
    _Float16 *Sh = Ph, *Sl = Ph + NTHh;                 // sum halves (reuse Q slot)
    _Float16* Fh = (_Float16*)(wsf + 2*NBf);            // FF intermediate hi
    _Float16* Fl = (_Float16*)(wsf + 3*NBf);            // FF intermediate lo
    _Float16* Ch = (_Float16*)(wsf + 4*NBf);
    _Float16* Cl = Ch + NTHh;
    const long wa0 = 5*NBf;
    _Float16* WAh = (_Float16*)(wsf + wa0);             // 8*HH halves (QKVO hi+lo)
    _Float16* WAl = WAh + 4*HH;
    const long wb1 = wa0 + 2359296;
    _Float16* WB1h = (_Float16*)(wsf + wb1);
    _Float16* WB1l = WB1h + 2359296;
    const long wb2 = wb1 + 2359296;
    _Float16* WB2h = (_Float16*)(wsf + wb2);
    _Float16* WB2l = WB2h + 2359296;
    float* iloss = wsf + wb2 + 2359296;
    float* crfv  = iloss + 64;
    // heads scratch in P region (free after encoder)
    float* H1 = Pf;                                     // 8192*256
    float* logits = Pf + 2097152;                       // 8192*122
    unsigned char* BPg = (unsigned char*)(Pf + 2097152 + 999424);

    auto g3 = [&](int gy, int gz,
                  const _Float16* A_h, const _Float16* A_l, int lda,
                  const _Float16* WtH, const _Float16* WtL, int ldw, long wz,
                  float* C, _Float16* OH, _Float16* OL, int ldc, long oz,
                  const _Float16* Rh, const _Float16* Rl,
                  const float* b0, const float* b1_, const float* b2_,
                  int K, int flags) {
        hipLaunchKernelGGL(gemm3_kernel, dim3(NT_/128, gy, gz), dim3(256), 0, stream,
                           A_h, A_l, lda, WtH, WtL, ldw, wz,
                           C, OH, OL, ldc, oz, Rh, Rl, H_, b0, b1_, b2_, K, flags);
    };

    hipLaunchKernelGGL(embed_ln_kernel, dim3(NT_), dim3(256), 0, stream,
                       ids, we, pe, embs, embb, Xh, Xl);

    for (int i = 0; i < L_; i++) {
        const long WO = (long)i*HH;
        // QKV+O weights -> WA (z=4)
        hipLaunchKernelGGL(wconv_kernel, dim3(12,12,4), dim3(256), 0, stream,
                           Wq+WO, Wk+WO, Wv+WO, Wo+WO, H_, H_, WAh, WAl, HH);
        // QKV (z=3)
        g3(6, 3, Xh, Xl, H_, WAh, WAl, H_, HH,
           nullptr, Ph, Ph+NTHh, H_, 2*NTHh, nullptr, nullptr,
           bq+i*H_, bk+i*H_, bv+i*H_, H_, 0);
        // attention
        hipLaunchKernelGGL(attn2_kernel, dim3(B_*NH_*2), dim3(256), 0, stream,
                           Qh, Ql, Kh, Kl, Vh, Vl, amask, Ch, Cl);
        // O-proj + residual -> sum halves (Sh/Sl)
        g3(6, 1, Ch, Cl, H_, WAh+3*HH, WAl+3*HH, H_, 0,
           nullptr, Sh, Sl, H_, 0, Xh, Xl,
           bo+i*H_, nullptr, nullptr, H_, GF_ADDRES);
        hipLaunchKernelGGL(ln2_kernel, dim3(NT_), dim3(384), 0, stream,
                           Sh, Sl, sas+i*H_, sab+i*H_, Xh, Xl,
                           (_Float16*)nullptr, (_Float16*)nullptr);
        // FF weights
        hipLaunchKernelGGL(wconv_kernel, dim3(12,48,1), dim3(256), 0, stream,
                           W1f+(long)i*H_*FF_, nullptr, nullptr, nullptr,
                           H_, FF_, WB1h, WB1l, 0);
        hipLaunchKernelGGL(wconv_kernel, dim3(48,12,1), dim3(256), 0, stream,
                           W2f+(long)i*FF_*H_, nullptr, nullptr, nullptr,
                           FF_, H_, WB2h, WB2l, 0);
        for (int c = 0; c < 2; c++) {
            const int CW = FF_/2;  // 1536
            g3(12, 1, Xh, Xl, H_,
               WB1h+(long)c*CW*H_, WB1l+(long)c*CW*H_, H_, 0,
               nullptr, Fh, Fl, CW, 0, nullptr, nullptr,
               b1f+(long)i*FF_+c*CW, nullptr, nullptr, H_, GF_GELU_OUT);
            g3(6, 1, Fh, Fl, CW,
               WB2h+(long)c*CW, WB2l+(long)c*CW, FF_, 0,
               nullptr, Sh, Sl, H_, 0, Xh, Xl,
               (c==0) ? (b2f+i*H_) : nullptr, nullptr, nullptr,
               CW, (c==0) ? GF_ADDRES : GF_ACCH);
        }
        hipLaunchKernelGGL(ln2_kernel, dim3(NT_), dim3(384), 0, stream,
                           Sh, Sl, ols+i*H_, olb+i*H_, Xh, Xl,
                           (i==L_-1) ? Ch : (_Float16*)nullptr,
                           (i==L_-1) ? Cl : (_Float16*)nullptr);
    }

    hipLaunchKernelGGL(intent_kernel, dim3(B_), dim3(64), 0, stream,
                       Xh, Xl, iW1, ib1, iW2, ib2, itgt, iloss, outf);

    // slots head: H1 = relu(relu(x)@sW1 + sb1)  (relu(x) halves are in Ch/Cl)
    hipLaunchKernelGGL(wconv_kernel, dim3(12,4,1), dim3(256), 0, stream,
                       sW1, nullptr, nullptr, nullptr, H_, 256,
                       WAh, WAh + (long)256*H_, 0);
    g3(2, 1, Ch, Cl, H_, WAh, WAh + (long)256*H_, H_, 0,
       H1, nullptr, nullptr, 256, 0, nullptr, nullptr,
       sb1, nullptr, nullptr, H_, GF_RELU_OUT);
    hipLaunchKernelGGL(gemm_kernel, dim3(NT_/BM, 2), dim3(256), 0, stream,
                       H1, 256, sW2, TAGS_, logits, TAGS_, sb2, NT_, TAGS_, 256);

    hipLaunchKernelGGL(crf_vit_kernel, dim3(B_, 2), dim3(64), 0, stream,
                       logits, stgt, smask, crfs, crfe, crft, crfv, BPg, outf);

    hipLaunchKernelGGL(combine_kernel, dim3(1), dim3(64), 0, stream,
                       iloss, crfv, lv, outf);
}

// Round 4
// 4882.092 us; speedup vs baseline: 1.0389x; 1.0389x over previous
//
#include <hip/hip_runtime.h>
#include <math.h>
#include <stdint.h>

// ---- problem constants ----
#define B_      64
#define S_      128
#define H_      768
#define L_      6
#define NH_     12
#define DH_     64
#define FF_     3072
#define INTENT_ 22
#define TAGS_   122
#define NT_     (B_*S_)          // 8192 tokens
#define LN_EPS  1e-12f
#define INV_SQRT_DH 0.125f

#define GF_RELU_OUT 2
#define GF_GELU_OUT 4
#define GF_ADDRES   16   // add residual from Rh/Rl halves
#define GF_ACCH     32   // accumulate from current OH/OL contents

typedef _Float16 half8 __attribute__((ext_vector_type(8)));
typedef float    f32x4 __attribute__((ext_vector_type(4)));

// ===================== async global->LDS 16B =====================
__device__ __forceinline__ void gld16(const _Float16* g, _Float16* l) {
    __builtin_amdgcn_global_load_lds(
        (const __attribute__((address_space(1))) unsigned int*)(uintptr_t)g,
        (__attribute__((address_space(3))) unsigned int*)(unsigned int)(uintptr_t)l,
        16, 0, 0);
}

__device__ inline float wave_max(float v){
    #pragma unroll
    for (int d = 32; d; d >>= 1) v = fmaxf(v, __shfl_xor(v, d));
    return v;
}
__device__ inline float wave_sum(float v){
    #pragma unroll
    for (int d = 32; d; d >>= 1) v += __shfl_xor(v, d);
    return v;
}

// ===================== embedding + LN -> split halves =====================
__global__ __launch_bounds__(256) void embed_ln_kernel(
    const int* __restrict__ ids, const float* __restrict__ we,
    const float* __restrict__ pe, const float* __restrict__ gs,
    const float* __restrict__ gb, _Float16* __restrict__ Xh,
    _Float16* __restrict__ Xl)
{
    __shared__ float red[256];
    int bs = blockIdx.x;
    int sq = bs % S_;
    int id = ids[bs];
    int tid = threadIdx.x;
    const float* wrow = we + (size_t)id * H_;
    const float* prow = pe + (size_t)sq * H_;
    float z[3];
    #pragma unroll
    for (int r = 0; r < 3; r++) {
        int h = tid + 256*r;
        z[r] = wrow[h] + prow[h];
    }
    float sum = z[0]+z[1]+z[2];
    red[tid] = sum; __syncthreads();
    for (int off = 128; off > 0; off >>= 1) {
        if (tid < off) red[tid] += red[tid+off];
        __syncthreads();
    }
    float m = red[0] * (1.0f/H_); __syncthreads();
    float vs = 0.f;
    #pragma unroll
    for (int r = 0; r < 3; r++) { float d = z[r]-m; vs += d*d; }
    red[tid] = vs; __syncthreads();
    for (int off = 128; off > 0; off >>= 1) {
        if (tid < off) red[tid] += red[tid+off];
        __syncthreads();
    }
    float rstd = 1.0f / sqrtf(red[0]*(1.0f/H_) + LN_EPS);
    #pragma unroll
    for (int r = 0; r < 3; r++) {
        int h = tid + 256*r;
        float val = (z[r]-m)*rstd*gs[h] + gb[h];
        _Float16 hv = (_Float16)val;
        Xh[(size_t)bs*H_ + h] = hv;
        Xl[(size_t)bs*H_ + h] = (_Float16)(val - (float)hv);
    }
}

// ===================== LN over sum-halves -> split halves (+relu copy) ====
__global__ __launch_bounds__(384) void ln2_kernel(
    const _Float16* __restrict__ Sh, const _Float16* __restrict__ Sl,
    const float* __restrict__ gs, const float* __restrict__ gb,
    _Float16* __restrict__ Xh, _Float16* __restrict__ Xl,
    _Float16* __restrict__ Rh, _Float16* __restrict__ Rl)
{
    __shared__ float red[512];
    int bs = blockIdx.x, tid = threadIdx.x;
    size_t base = (size_t)bs*H_ + tid*2;
    union UU { _Float16 h[2]; unsigned u; };
    UU uh, ul;
    uh.u = *(const unsigned*)(Sh + base);
    ul.u = *(const unsigned*)(Sl + base);
    float z0 = (float)uh.h[0] + (float)ul.h[0];
    float z1 = (float)uh.h[1] + (float)ul.h[1];
    red[tid] = z0 + z1;
    if (tid < 128) red[384+tid] = 0.f;
    __syncthreads();
    for (int off = 256; off > 0; off >>= 1) {
        if (tid < off) red[tid] += red[tid+off];
        __syncthreads();
    }
    float m = red[0] * (1.0f/H_);
    __syncthreads();
    float d0 = z0-m, d1 = z1-m;
    red[tid] = d0*d0 + d1*d1;
    if (tid < 128) red[384+tid] = 0.f;
    __syncthreads();
    for (int off = 256; off > 0; off >>= 1) {
        if (tid < off) red[tid] += red[tid+off];
        __syncthreads();
    }
    float rstd = 1.0f / sqrtf(red[0]*(1.0f/H_) + LN_EPS);
    float2 gv = *(const float2*)(gs + tid*2);
    float2 bv = *(const float2*)(gb + tid*2);
    float v0 = d0*rstd*gv.x + bv.x;
    float v1 = d1*rstd*gv.y + bv.y;
    UU oh, ol;
    oh.h[0] = (_Float16)v0; ol.h[0] = (_Float16)(v0 - (float)oh.h[0]);
    oh.h[1] = (_Float16)v1; ol.h[1] = (_Float16)(v1 - (float)oh.h[1]);
    *(unsigned*)(Xh + base) = oh.u;
    *(unsigned*)(Xl + base) = ol.u;
    if (Rh) {
        float r0 = fmaxf(v0, 0.f), r1 = fmaxf(v1, 0.f);
        UU rh, rl;
        rh.h[0] = (_Float16)r0; rl.h[0] = (_Float16)(r0 - (float)rh.h[0]);
        rh.h[1] = (_Float16)r1; rl.h[1] = (_Float16)(r1 - (float)rh.h[1]);
        *(unsigned*)(Rh + base) = rh.u;
        *(unsigned*)(Rl + base) = rl.u;
    }
}

// ===================== weight transpose + fp16 hi/lo split =====================
// W [K][N] fp32 row-major -> Wt hi/lo [N][K] halves. grid (K/64, N/64, nz)
__global__ __launch_bounds__(256) void wconv_kernel(
    const float* __restrict__ W0, const float* __restrict__ W1,
    const float* __restrict__ W2, const float* __restrict__ W3,
    int K, int N, _Float16* __restrict__ OH, _Float16* __restrict__ OL, long zoff)
{
    __shared__ float t[64][65];
    int z = blockIdx.z;
    const float* W = (z==0) ? W0 : ((z==1) ? W1 : ((z==2) ? W2 : W3));
    OH += (long)z*zoff; OL += (long)z*zoff;
    int k0 = blockIdx.x*64, n0 = blockIdx.y*64;
    int tid = threadIdx.x;
    int lr = tid>>4, lc = (tid&15)*4;
    #pragma unroll
    for (int p = 0; p < 4; p++) {
        float4 v = *(const float4*)&W[(size_t)(k0+lr+16*p)*N + n0 + lc];
        t[lr+16*p][lc]   = v.x; t[lr+16*p][lc+1] = v.y;
        t[lr+16*p][lc+2] = v.z; t[lr+16*p][lc+3] = v.w;
    }
    __syncthreads();
    int n = tid>>2, kb = (tid&3)*16;
    union U { _Float16 h[8]; uint4 u; } h0, h1, l0, l1;
    #pragma unroll
    for (int e = 0; e < 8; e++) {
        float x = t[kb+e][n];
        _Float16 hv = (_Float16)x;
        h0.h[e] = hv; l0.h[e] = (_Float16)(x - (float)hv);
    }
    #pragma unroll
    for (int e = 0; e < 8; e++) {
        float x = t[kb+8+e][n];
        _Float16 hv = (_Float16)x;
        h1.h[e] = hv; l1.h[e] = (_Float16)(x - (float)hv);
    }
    size_t ob = (size_t)(n0+n)*K + k0 + kb;
    *(uint4*)&OH[ob]   = h0.u;
    *(uint4*)&OH[ob+8] = h1.u;
    *(uint4*)&OL[ob]   = l0.u;
    *(uint4*)&OL[ob+8] = l1.u;
}

// ===================== MFMA fp16-split GEMM v3 (global_load_lds staging) ====
// All inputs pre-split halves. M fixed by grid.x*128, N by grid.y*128, K param.
// Staging keeps the COALESCED global pattern (4 consecutive lanes cover one
// contiguous 64B row segment) but XOR-permutes the 16B k-chunk WITHIN each
// row: slot = kchunk ^ ((row>>1)&3). global_load_lds writes LDS linearly
// (rule #21), so the LDS layout inherits the permutation; the fragment
// ds_read_b128 applies the same XOR and lands 2 lanes/bank (free).
__global__ __launch_bounds__(256) void gemm3_kernel(
    const _Float16* __restrict__ AhG, const _Float16* __restrict__ AlG, int lda,
    const _Float16* __restrict__ WtHb, const _Float16* __restrict__ WtLb,
    int ldw, long wz,
    float* __restrict__ C, _Float16* __restrict__ OHb, _Float16* __restrict__ OLb,
    int ldc, long oz,
    const _Float16* __restrict__ Rh, const _Float16* __restrict__ Rl, int ldr,
    const float* __restrict__ bias0, const float* __restrict__ bias1,
    const float* __restrict__ bias2,
    int K, int flags)
{
    __shared__ __align__(16) _Float16 Ah[128*32], Al[128*32];
    __shared__ __align__(16) _Float16 Bh[128*32], Bl[128*32];
    const int z = blockIdx.z;
    const _Float16* WtH = WtHb + (long)z*wz;
    const _Float16* WtL = WtLb + (long)z*wz;
    _Float16* oh = OHb ? OHb + (long)z*oz : (_Float16*)0;
    _Float16* ol = OLb ? OLb + (long)z*oz : (_Float16*)0;
    const float* bias = (z==0) ? bias0 : ((z==1) ? bias1 : bias2);
    const int tid = threadIdx.x, lane = tid&63, wid = tid>>6;
    const int wm = wid&1, wn = wid>>1;
    const int l15 = lane&15, quad = lane>>4;
    const int m0 = blockIdx.x*128, n0 = blockIdx.y*128;

    // staging assignment: wave 0->Ah, 1->Al, 2->Bh, 3->Bl
    const _Float16* gsrc; _Float16* lbuf; int ld_s; int r0;
    if (wid == 0)      { gsrc = AhG; lbuf = Ah; ld_s = lda; r0 = m0; }
    else if (wid == 1) { gsrc = AlG; lbuf = Al; ld_s = lda; r0 = m0; }
    else if (wid == 2) { gsrc = WtH; lbuf = Bh; ld_s = ldw; r0 = n0; }
    else               { gsrc = WtL; lbuf = Bl; ld_s = ldw; r0 = n0; }
    // coalesced rows (lane>>2) with per-row k-chunk XOR swizzle.
    const int kch = (lane&3) ^ ((lane>>3)&3);
    const _Float16* gbase = gsrc + (size_t)(r0 + (lane>>2))*ld_s + kch*8;

    // fragment-read slot: stored slot = quad ^ ((l15>>1)&3)
    const int slot = quad ^ ((l15>>1)&3);

    f32x4 acc[4][4];
    #pragma unroll
    for (int i = 0; i < 4; i++)
        #pragma unroll
        for (int j = 0; j < 4; j++)
            acc[i][j] = (f32x4){0.f,0.f,0.f,0.f};

    for (int k0 = 0; k0 < K; k0 += 32) {
        #pragma unroll
        for (int q = 0; q < 8; q++)
            gld16(gbase + (size_t)(q*16)*ld_s + k0, lbuf + q*512);
        __syncthreads();
        half8 afh[4], afl[4], bfh[4], bfl[4];
        #pragma unroll
        for (int i = 0; i < 4; i++) {
            int m = wm*64 + i*16 + l15;
            afh[i] = *(const half8*)&Ah[m*32 + slot*8];
            afl[i] = *(const half8*)&Al[m*32 + slot*8];
            int n = wn*64 + i*16 + l15;
            bfh[i] = *(const half8*)&Bh[n*32 + slot*8];
            bfl[i] = *(const half8*)&Bl[n*32 + slot*8];
        }
        #pragma unroll
        for (int i = 0; i < 4; i++)
            #pragma unroll
            for (int j = 0; j < 4; j++) {
                acc[i][j] = __builtin_amdgcn_mfma_f32_16x16x32_f16(afh[i], bfh[j], acc[i][j], 0,0,0);
                acc[i][j] = __builtin_amdgcn_mfma_f32_16x16x32_f16(afh[i], bfl[j], acc[i][j], 0,0,0);
                acc[i][j] = __builtin_amdgcn_mfma_f32_16x16x32_f16(afl[i], bfh[j], acc[i][j], 0,0,0);
            }
        __syncthreads();
    }
    // ---- epilogue: C/D layout col=lane&15, row=quad*4+reg ----
    #pragma unroll
    for (int i = 0; i < 4; i++)
        #pragma unroll
        for (int j = 0; j < 4; j++)
            #pragma unroll
            for (int r = 0; r < 4; r++) {
                int gm = m0 + wm*64 + i*16 + quad*4 + r;
                int gn = n0 + wn*64 + j*16 + l15;
                float v = acc[i][j][r];
                if (bias) v += bias[gn];
                size_t ox = (size_t)gm*ldc + gn;
                if (flags & GF_ADDRES) {
                    size_t rx = (size_t)gm*ldr + gn;
                    v += (float)Rh[rx] + (float)Rl[rx];
                }
                if (flags & GF_ACCH)
                    v += (float)oh[ox] + (float)ol[ox];
                if (flags & GF_RELU_OUT) v = fmaxf(v, 0.f);
                if (flags & GF_GELU_OUT) v = 0.5f*v*(1.0f + erff(v*0.70710678118654752f));
                if (oh) {
                    _Float16 hv = (_Float16)v;
                    oh[ox] = hv;
                    ol[ox] = (_Float16)(v - (float)hv);
                } else {
                    C[ox] = v;
                }
            }
}

// ===================== fp32 GEMM (small head GEMM, N=122) =====================
#define BM 64
#define BN 64
#define BK 16
__global__ __launch_bounds__(256) void gemm_kernel(
    const float* __restrict__ A, int lda,
    const float* __restrict__ W, int ldb,
    float* __restrict__ C, int ldc,
    const float* __restrict__ bias,
    int M, int N, int K)
{
    __shared__ __align__(16) float As[BK][BM+4];
    __shared__ __align__(16) float Bs[BK][BN+4];
    int tid = threadIdx.x;
    int tx = tid & 15, ty = tid >> 4;
    int m0 = blockIdx.x * BM;
    int n0 = blockIdx.y * BN;
    float acc[4][4] = {};
    for (int k0 = 0; k0 < K; k0 += BK) {
        #pragma unroll
        for (int r = 0; r < 4; r++) {
            int li = tid + 256*r;
            int m  = li >> 4;
            int kk = li & 15;
            int gm = m0 + m, gk = k0 + kk;
            As[kk][m] = (gm < M && gk < K) ? A[(size_t)gm*lda + gk] : 0.f;
        }
        #pragma unroll
        for (int r = 0; r < 4; r++) {
            int li = tid + 256*r;
            int kk = li >> 6;
            int n  = li & 63;
            int gk = k0 + kk, gn = n0 + n;
            Bs[kk][n] = (gk < K && gn < N) ? W[(size_t)gk*ldb + gn] : 0.f;
        }
        __syncthreads();
        #pragma unroll
        for (int kk = 0; kk < BK; kk++) {
            float4 a  = *(const float4*)&As[kk][ty*4];
            float4 bb = *(const float4*)&Bs[kk][tx*4];
            float av[4] = {a.x, a.y, a.z, a.w};
            float bv[4] = {bb.x, bb.y, bb.z, bb.w};
            #pragma unroll
            for (int i = 0; i < 4; i++)
                #pragma unroll
                for (int j = 0; j < 4; j++)
                    acc[i][j] += av[i] * bv[j];
        }
        __syncthreads();
    }
    #pragma unroll
    for (int i = 0; i < 4; i++) {
        int gm = m0 + ty*4 + i;
        if (gm >= M) continue;
        #pragma unroll
        for (int j = 0; j < 4; j++) {
            int gn = n0 + tx*4 + j;
            if (gn >= N) continue;
            float v = acc[i][j];
            if (bias) v += bias[gn];
            C[(size_t)gm*ldc + gn] = v;
        }
    }
}

// ===================== MFMA attention =====================
__device__ inline int scidx(int row, int col) {
    return row*128 + (((col>>2) ^ (row&7))<<2) + (col&3);
}
__global__ __launch_bounds__(256) void attn2_kernel(
    const _Float16* __restrict__ QhG, const _Float16* __restrict__ QlG,
    const _Float16* __restrict__ KhG, const _Float16* __restrict__ KlG,
    const _Float16* __restrict__ VhG, const _Float16* __restrict__ VlG,
    const int* __restrict__ amask,
    _Float16* __restrict__ Ch, _Float16* __restrict__ Cl)
{
    __shared__ __align__(16) char smem[65536];
    _Float16* Qh_s = (_Float16*)smem;            // [64][72]
    _Float16* Ql_s = Qh_s + 64*72;
    _Float16* Kh_s = Ql_s + 64*72;               // [128][72]
    _Float16* Kl_s = Kh_s + 128*72;
    float*    Sc   = (float*)smem;               // [64][128] swizzled (phase 2)
    _Float16* Vth  = (_Float16*)(smem + 32768);  // [64][128] swizzled
    _Float16* Vtl  = Vth + 64*128;

    int blk = blockIdx.x;
    int qh2 = blk & 1;
    int bh  = blk >> 1;
    int b = bh / NH_, hh = bh % NH_;
    const int tid = threadIdx.x, lane = tid&63, wid = tid>>6;
    const int l15 = lane&15, quad = lane>>4;
    const int qr = wid*16;
    size_t tokb = (size_t)b*S_*H_ + (size_t)hh*DH_;

    float nmask[8];
    #pragma unroll
    for (int j = 0; j < 8; j++)
        nmask[j] = (amask[b*S_ + j*16 + l15] > 0) ? 0.f : -1e9f;

    {
        int row = tid>>2, part = (tid&3)*16;
        size_t qg = tokb + (size_t)(qh2*64 + row)*H_ + part;
        *(uint4*)&Qh_s[row*72 + part] = *(const uint4*)(QhG + qg);
        *(uint4*)&Ql_s[row*72 + part] = *(const uint4*)(QlG + qg);
        #pragma unroll
        for (int p = 0; p < 2; p++) {
            int krow = row + p*64;
            size_t kg = tokb + (size_t)krow*H_ + part;
            *(uint4*)&Kh_s[krow*72 + part] = *(const uint4*)(KhG + kg);
            *(uint4*)&Kl_s[krow*72 + part] = *(const uint4*)(KlG + kg);
        }
    }
    __syncthreads();

    f32x4 acc1[8];
    #pragma unroll
    for (int j = 0; j < 8; j++) acc1[j] = (f32x4){0.f,0.f,0.f,0.f};
    half8 aqh[2], aql[2];
    #pragma unroll
    for (int kc = 0; kc < 2; kc++) {
        aqh[kc] = *(const half8*)&Qh_s[(qr + l15)*72 + kc*32 + quad*8];
        aql[kc] = *(const half8*)&Ql_s[(qr + l15)*72 + kc*32 + quad*8];
    }
    #pragma unroll
    for (int j = 0; j < 8; j++) {
        #pragma unroll
        for (int kc = 0; kc < 2; kc++) {
            half8 bkh = *(const half8*)&Kh_s[(j*16 + l15)*72 + kc*32 + quad*8];
            half8 bkl = *(const half8*)&Kl_s[(j*16 + l15)*72 + kc*32 + quad*8];
            acc1[j] = __builtin_amdgcn_mfma_f32_16x16x32_f16(aqh[kc], bkh, acc1[j], 0,0,0);
            acc1[j] = __builtin_amdgcn_mfma_f32_16x16x32_f16(aqh[kc], bkl, acc1[j], 0,0,0);
            acc1[j] = __builtin_amdgcn_mfma_f32_16x16x32_f16(aql[kc], bkh, acc1[j], 0,0,0);
        }
    }
    __syncthreads();

    #pragma unroll
    for (int j = 0; j < 8; j++)
        #pragma unroll
        for (int r = 0; r < 4; r++) {
            int row = qr + quad*4 + r;
            int col = j*16 + l15;
            Sc[scidx(row, col)] = acc1[j][r]*INV_SQRT_DH + nmask[j];
        }
    {
        int key = tid>>1, dh = (tid&1)*32;
        union V32 { _Float16 h[32]; uint4 u[4]; } bufh, bufl;
        #pragma unroll
        for (int e = 0; e < 4; e++) {
            bufh.u[e] = *(const uint4*)(VhG + tokb + (size_t)key*H_ + dh + e*8);
            bufl.u[e] = *(const uint4*)(VlG + tokb + (size_t)key*H_ + dh + e*8);
        }
        int kg = key>>3, kr = key&7;
        #pragma unroll
        for (int e = 0; e < 32; e++) {
            int d = dh + e;
            int pos = kg ^ (d & 7);
            Vth[d*128 + pos*8 + kr] = bufh.h[e];
            Vtl[d*128 + pos*8 + kr] = bufl.h[e];
        }
    }
    __syncthreads();

    {
        int row = tid>>2, part = (tid&3)*32;
        float mx = -INFINITY;
        #pragma unroll 8
        for (int e = 0; e < 32; e++)
            mx = fmaxf(mx, Sc[scidx(row, part+e)]);
        mx = fmaxf(mx, __shfl_xor(mx, 1));
        mx = fmaxf(mx, __shfl_xor(mx, 2));
        float s = 0.f;
        #pragma unroll 8
        for (int e = 0; e < 32; e++) {
            int idx = scidx(row, part+e);
            float ev = expf(Sc[idx] - mx);
            Sc[idx] = ev; s += ev;
        }
        s += __shfl_xor(s, 1);
        s += __shfl_xor(s, 2);
        float inv = 1.0f / s;
        #pragma unroll 8
        for (int e = 0; e < 32; e++)
            Sc[scidx(row, part+e)] *= inv;
    }
    __syncthreads();

    f32x4 acc2[4];
    #pragma unroll
    for (int jd = 0; jd < 4; jd++) acc2[jd] = (f32x4){0.f,0.f,0.f,0.f};
    #pragma unroll
    for (int kc = 0; kc < 4; kc++) {
        int q = qr + l15;
        int g16 = kc*8 + quad*2;
        float4 p0 = *(const float4*)&Sc[q*128 + ((g16   ^ (q&7))<<2)];
        float4 p1 = *(const float4*)&Sc[q*128 + (((g16+1) ^ (q&7))<<2)];
        float pv[8] = {p0.x,p0.y,p0.z,p0.w, p1.x,p1.y,p1.z,p1.w};
        union U { _Float16 h[8]; half8 v; } ph, pl;
        #pragma unroll
        for (int e = 0; e < 8; e++) {
            _Float16 hv = (_Float16)pv[e];
            ph.h[e] = hv; pl.h[e] = (_Float16)(pv[e] - (float)hv);
        }
        #pragma unroll
        for (int jd = 0; jd < 4; jd++) {
            int n = jd*16 + l15;
            int pos = (kc*4 + quad) ^ (n & 7);
            half8 vh = *(const half8*)&Vth[n*128 + pos*8];
            half8 vl = *(const half8*)&Vtl[n*128 + pos*8];
            acc2[jd] = __builtin_amdgcn_mfma_f32_16x16x32_f16(ph.v, vh, acc2[jd], 0,0,0);
            acc2[jd] = __builtin_amdgcn_mfma_f32_16x16x32_f16(ph.v, vl, acc2[jd], 0,0,0);
            acc2[jd] = __builtin_amdgcn_mfma_f32_16x16x32_f16(pl.v, vh, acc2[jd], 0,0,0);
        }
    }
    #pragma unroll
    for (int jd = 0; jd < 4; jd++)
        #pragma unroll
        for (int r = 0; r < 4; r++) {
            int row = qr + quad*4 + r;
            int token = b*S_ + qh2*64 + row;
            int d = jd*16 + l15;
            float v = acc2[jd][r];
            _Float16 hv = (_Float16)v;
            Ch[(size_t)token*H_ + hh*DH_ + d] = hv;
            Cl[(size_t)token*H_ + hh*DH_ + d] = (_Float16)(v - (float)hv);
        }
}

// ===================== intent head =====================
__global__ __launch_bounds__(64) void intent_kernel(
    const _Float16* __restrict__ Xh, const _Float16* __restrict__ Xl,
    const float* __restrict__ iW1,
    const float* __restrict__ ib1, const float* __restrict__ iW2,
    const float* __restrict__ ib2, const int* __restrict__ tgt,
    float* __restrict__ iloss, float* __restrict__ outf)
{
    int b = blockIdx.x; int j = threadIdx.x;
    __shared__ float h1[64];
    __shared__ float lg[32];
    const _Float16* x0h = Xh + (size_t)b*S_*H_;
    const _Float16* x0l = Xl + (size_t)b*S_*H_;
    float acc = ib1[j];
    for (int h = 0; h < H_; h++) {
        float x = (float)x0h[h] + (float)x0l[h];
        acc += fmaxf(x, 0.f) * iW1[(size_t)h*64 + j];
    }
    h1[j] = fmaxf(acc, 0.f);
    __syncthreads();
    if (j < INTENT_) {
        float l = ib2[j];
        for (int k = 0; k < 64; k++) l += h1[k]*iW2[k*INTENT_ + j];
        lg[j] = l;
    }
    __syncthreads();
    if (j == 0) {
        float mx = -INFINITY; int bi = 0;
        for (int c = 0; c < INTENT_; c++) if (lg[c] > mx) { mx = lg[c]; bi = c; }
        float sm = 0.f;
        for (int c = 0; c < INTENT_; c++) sm += expf(lg[c]-mx);
        float lse = mx + logf(sm);
        iloss[b] = lse - lg[tgt[b]];
        outf[1 + (size_t)NT_ + b] = (float)bi;
    }
}

// ===================== fused CRF-llh + Viterbi (2-wave blocks) =============
// grid (64, 2): y=0 -> CRF llh ; y=1 -> Viterbi. 128 threads, thread == tag.
// alpha lives in registers; per-step all-to-all via double-buffered LDS
// (exbuf[par]) + ONE barrier per step. Transition matrix Ti[j][i] row-major
// with stride VST=132 floats (528 B = 33 x 16B, odd multiple -> each lane's
// ds_read_b128 lands in 16B-slot (j mod 8): even distribution, conflict-free).
// llh uses defer-max (T13): ealpha computed against PREVIOUS step's global
// max (exchanged at the same barrier) -- mathematically identical, per-step
// alpha drift is small so exp() stays well inside fp32 range.
#define VST 132
__global__ __launch_bounds__(128) void crf_vit_kernel(
    const float* __restrict__ E_, const int* __restrict__ tags,
    const int* __restrict__ mask, const float* __restrict__ start,
    const float* __restrict__ endv, const float* __restrict__ trans,
    float* __restrict__ crfv, unsigned char* __restrict__ BPg,
    float* __restrict__ outf)
{
    __shared__ __align__(16) float Ti[TAGS_*VST];   // 64,416 B  [j][i]
    __shared__ __align__(16) float exbuf[2][128];   // 1,024 B  (dbuf exchange)
    __shared__ float mxw[2][2];                     // per-wave max, by parity
    __shared__ float red8[4];
    __shared__ int lastt;
    int b = blockIdx.x, mode = blockIdx.y;
    int tid = threadIdx.x, lane = tid&63, wid = tid>>6;
    int j = tid;
    bool vj = (j < TAGS_);
    const float* E = E_ + (size_t)b*S_*TAGS_;

    // load Ti[j][i] (exp-domain for llh, raw for viterbi); pad cols never read
    for (int o = tid; o < TAGS_*VST; o += 128) {
        int jj = o / VST, i = o - jj*VST;
        float tv = (i < TAGS_) ? trans[i*TAGS_ + jj] : 0.f;
        Ti[o] = mode ? tv : expf(tv);
    }
    float a = vj ? (start[j] + E[j]) : -3e38f;

    if (mode == 0) {
        // ---------- CRF log-likelihood ----------
        // prologue: exact global max of alpha_0
        {
            float wm = wave_max(a);
            if (lane == 0) mxw[1][wid] = wm;   // parity of t=1 is 1
        }
        __syncthreads();                        // also covers Ti load
        float mxP = fmaxf(mxw[1][0], mxw[1][1]);
        float eC = vj ? E[(size_t)TAGS_ + j] : 0.f;   // E[t=1][j]
        int   mC = mask[b*S_ + 1];
        for (int t = 1; t < S_; t++) {
            int par = t & 1;
            float e = eC; int m_t = mC;
            if (t + 1 < S_) {                   // prefetch next step
                eC = vj ? E[(size_t)(t+1)*TAGS_ + j] : 0.f;
                mC = mask[b*S_ + t + 1];
            }
            float ea = vj ? expf(a - mxP) : 0.f;
            exbuf[par][tid] = ea;
            float wm = wave_max(a);
            if (lane == 0) mxw[par][wid] = wm;
            __syncthreads();
            float mxC = fmaxf(mxw[par][0], mxw[par][1]);
            const float* tr = &Ti[j*VST];
            const float* eb = &exbuf[par][0];
            float s0 = 0.f, s1 = 0.f, s2 = 0.f, s3 = 0.f;
            #pragma unroll
            for (int q = 0; q < 30; q++) {
                float4 av = *(const float4*)&eb[q*4];   // broadcast
                float4 tv = *(const float4*)&tr[q*4];   // conflict-free
                s0 += av.x*tv.x; s1 += av.y*tv.y;
                s2 += av.z*tv.z; s3 += av.w*tv.w;
            }
            {
                float2 av = *(const float2*)&eb[120];
                float2 tv = *(const float2*)&tr[120];
                s0 += av.x*tv.x; s1 += av.y*tv.y;
            }
            float s = (s0 + s1) + (s2 + s3);
            if (m_t && vj) a = mxP + logf(s) + e;
            mxP = mxC;
        }
        // numerator: thread == timestep (S_ == 128)
        float term = 0.f, mkf = 0.f;
        {
            int mk = mask[b*S_ + tid]; mkf = (float)mk;
            if (tid >= 1 && mk) {
                int tg = tags[b*S_ + tid], tgp = tags[b*S_ + tid - 1];
                term = trans[tgp*TAGS_ + tg] + E[(size_t)tid*TAGS_ + tg];
            }
        }
        float ts = wave_sum(term);
        float ms = wave_sum(mkf);
        float w = vj ? a + endv[j] : -3e38f;
        float wmx = wave_max(w);
        if (lane == 0) { red8[wid] = wmx; mxw[0][wid] = ts; mxw[1][wid] = ms; }
        __syncthreads();
        float m2 = fmaxf(red8[0], red8[1]);
        float sd = vj ? expf(w - m2) : 0.f;
        sd = wave_sum(sd);
        if (lane == 0) red8[2 + wid] = sd;
        __syncthreads();
        if (tid == 0) {
            float denom = m2 + logf(red8[2] + red8[3]);
            float tsum = mxw[0][0] + mxw[0][1];
            int msum = (int)(mxw[1][0] + mxw[1][1]);
            int tag0 = tags[b*S_];
            int last_tag = tags[b*S_ + (msum - 1)];
            crfv[b] = start[tag0] + E[tag0] + tsum + endv[last_tag] - denom;
        }
    } else {
        // ---------- Viterbi ----------
        __syncthreads();                        // Ti load
        size_t bpb = (size_t)b*(S_-1)*TAGS_;
        float eC = vj ? E[(size_t)TAGS_ + j] : 0.f;
        int   mC = mask[b*S_ + 1];
        for (int t = 1; t < S_; t++) {
            int par = t & 1;
            float e = eC; int m_t = mC;
            if (t + 1 < S_) {
                eC = vj ? E[(size_t)(t+1)*TAGS_ + j] : 0.f;
                mC = mask[b*S_ + t + 1];
            }
            exbuf[par][tid] = a;
            __syncthreads();
            const float* tr = &Ti[j*VST];
            const float* ab = &exbuf[par][0];
            float b0 = -3e38f, b1 = -3e38f, b2 = -3e38f, b3 = -3e38f;
            int i0 = 0, i1 = 1, i2 = 2, i3 = 3;
            #pragma unroll
            for (int q = 0; q < 30; q++) {
                float4 av = *(const float4*)&ab[q*4];
                float4 tv = *(const float4*)&tr[q*4];
                float c;
                c = av.x + tv.x; if (c > b0) { b0 = c; i0 = q*4; }
                c = av.y + tv.y; if (c > b1) { b1 = c; i1 = q*4+1; }
                c = av.z + tv.z; if (c > b2) { b2 = c; i2 = q*4+2; }
                c = av.w + tv.w; if (c > b3) { b3 = c; i3 = q*4+3; }
            }
            {
                float2 av = *(const float2*)&ab[120];
                float2 tv = *(const float2*)&tr[120];
                float c;
                c = av.x + tv.x; if (c > b0) { b0 = c; i0 = 120; }
                c = av.y + tv.y; if (c > b1) { b1 = c; i1 = 121; }
            }
            // merge with first-index tie-break (i0<i1<i2<i3 patterns interleave,
            // resolve ties by smaller index)
            float bb = b0; int bi = i0;
            if (b1 > bb || (b1 == bb && i1 < bi)) { bb = b1; bi = i1; }
            if (b2 > bb || (b2 == bb && i2 < bi)) { bb = b2; bi = i2; }
            if (b3 > bb || (b3 == bb && i3 < bi)) { bb = b3; bi = i3; }
            float nv; int nb;
            if (m_t) { nv = bb + e; nb = bi; }
            else     { nv = a; nb = j; }
            if (vj) {
                a = nv;
                BPg[bpb + (size_t)(t-1)*TAGS_ + j] = (unsigned char)nb;
            }
        }
        // last tag = argmax(alpha + endv), first index on ties
        float w = vj ? a + endv[j] : -3e38f;
        float v = w; int idx = j;
        #pragma unroll
        for (int d = 32; d; d >>= 1) {
            float ov = __shfl_xor(v, d); int oi = __shfl_xor(idx, d);
            if (ov > v || (ov == v && oi < idx)) { v = ov; idx = oi; }
        }
        if (lane == 0) { red8[wid] = v; ((int*)&red8[2])[wid] = idx; }
        __syncthreads();
        if (tid == 0) {
            float v0 = red8[0], v1 = red8[1];
            int x0 = ((int*)&red8[2])[0], x1 = ((int*)&red8[2])[1];
            lastt = (v1 > v0 || (v1 == v0 && x1 < x0)) ? x1 : x0;
        }
        __syncthreads();
        // backtrace: copy BP into LDS (reuse Ti), serial walk on thread 0
        unsigned char* bpl = (unsigned char*)Ti;
        for (int o = tid; o < (S_-1)*TAGS_; o += 128)
            bpl[o] = BPg[bpb + o];
        __syncthreads();
        if (tid == 0) {
            int tag = lastt;
            outf[1 + (size_t)b*S_ + (S_-1)] = (float)tag;
            for (int t = S_-1; t >= 1; t--) {
                tag = bpl[(t-1)*TAGS_ + tag];
                outf[1 + (size_t)b*S_ + (t-1)] = (float)tag;
            }
        }
    }
}

// ===================== final joint loss =====================
__global__ void combine_kernel(const float* __restrict__ iloss,
                               const float* __restrict__ crfv,
                               const float* __restrict__ lv,
                               float* __restrict__ outf)
{
    if (threadIdx.x == 0 && blockIdx.x == 0) {
        float si = 0.f, sc = 0.f;
        for (int b = 0; b < B_; b++) { si += iloss[b]; sc += crfv[b]; }
        float p1 = expf(-lv[0]), p2 = expf(-lv[1]);
        float slots_loss = -sc;
        outf[0] = p1*si + (float)B_*lv[0] + p2*slots_loss + lv[1];
    }
}

// ===================== host launch =====================
extern "C" void kernel_launch(void* const* d_in, const int* in_sizes, int n_in,
                              void* d_out, int out_size, void* d_ws, size_t ws_size,
                              hipStream_t stream) {
    const int*   ids   = (const int*)  d_in[0];
    const int*   amask = (const int*)  d_in[1];
    const int*   itgt  = (const int*)  d_in[2];
    const int*   stgt  = (const int*)  d_in[3];
    const int*   smask = (const int*)  d_in[4];
    const float* we    = (const float*)d_in[5];
    const float* pe    = (const float*)d_in[6];
    const float* embs  = (const float*)d_in[7];
    const float* embb  = (const float*)d_in[8];
    const float* Wq    = (const float*)d_in[9];
    const float* bq    = (const float*)d_in[10];
    const float* Wk    = (const float*)d_in[11];
    const float* bk    = (const float*)d_in[12];
    const float* Wv    = (const float*)d_in[13];
    const float* bv    = (const float*)d_in[14];
    const float* Wo    = (const float*)d_in[15];
    const float* bo    = (const float*)d_in[16];
    const float* sas   = (const float*)d_in[17];
    const float* sab   = (const float*)d_in[18];
    const float* W1f   = (const float*)d_in[19];
    const float* b1f   = (const float*)d_in[20];
    const float* W2f   = (const float*)d_in[21];
    const float* b2f   = (const float*)d_in[22];
    const float* ols   = (const float*)d_in[23];
    const float* olb   = (const float*)d_in[24];
    const float* iW1   = (const float*)d_in[25];
    const float* ib1   = (const float*)d_in[26];
    const float* iW2   = (const float*)d_in[27];
    const float* ib2   = (const float*)d_in[28];
    const float* sW1   = (const float*)d_in[29];
    const float* sb1   = (const float*)d_in[30];
    const float* sW2   = (const float*)d_in[31];
    const float* sb2   = (const float*)d_in[32];
    const float* crfs  = (const float*)d_in[33];
    const float* crfe  = (const float*)d_in[34];
    const float* crft  = (const float*)d_in[35];
    const float* lv    = (const float*)d_in[36];

    float* outf = (float*)d_out;
    float* wsf  = (float*)d_ws;
    const long NTHh = (long)NT_ * H_;        // 6,291,456 (halves per tensor)
    const long NBf  = NTHh;                  // floats per fp32-equivalent tensor
    const long HH   = (long)H_ * H_;         // 589,824

    // layout (floats): [XhXl: NBf][P: 3*NBf][ChCl: NBf][WA][WB1][WB2][misc]
    _Float16* Xh = (_Float16*)wsf;
    _Float16* Xl = Xh + NTHh;
    float*    Pf = wsf + NBf;
    _Float16* Ph = (_Float16*)Pf;
    _Float16 *Qh = Ph, *Ql = Ph + NTHh, *Kh = Ph + 2*NTHh, *Kl = Ph + 3*NTHh,
             *Vh = Ph + 4*NTHh, *Vl = Ph + 5*NTHh;
    _Float16 *Sh = Ph, *Sl = Ph + NTHh;                 // sum halves (reuse Q slot)
    _Float16* Fh = (_Float16*)(wsf + 2*NBf);            // FF intermediate hi
    _Float16* Fl = (_Float16*)(wsf + 3*NBf);            // FF intermediate lo
    _Float16* Ch = (_Float16*)(wsf + 4*NBf);
    _Float16* Cl = Ch + NTHh;
    const long wa0 = 5*NBf;
    _Float16* WAh = (_Float16*)(wsf + wa0);             // 8*HH halves (QKVO hi+lo)
    _Float16* WAl = WAh + 4*HH;
    const long wb1 = wa0 + 2359296;
    _Float16* WB1h = (_Float16*)(wsf + wb1);
    _Float16* WB1l = WB1h + 2359296;
    const long wb2 = wb1 + 2359296;
    _Float16* WB2h = (_Float16*)(wsf + wb2);
    _Float16* WB2l = WB2h + 2359296;
    float* iloss = wsf + wb2 + 2359296;
    float* crfv  = iloss + 64;
    // heads scratch in P region (free after encoder)
    float* H1 = Pf;                                     // 8192*256
    float* logits = Pf + 2097152;                       // 8192*122
    unsigned char* BPg = (unsigned char*)(Pf + 2097152 + 999424);

    auto g3 = [&](int gy, int gz,
                  const _Float16* A_h, const _Float16* A_l, int lda,
                  const _Float16* WtH, const _Float16* WtL, int ldw, long wz,
                  float* C, _Float16* OH, _Float16* OL, int ldc, long oz,
                  const _Float16* Rh, const _Float16* Rl,
                  const float* b0, const float* b1_, const float* b2_,
                  int K, int flags) {
        hipLaunchKernelGGL(gemm3_kernel, dim3(NT_/128, gy, gz), dim3(256), 0, stream,
                           A_h, A_l, lda, WtH, WtL, ldw, wz,
                           C, OH, OL, ldc, oz, Rh, Rl, H_, b0, b1_, b2_, K, flags);
    };

    hipLaunchKernelGGL(embed_ln_kernel, dim3(NT_), dim3(256), 0, stream,
                       ids, we, pe, embs, embb, Xh, Xl);

    for (int i = 0; i < L_; i++) {
        const long WO = (long)i*HH;
        // QKV+O weights -> WA (z=4)
        hipLaunchKernelGGL(wconv_kernel, dim3(12,12,4), dim3(256), 0, stream,
                           Wq+WO, Wk+WO, Wv+WO, Wo+WO, H_, H_, WAh, WAl, HH);
        // QKV (z=3)
        g3(6, 3, Xh, Xl, H_, WAh, WAl, H_, HH,
           nullptr, Ph, Ph+NTHh, H_, 2*NTHh, nullptr, nullptr,
           bq+i*H_, bk+i*H_, bv+i*H_, H_, 0);
        // attention
        hipLaunchKernelGGL(attn2_kernel, dim3(B_*NH_*2), dim3(256), 0, stream,
                           Qh, Ql, Kh, Kl, Vh, Vl, amask, Ch, Cl);
        // O-proj + residual -> sum halves (Sh/Sl)
        g3(6, 1, Ch, Cl, H_, WAh+3*HH, WAl+3*HH, H_, 0,
           nullptr, Sh, Sl, H_, 0, Xh, Xl,
           bo+i*H_, nullptr, nullptr, H_, GF_ADDRES);
        hipLaunchKernelGGL(ln2_kernel, dim3(NT_), dim3(384), 0, stream,
                           Sh, Sl, sas+i*H_, sab+i*H_, Xh, Xl,
                           (_Float16*)nullptr, (_Float16*)nullptr);
        // FF weights
        hipLaunchKernelGGL(wconv_kernel, dim3(12,48,1), dim3(256), 0, stream,
                           W1f+(long)i*H_*FF_, nullptr, nullptr, nullptr,
                           H_, FF_, WB1h, WB1l, 0);
        hipLaunchKernelGGL(wconv_kernel, dim3(48,12,1), dim3(256), 0, stream,
                           W2f+(long)i*FF_*H_, nullptr, nullptr, nullptr,
                           FF_, H_, WB2h, WB2l, 0);
        for (int c = 0; c < 2; c++) {
            const int CW = FF_/2;  // 1536
            g3(12, 1, Xh, Xl, H_,
               WB1h+(long)c*CW*H_, WB1l+(long)c*CW*H_, H_, 0,
               nullptr, Fh, Fl, CW, 0, nullptr, nullptr,
               b1f+(long)i*FF_+c*CW, nullptr, nullptr, H_, GF_GELU_OUT);
            g3(6, 1, Fh, Fl, CW,
               WB2h+(long)c*CW, WB2l+(long)c*CW, FF_, 0,
               nullptr, Sh, Sl, H_, 0, Xh, Xl,
               (c==0) ? (b2f+i*H_) : nullptr, nullptr, nullptr,
               CW, (c==0) ? GF_ADDRES : GF_ACCH);
        }
        hipLaunchKernelGGL(ln2_kernel, dim3(NT_), dim3(384), 0, stream,
                           Sh, Sl, ols+i*H_, olb+i*H_, Xh, Xl,
                           (i==L_-1) ? Ch : (_Float16*)nullptr,
                           (i==L_-1) ? Cl : (_Float16*)nullptr);
    }

    hipLaunchKernelGGL(intent_kernel, dim3(B_), dim3(64), 0, stream,
                       Xh, Xl, iW1, ib1, iW2, ib2, itgt, iloss, outf);

    // slots head: H1 = relu(relu(x)@sW1 + sb1)  (relu(x) halves are in Ch/Cl)
    hipLaunchKernelGGL(wconv_kernel, dim3(12,4,1), dim3(256), 0, stream,
                       sW1, nullptr, nullptr, nullptr, H_, 256,
                       WAh, WAh + (long)256*H_, 0);
    g3(2, 1, Ch, Cl, H_, WAh, WAh + (long)256*H_, H_, 0,
       H1, nullptr, nullptr, 256, 0, nullptr, nullptr,
       sb1, nullptr, nullptr, H_, GF_RELU_OUT);
    hipLaunchKernelGGL(gemm_kernel, dim3(NT_/BM, 2), dim3(256), 0, stream,
                       H1, 256, sW2, TAGS_, logits, TAGS_, sb2, NT_, TAGS_, 256);

    hipLaunchKernelGGL(crf_vit_kernel, dim3(B_, 2), dim3(128), 0, stream,
                       logits, stgt, smask, crfs, crfe, crft, crfv, BPg, outf);

    hipLaunchKernelGGL(combine_kernel, dim3(1), dim3(64), 0, stream,
                       iloss, crfv, lv, outf);
}

// Round 5
// 4807.608 us; speedup vs baseline: 1.0550x; 1.0155x over previous
//
#include <hip/hip_runtime.h>
#include <math.h>
#include <stdint.h>

// ---- problem constants ----
#define B_      64
#define S_      128
#define H_      768
#define L_      6
#define NH_     12
#define DH_     64
#define FF_     3072
#define INTENT_ 22
#define TAGS_   122
#define NT_     (B_*S_)          // 8192 tokens
#define LN_EPS  1e-12f
#define INV_SQRT_DH 0.125f

#define GF_RELU_OUT 2
#define GF_GELU_OUT 4
#define GF_ADDRES   16   // add residual from Rh/Rl halves
#define GF_ACCH     32   // accumulate from current OH/OL contents

typedef _Float16 half8 __attribute__((ext_vector_type(8)));
typedef float    f32x4 __attribute__((ext_vector_type(4)));

// ===================== async global->LDS 16B =====================
__device__ __forceinline__ void gld16(const _Float16* g, _Float16* l) {
    __builtin_amdgcn_global_load_lds(
        (const __attribute__((address_space(1))) unsigned int*)(uintptr_t)g,
        (__attribute__((address_space(3))) unsigned int*)(unsigned int)(uintptr_t)l,
        16, 0, 0);
}

__device__ inline float wave_max(float v){
    #pragma unroll
    for (int d = 32; d; d >>= 1) v = fmaxf(v, __shfl_xor(v, d));
    return v;
}
__device__ inline float wave_sum(float v){
    #pragma unroll
    for (int d = 32; d; d >>= 1) v += __shfl_xor(v, d);
    return v;
}

// ===================== embedding + LN -> split halves =====================
__global__ __launch_bounds__(256) void embed_ln_kernel(
    const int* __restrict__ ids, const float* __restrict__ we,
    const float* __restrict__ pe, const float* __restrict__ gs,
    const float* __restrict__ gb, _Float16* __restrict__ Xh,
    _Float16* __restrict__ Xl)
{
    __shared__ float red[256];
    int bs = blockIdx.x;
    int sq = bs % S_;
    int id = ids[bs];
    int tid = threadIdx.x;
    const float* wrow = we + (size_t)id * H_;
    const float* prow = pe + (size_t)sq * H_;
    float z[3];
    #pragma unroll
    for (int r = 0; r < 3; r++) {
        int h = tid + 256*r;
        z[r] = wrow[h] + prow[h];
    }
    float sum = z[0]+z[1]+z[2];
    red[tid] = sum; __syncthreads();
    for (int off = 128; off > 0; off >>= 1) {
        if (tid < off) red[tid] += red[tid+off];
        __syncthreads();
    }
    float m = red[0] * (1.0f/H_); __syncthreads();
    float vs = 0.f;
    #pragma unroll
    for (int r = 0; r < 3; r++) { float d = z[r]-m; vs += d*d; }
    red[tid] = vs; __syncthreads();
    for (int off = 128; off > 0; off >>= 1) {
        if (tid < off) red[tid] += red[tid+off];
        __syncthreads();
    }
    float rstd = 1.0f / sqrtf(red[0]*(1.0f/H_) + LN_EPS);
    #pragma unroll
    for (int r = 0; r < 3; r++) {
        int h = tid + 256*r;
        float val = (z[r]-m)*rstd*gs[h] + gb[h];
        _Float16 hv = (_Float16)val;
        Xh[(size_t)bs*H_ + h] = hv;
        Xl[(size_t)bs*H_ + h] = (_Float16)(val - (float)hv);
    }
}

// ===================== LN over sum-halves -> split halves (+relu copy) ====
__global__ __launch_bounds__(384) void ln2_kernel(
    const _Float16* __restrict__ Sh, const _Float16* __restrict__ Sl,
    const float* __restrict__ gs, const float* __restrict__ gb,
    _Float16* __restrict__ Xh, _Float16* __restrict__ Xl,
    _Float16* __restrict__ Rh, _Float16* __restrict__ Rl)
{
    __shared__ float red[512];
    int bs = blockIdx.x, tid = threadIdx.x;
    size_t base = (size_t)bs*H_ + tid*2;
    union UU { _Float16 h[2]; unsigned u; };
    UU uh, ul;
    uh.u = *(const unsigned*)(Sh + base);
    ul.u = *(const unsigned*)(Sl + base);
    float z0 = (float)uh.h[0] + (float)ul.h[0];
    float z1 = (float)uh.h[1] + (float)ul.h[1];
    red[tid] = z0 + z1;
    if (tid < 128) red[384+tid] = 0.f;
    __syncthreads();
    for (int off = 256; off > 0; off >>= 1) {
        if (tid < off) red[tid] += red[tid+off];
        __syncthreads();
    }
    float m = red[0] * (1.0f/H_);
    __syncthreads();
    float d0 = z0-m, d1 = z1-m;
    red[tid] = d0*d0 + d1*d1;
    if (tid < 128) red[384+tid] = 0.f;
    __syncthreads();
    for (int off = 256; off > 0; off >>= 1) {
        if (tid < off) red[tid] += red[tid+off];
        __syncthreads();
    }
    float rstd = 1.0f / sqrtf(red[0]*(1.0f/H_) + LN_EPS);
    float2 gv = *(const float2*)(gs + tid*2);
    float2 bv = *(const float2*)(gb + tid*2);
    float v0 = d0*rstd*gv.x + bv.x;
    float v1 = d1*rstd*gv.y + bv.y;
    UU oh, ol;
    oh.h[0] = (_Float16)v0; ol.h[0] = (_Float16)(v0 - (float)oh.h[0]);
    oh.h[1] = (_Float16)v1; ol.h[1] = (_Float16)(v1 - (float)oh.h[1]);
    *(unsigned*)(Xh + base) = oh.u;
    *(unsigned*)(Xl + base) = ol.u;
    if (Rh) {
        float r0 = fmaxf(v0, 0.f), r1 = fmaxf(v1, 0.f);
        UU rh, rl;
        rh.h[0] = (_Float16)r0; rl.h[0] = (_Float16)(r0 - (float)rh.h[0]);
        rh.h[1] = (_Float16)r1; rl.h[1] = (_Float16)(r1 - (float)rh.h[1]);
        *(unsigned*)(Rh + base) = rh.u;
        *(unsigned*)(Rl + base) = rl.u;
    }
}

// ===================== weight transpose + fp16 hi/lo split =====================
// W [K][N] fp32 row-major -> Wt hi/lo [N][K] halves. grid (K/64, N/64, nz)
__global__ __launch_bounds__(256) void wconv_kernel(
    const float* __restrict__ W0, const float* __restrict__ W1,
    const float* __restrict__ W2, const float* __restrict__ W3,
    int K, int N, _Float16* __restrict__ OH, _Float16* __restrict__ OL, long zoff)
{
    __shared__ float t[64][65];
    int z = blockIdx.z;
    const float* W = (z==0) ? W0 : ((z==1) ? W1 : ((z==2) ? W2 : W3));
    OH += (long)z*zoff; OL += (long)z*zoff;
    int k0 = blockIdx.x*64, n0 = blockIdx.y*64;
    int tid = threadIdx.x;
    int lr = tid>>4, lc = (tid&15)*4;
    #pragma unroll
    for (int p = 0; p < 4; p++) {
        float4 v = *(const float4*)&W[(size_t)(k0+lr+16*p)*N + n0 + lc];
        t[lr+16*p][lc]   = v.x; t[lr+16*p][lc+1] = v.y;
        t[lr+16*p][lc+2] = v.z; t[lr+16*p][lc+3] = v.w;
    }
    __syncthreads();
    int n = tid>>2, kb = (tid&3)*16;
    union U { _Float16 h[8]; uint4 u; } h0, h1, l0, l1;
    #pragma unroll
    for (int e = 0; e < 8; e++) {
        float x = t[kb+e][n];
        _Float16 hv = (_Float16)x;
        h0.h[e] = hv; l0.h[e] = (_Float16)(x - (float)hv);
    }
    #pragma unroll
    for (int e = 0; e < 8; e++) {
        float x = t[kb+8+e][n];
        _Float16 hv = (_Float16)x;
        h1.h[e] = hv; l1.h[e] = (_Float16)(x - (float)hv);
    }
    size_t ob = (size_t)(n0+n)*K + k0 + kb;
    *(uint4*)&OH[ob]   = h0.u;
    *(uint4*)&OH[ob+8] = h1.u;
    *(uint4*)&OL[ob]   = l0.u;
    *(uint4*)&OL[ob+8] = l1.u;
}

// ===================== MFMA fp16-split GEMM v3 (global_load_lds staging) ====
// All inputs pre-split halves. M fixed by grid.x*128, N by grid.y*128, K param.
// Staging keeps the COALESCED global pattern (4 consecutive lanes cover one
// contiguous 64B row segment) but XOR-permutes the 16B k-chunk WITHIN each
// row: slot = kchunk ^ ((row>>1)&3). global_load_lds writes LDS linearly
// (rule #21), so the LDS layout inherits the permutation; the fragment
// ds_read_b128 applies the same XOR and lands 2 lanes/bank (free).
__global__ __launch_bounds__(256) void gemm3_kernel(
    const _Float16* __restrict__ AhG, const _Float16* __restrict__ AlG, int lda,
    const _Float16* __restrict__ WtHb, const _Float16* __restrict__ WtLb,
    int ldw, long wz,
    float* __restrict__ C, _Float16* __restrict__ OHb, _Float16* __restrict__ OLb,
    int ldc, long oz,
    const _Float16* __restrict__ Rh, const _Float16* __restrict__ Rl, int ldr,
    const float* __restrict__ bias0, const float* __restrict__ bias1,
    const float* __restrict__ bias2,
    int K, int flags)
{
    __shared__ __align__(16) _Float16 Ah[128*32], Al[128*32];
    __shared__ __align__(16) _Float16 Bh[128*32], Bl[128*32];
    const int z = blockIdx.z;
    const _Float16* WtH = WtHb + (long)z*wz;
    const _Float16* WtL = WtLb + (long)z*wz;
    _Float16* oh = OHb ? OHb + (long)z*oz : (_Float16*)0;
    _Float16* ol = OLb ? OLb + (long)z*oz : (_Float16*)0;
    const float* bias = (z==0) ? bias0 : ((z==1) ? bias1 : bias2);
    const int tid = threadIdx.x, lane = tid&63, wid = tid>>6;
    const int wm = wid&1, wn = wid>>1;
    const int l15 = lane&15, quad = lane>>4;
    const int m0 = blockIdx.x*128, n0 = blockIdx.y*128;

    // staging assignment: wave 0->Ah, 1->Al, 2->Bh, 3->Bl
    const _Float16* gsrc; _Float16* lbuf; int ld_s; int r0;
    if (wid == 0)      { gsrc = AhG; lbuf = Ah; ld_s = lda; r0 = m0; }
    else if (wid == 1) { gsrc = AlG; lbuf = Al; ld_s = lda; r0 = m0; }
    else if (wid == 2) { gsrc = WtH; lbuf = Bh; ld_s = ldw; r0 = n0; }
    else               { gsrc = WtL; lbuf = Bl; ld_s = ldw; r0 = n0; }
    // coalesced rows (lane>>2) with per-row k-chunk XOR swizzle.
    const int kch = (lane&3) ^ ((lane>>3)&3);
    const _Float16* gbase = gsrc + (size_t)(r0 + (lane>>2))*ld_s + kch*8;

    // fragment-read slot: stored slot = quad ^ ((l15>>1)&3)
    const int slot = quad ^ ((l15>>1)&3);

    f32x4 acc[4][4];
    #pragma unroll
    for (int i = 0; i < 4; i++)
        #pragma unroll
        for (int j = 0; j < 4; j++)
            acc[i][j] = (f32x4){0.f,0.f,0.f,0.f};

    for (int k0 = 0; k0 < K; k0 += 32) {
        #pragma unroll
        for (int q = 0; q < 8; q++)
            gld16(gbase + (size_t)(q*16)*ld_s + k0, lbuf + q*512);
        __syncthreads();
        half8 afh[4], afl[4], bfh[4], bfl[4];
        #pragma unroll
        for (int i = 0; i < 4; i++) {
            int m = wm*64 + i*16 + l15;
            afh[i] = *(const half8*)&Ah[m*32 + slot*8];
            afl[i] = *(const half8*)&Al[m*32 + slot*8];
            int n = wn*64 + i*16 + l15;
            bfh[i] = *(const half8*)&Bh[n*32 + slot*8];
            bfl[i] = *(const half8*)&Bl[n*32 + slot*8];
        }
        #pragma unroll
        for (int i = 0; i < 4; i++)
            #pragma unroll
            for (int j = 0; j < 4; j++) {
                acc[i][j] = __builtin_amdgcn_mfma_f32_16x16x32_f16(afh[i], bfh[j], acc[i][j], 0,0,0);
                acc[i][j] = __builtin_amdgcn_mfma_f32_16x16x32_f16(afh[i], bfl[j], acc[i][j], 0,0,0);
                acc[i][j] = __builtin_amdgcn_mfma_f32_16x16x32_f16(afl[i], bfh[j], acc[i][j], 0,0,0);
            }
        __syncthreads();
    }
    // ---- epilogue: C/D layout col=lane&15, row=quad*4+reg ----
    #pragma unroll
    for (int i = 0; i < 4; i++)
        #pragma unroll
        for (int j = 0; j < 4; j++)
            #pragma unroll
            for (int r = 0; r < 4; r++) {
                int gm = m0 + wm*64 + i*16 + quad*4 + r;
                int gn = n0 + wn*64 + j*16 + l15;
                float v = acc[i][j][r];
                if (bias) v += bias[gn];
                size_t ox = (size_t)gm*ldc + gn;
                if (flags & GF_ADDRES) {
                    size_t rx = (size_t)gm*ldr + gn;
                    v += (float)Rh[rx] + (float)Rl[rx];
                }
                if (flags & GF_ACCH)
                    v += (float)oh[ox] + (float)ol[ox];
                if (flags & GF_RELU_OUT) v = fmaxf(v, 0.f);
                if (flags & GF_GELU_OUT) v = 0.5f*v*(1.0f + erff(v*0.70710678118654752f));
                if (oh) {
                    _Float16 hv = (_Float16)v;
                    oh[ox] = hv;
                    ol[ox] = (_Float16)(v - (float)hv);
                } else {
                    C[ox] = v;
                }
            }
}

// ===================== fp32 GEMM (small head GEMM, N=122) =====================
#define BM 64
#define BN 64
#define BK 16
__global__ __launch_bounds__(256) void gemm_kernel(
    const float* __restrict__ A, int lda,
    const float* __restrict__ W, int ldb,
    float* __restrict__ C, int ldc,
    const float* __restrict__ bias,
    int M, int N, int K)
{
    __shared__ __align__(16) float As[BK][BM+4];
    __shared__ __align__(16) float Bs[BK][BN+4];
    int tid = threadIdx.x;
    int tx = tid & 15, ty = tid >> 4;
    int m0 = blockIdx.x * BM;
    int n0 = blockIdx.y * BN;
    float acc[4][4] = {};
    for (int k0 = 0; k0 < K; k0 += BK) {
        #pragma unroll
        for (int r = 0; r < 4; r++) {
            int li = tid + 256*r;
            int m  = li >> 4;
            int kk = li & 15;
            int gm = m0 + m, gk = k0 + kk;
            As[kk][m] = (gm < M && gk < K) ? A[(size_t)gm*lda + gk] : 0.f;
        }
        #pragma unroll
        for (int r = 0; r < 4; r++) {
            int li = tid + 256*r;
            int kk = li >> 6;
            int n  = li & 63;
            int gk = k0 + kk, gn = n0 + n;
            Bs[kk][n] = (gk < K && gn < N) ? W[(size_t)gk*ldb + gn] : 0.f;
        }
        __syncthreads();
        #pragma unroll
        for (int kk = 0; kk < BK; kk++) {
            float4 a  = *(const float4*)&As[kk][ty*4];
            float4 bb = *(const float4*)&Bs[kk][tx*4];
            float av[4] = {a.x, a.y, a.z, a.w};
            float bv[4] = {bb.x, bb.y, bb.z, bb.w};
            #pragma unroll
            for (int i = 0; i < 4; i++)
                #pragma unroll
                for (int j = 0; j < 4; j++)
                    acc[i][j] += av[i] * bv[j];
        }
        __syncthreads();
    }
    #pragma unroll
    for (int i = 0; i < 4; i++) {
        int gm = m0 + ty*4 + i;
        if (gm >= M) continue;
        #pragma unroll
        for (int j = 0; j < 4; j++) {
            int gn = n0 + tx*4 + j;
            if (gn >= N) continue;
            float v = acc[i][j];
            if (bias) v += bias[gn];
            C[(size_t)gm*ldc + gn] = v;
        }
    }
}

// ===================== MFMA attention =====================
__device__ inline int scidx(int row, int col) {
    return row*128 + (((col>>2) ^ (row&7))<<2) + (col&3);
}
__global__ __launch_bounds__(256) void attn2_kernel(
    const _Float16* __restrict__ QhG, const _Float16* __restrict__ QlG,
    const _Float16* __restrict__ KhG, const _Float16* __restrict__ KlG,
    const _Float16* __restrict__ VhG, const _Float16* __restrict__ VlG,
    const int* __restrict__ amask,
    _Float16* __restrict__ Ch, _Float16* __restrict__ Cl)
{
    __shared__ __align__(16) char smem[65536];
    _Float16* Qh_s = (_Float16*)smem;            // [64][72]
    _Float16* Ql_s = Qh_s + 64*72;
    _Float16* Kh_s = Ql_s + 64*72;               // [128][72]
    _Float16* Kl_s = Kh_s + 128*72;
    float*    Sc   = (float*)smem;               // [64][128] swizzled (phase 2)
    _Float16* Vth  = (_Float16*)(smem + 32768);  // [64][128] swizzled
    _Float16* Vtl  = Vth + 64*128;

    int blk = blockIdx.x;
    int qh2 = blk & 1;
    int bh  = blk >> 1;
    int b = bh / NH_, hh = bh % NH_;
    const int tid = threadIdx.x, lane = tid&63, wid = tid>>6;
    const int l15 = lane&15, quad = lane>>4;
    const int qr = wid*16;
    size_t tokb = (size_t)b*S_*H_ + (size_t)hh*DH_;

    float nmask[8];
    #pragma unroll
    for (int j = 0; j < 8; j++)
        nmask[j] = (amask[b*S_ + j*16 + l15] > 0) ? 0.f : -1e9f;

    {
        int row = tid>>2, part = (tid&3)*16;
        size_t qg = tokb + (size_t)(qh2*64 + row)*H_ + part;
        *(uint4*)&Qh_s[row*72 + part] = *(const uint4*)(QhG + qg);
        *(uint4*)&Ql_s[row*72 + part] = *(const uint4*)(QlG + qg);
        #pragma unroll
        for (int p = 0; p < 2; p++) {
            int krow = row + p*64;
            size_t kg = tokb + (size_t)krow*H_ + part;
            *(uint4*)&Kh_s[krow*72 + part] = *(const uint4*)(KhG + kg);
            *(uint4*)&Kl_s[krow*72 + part] = *(const uint4*)(KlG + kg);
        }
    }
    __syncthreads();

    f32x4 acc1[8];
    #pragma unroll
    for (int j = 0; j < 8; j++) acc1[j] = (f32x4){0.f,0.f,0.f,0.f};
    half8 aqh[2], aql[2];
    #pragma unroll
    for (int kc = 0; kc < 2; kc++) {
        aqh[kc] = *(const half8*)&Qh_s[(qr + l15)*72 + kc*32 + quad*8];
        aql[kc] = *(const half8*)&Ql_s[(qr + l15)*72 + kc*32 + quad*8];
    }
    #pragma unroll
    for (int j = 0; j < 8; j++) {
        #pragma unroll
        for (int kc = 0; kc < 2; kc++) {
            half8 bkh = *(const half8*)&Kh_s[(j*16 + l15)*72 + kc*32 + quad*8];
            half8 bkl = *(const half8*)&Kl_s[(j*16 + l15)*72 + kc*32 + quad*8];
            acc1[j] = __builtin_amdgcn_mfma_f32_16x16x32_f16(aqh[kc], bkh, acc1[j], 0,0,0);
            acc1[j] = __builtin_amdgcn_mfma_f32_16x16x32_f16(aqh[kc], bkl, acc1[j], 0,0,0);
            acc1[j] = __builtin_amdgcn_mfma_f32_16x16x32_f16(aql[kc], bkh, acc1[j], 0,0,0);
        }
    }
    __syncthreads();

    #pragma unroll
    for (int j = 0; j < 8; j++)
        #pragma unroll
        for (int r = 0; r < 4; r++) {
            int row = qr + quad*4 + r;
            int col = j*16 + l15;
            Sc[scidx(row, col)] = acc1[j][r]*INV_SQRT_DH + nmask[j];
        }
    {
        int key = tid>>1, dh = (tid&1)*32;
        union V32 { _Float16 h[32]; uint4 u[4]; } bufh, bufl;
        #pragma unroll
        for (int e = 0; e < 4; e++) {
            bufh.u[e] = *(const uint4*)(VhG + tokb + (size_t)key*H_ + dh + e*8);
            bufl.u[e] = *(const uint4*)(VlG + tokb + (size_t)key*H_ + dh + e*8);
        }
        int kg = key>>3, kr = key&7;
        #pragma unroll
        for (int e = 0; e < 32; e++) {
            int d = dh + e;
            int pos = kg ^ (d & 7);
            Vth[d*128 + pos*8 + kr] = bufh.h[e];
            Vtl[d*128 + pos*8 + kr] = bufl.h[e];
        }
    }
    __syncthreads();

    {
        int row = tid>>2, part = (tid&3)*32;
        float mx = -INFINITY;
        #pragma unroll 8
        for (int e = 0; e < 32; e++)
            mx = fmaxf(mx, Sc[scidx(row, part+e)]);
        mx = fmaxf(mx, __shfl_xor(mx, 1));
        mx = fmaxf(mx, __shfl_xor(mx, 2));
        float s = 0.f;
        #pragma unroll 8
        for (int e = 0; e < 32; e++) {
            int idx = scidx(row, part+e);
            float ev = expf(Sc[idx] - mx);
            Sc[idx] = ev; s += ev;
        }
        s += __shfl_xor(s, 1);
        s += __shfl_xor(s, 2);
        float inv = 1.0f / s;
        #pragma unroll 8
        for (int e = 0; e < 32; e++)
            Sc[scidx(row, part+e)] *= inv;
    }
    __syncthreads();

    f32x4 acc2[4];
    #pragma unroll
    for (int jd = 0; jd < 4; jd++) acc2[jd] = (f32x4){0.f,0.f,0.f,0.f};
    #pragma unroll
    for (int kc = 0; kc < 4; kc++) {
        int q = qr + l15;
        int g16 = kc*8 + quad*2;
        float4 p0 = *(const float4*)&Sc[q*128 + ((g16   ^ (q&7))<<2)];
        float4 p1 = *(const float4*)&Sc[q*128 + (((g16+1) ^ (q&7))<<2)];
        float pv[8] = {p0.x,p0.y,p0.z,p0.w, p1.x,p1.y,p1.z,p1.w};
        union U { _Float16 h[8]; half8 v; } ph, pl;
        #pragma unroll
        for (int e = 0; e < 8; e++) {
            _Float16 hv = (_Float16)pv[e];
            ph.h[e] = hv; pl.h[e] = (_Float16)(pv[e] - (float)hv);
        }
        #pragma unroll
        for (int jd = 0; jd < 4; jd++) {
            int n = jd*16 + l15;
            int pos = (kc*4 + quad) ^ (n & 7);
            half8 vh = *(const half8*)&Vth[n*128 + pos*8];
            half8 vl = *(const half8*)&Vtl[n*128 + pos*8];
            acc2[jd] = __builtin_amdgcn_mfma_f32_16x16x32_f16(ph.v, vh, acc2[jd], 0,0,0);
            acc2[jd] = __builtin_amdgcn_mfma_f32_16x16x32_f16(ph.v, vl, acc2[jd], 0,0,0);
            acc2[jd] = __builtin_amdgcn_mfma_f32_16x16x32_f16(pl.v, vh, acc2[jd], 0,0,0);
        }
    }
    #pragma unroll
    for (int jd = 0; jd < 4; jd++)
        #pragma unroll
        for (int r = 0; r < 4; r++) {
            int row = qr + quad*4 + r;
            int token = b*S_ + qh2*64 + row;
            int d = jd*16 + l15;
            float v = acc2[jd][r];
            _Float16 hv = (_Float16)v;
            Ch[(size_t)token*H_ + hh*DH_ + d] = hv;
            Cl[(size_t)token*H_ + hh*DH_ + d] = (_Float16)(v - (float)hv);
        }
}

// ===================== intent head =====================
__global__ __launch_bounds__(64) void intent_kernel(
    const _Float16* __restrict__ Xh, const _Float16* __restrict__ Xl,
    const float* __restrict__ iW1,
    const float* __restrict__ ib1, const float* __restrict__ iW2,
    const float* __restrict__ ib2, const int* __restrict__ tgt,
    float* __restrict__ iloss, float* __restrict__ outf)
{
    int b = blockIdx.x; int j = threadIdx.x;
    __shared__ float h1[64];
    __shared__ float lg[32];
    const _Float16* x0h = Xh + (size_t)b*S_*H_;
    const _Float16* x0l = Xl + (size_t)b*S_*H_;
    float acc = ib1[j];
    for (int h = 0; h < H_; h++) {
        float x = (float)x0h[h] + (float)x0l[h];
        acc += fmaxf(x, 0.f) * iW1[(size_t)h*64 + j];
    }
    h1[j] = fmaxf(acc, 0.f);
    __syncthreads();
    if (j < INTENT_) {
        float l = ib2[j];
        for (int k = 0; k < 64; k++) l += h1[k]*iW2[k*INTENT_ + j];
        lg[j] = l;
    }
    __syncthreads();
    if (j == 0) {
        float mx = -INFINITY; int bi = 0;
        for (int c = 0; c < INTENT_; c++) if (lg[c] > mx) { mx = lg[c]; bi = c; }
        float sm = 0.f;
        for (int c = 0; c < INTENT_; c++) sm += expf(lg[c]-mx);
        float lse = mx + logf(sm);
        iloss[b] = lse - lg[tgt[b]];
        outf[1 + (size_t)NT_ + b] = (float)bi;
    }
}

// ===================== fused CRF-llh + Viterbi (512 thr, 1 barrier/step) ===
// grid (64, 2): y=0 -> CRF llh ; y=1 -> Viterbi.
// 512 threads: j = tid>>2 (tag), p = tid&3 (i-partition, i = 4e+p).
// Proven 512-thread structure (8 waves, tT[j*130+i] conflict-free scalar
// reads) but alpha lives in REGISTERS (all 4 p-threads hold identical copies
// after the 2-shfl reduce) and ealpha/alpha are exchanged via a PARITY
// double-buffer -> exactly ONE __syncthreads per scan step (llh was 4,
// viterbi was 2). The logsumexp subtractor X is mathematically arbitrary
// (nv = X + log sum exp(a_i - X) * T is exact for any X); we use the global
// max DEFERRED by one step (drift/step <= ~log(122), exp stays tiny).
#define VST 130
__global__ __launch_bounds__(512) void crf_vit_kernel(
    const float* __restrict__ E_, const int* __restrict__ tags,
    const int* __restrict__ mask, const float* __restrict__ start,
    const float* __restrict__ endv, const float* __restrict__ trans,
    float* __restrict__ crfv, unsigned char* __restrict__ BPg,
    float* __restrict__ outf)
{
    __shared__ __align__(16) float tT[TAGS_*VST];   // 63,440 B [j][i]
    __shared__ __align__(16) float eal[2][128];     // parity exchange buffer
    __shared__ float mxw[2][8];                     // per-wave max, by parity
    __shared__ float mxbuf[16];
    __shared__ int lastt;
    int b = blockIdx.x;
    int mode = blockIdx.y;
    int tid = threadIdx.x, lane = tid&63, wid = tid>>6;
    int j = tid>>2, p = tid&3;
    int cnt = (p < 2) ? 31 : 30;
    bool vj = (j < TAGS_);
    const float* E = E_ + (size_t)b*S_*TAGS_;

    if (vj) {
        for (int e = 0; e < cnt; e++) {
            int i = 4*e + p;
            float tv = trans[i*TAGS_ + j];
            tT[j*VST + i] = mode ? tv : expf(tv);
        }
    }
    float aj = vj ? (start[j] + E[j]) : -3e38f;

    if (mode == 0) {
        // ---------- CRF log-likelihood ----------
        // prologue: exact max of alpha0 -> xc; eal[0] = exp(a0 - xc)
        {
            float wm = wave_max(aj);
            if (lane == 0) mxw[0][wid] = wm;
        }
        __syncthreads();                    // also covers tT load
        float gm = mxw[0][0];
        #pragma unroll
        for (int w = 1; w < 8; w++) gm = fmaxf(gm, mxw[0][w]);
        float xc = gm;                      // subtractor of eal[cur]
        if (p == 0) eal[0][j] = vj ? expf(aj - xc) : 0.f;
        __syncthreads();
        int cur = 0;
        float eC = vj ? E[(size_t)TAGS_ + j] : 0.f;   // E[1][j]
        int   mC = mask[b*S_ + 1];
        for (int t = 1; t < S_; t++) {
            float e = eC; int m_t = mC;
            if (t + 1 < S_) {               // prefetch next step
                eC = vj ? E[(size_t)(t+1)*TAGS_ + j] : 0.f;
                mC = mask[b*S_ + t + 1];
            }
            float s = 0.f;
            if (vj) {
                const float* tr = &tT[j*VST];
                const float* eb = &eal[cur][0];
                float sa = 0.f, sb = 0.f;
                for (int e2 = 0; e2 + 1 < cnt; e2 += 2) {
                    int i0 = 4*e2 + p, i1 = 4*e2 + 4 + p;
                    sa += eb[i0] * tr[i0];
                    sb += eb[i1] * tr[i1];
                }
                if (cnt & 1) { int il = 4*(cnt-1) + p; sa += eb[il] * tr[il]; }
                s = sa + sb;
            }
            s += __shfl_xor(s, 1);
            s += __shfl_xor(s, 2);
            if (m_t && vj) aj = xc + logf(s) + e;
            int nxt = cur ^ 1;
            float xn = gm;                  // deferred subtractor (exact math)
            if (p == 0) eal[nxt][j] = vj ? expf(aj - xn) : 0.f;
            float wm2 = wave_max(aj);
            if (lane == 0) mxw[nxt][wid] = wm2;
            __syncthreads();                // ONE barrier per step
            float nm = mxw[nxt][0];
            #pragma unroll
            for (int w = 1; w < 8; w++) nm = fmaxf(nm, mxw[nxt][w]);
            gm = nm;
            xc = xn;
            cur = nxt;
        }
        // dump alpha to LDS for the final reduction (reuse eal[0])
        if (p == 0) eal[0][j] = aj;
        // numerator over timesteps (threads 0..127 handle t)
        float term = 0.f, mkf = 0.f;
        if (tid < S_) {
            int mk = mask[b*S_ + tid]; mkf = (float)mk;
            if (tid >= 1 && mk) {
                int tg = tags[b*S_ + tid], tgp = tags[b*S_ + tid - 1];
                term = trans[tgp*TAGS_ + tg] + E[(size_t)tid*TAGS_ + tg];
            }
        }
        if (wid < 2) {
            float ts = wave_sum(term);
            float ms = wave_sum(mkf);
            if (lane == 0) { mxbuf[2+wid] = ts; mxbuf[4+wid] = ms; }
        }
        __syncthreads();
        if (wid == 0) {
            const float* alp = &eal[0][0];
            float v1 = (lane < TAGS_) ? alp[lane] + endv[lane] : -3e38f;
            float v2 = (lane+64 < TAGS_) ? alp[lane+64] + endv[lane+64] : -3e38f;
            float m = wave_max(fmaxf(v1, v2));
            float sd = ((lane < TAGS_) ? expf(v1 - m) : 0.f)
                     + ((lane+64 < TAGS_) ? expf(v2 - m) : 0.f);
            sd = wave_sum(sd);
            if (lane == 0) {
                float denom = m + logf(sd);
                float numsum = mxbuf[2] + mxbuf[3];
                int msum = (int)(mxbuf[4] + mxbuf[5]);
                int tag0 = tags[b*S_];
                int last_tag = tags[b*S_ + (msum - 1)];
                float num = start[tag0] + E[tag0] + numsum + endv[last_tag];
                crfv[b] = num - denom;
            }
        }
    } else {
        // ---------- Viterbi ----------
        if (p == 0) eal[0][j] = aj;
        __syncthreads();                    // covers tT load + alpha0
        int cur = 0;
        size_t bpb = (size_t)b*(S_-1)*TAGS_;
        float eC = vj ? E[(size_t)TAGS_ + j] : 0.f;
        int   mC = mask[b*S_ + 1];
        for (int t = 1; t < S_; t++) {
            float ee = eC; int m_t = mC;
            if (t + 1 < S_) {
                eC = vj ? E[(size_t)(t+1)*TAGS_ + j] : 0.f;
                mC = mask[b*S_ + t + 1];
            }
            float best = -3e38f; int bi = 0;
            if (vj) {
                const float* tr = &tT[j*VST];
                const float* ab = &eal[cur][0];
                for (int e = 0; e < cnt; e++) {
                    int i = 4*e + p;
                    float v = ab[i] + tr[i];
                    if (v > best) { best = v; bi = i; }
                }
            }
            {
                float ov = __shfl_xor(best, 1); int oi = __shfl_xor(bi, 1);
                if (ov > best || (ov == best && oi < bi)) { best = ov; bi = oi; }
                ov = __shfl_xor(best, 2); oi = __shfl_xor(bi, 2);
                if (ov > best || (ov == best && oi < bi)) { best = ov; bi = oi; }
            }
            float nv; int nb;
            if (m_t) { nv = best + ee; nb = bi; }
            else     { nv = aj; nb = j; }
            int nxt = cur ^ 1;
            if (vj) {
                aj = nv;
                if (p == 0) {
                    eal[nxt][j] = aj;
                    BPg[bpb + (size_t)(t-1)*TAGS_ + j] = (unsigned char)nb;
                }
            }
            __syncthreads();                // ONE barrier per step
            cur = nxt;
        }
        // dump alpha for final argmax
        if (p == 0) eal[0][j] = aj;
        __syncthreads();
        if (wid == 0) {
            const float* alp = &eal[0][0];
            float v; int idx;
            float v1 = (lane < TAGS_) ? alp[lane] + endv[lane] : -3e38f;
            float v2 = (lane+64 < TAGS_) ? alp[lane+64] + endv[lane+64] : -3e38f;
            if (v2 > v1) { v = v2; idx = lane+64; } else { v = v1; idx = lane; }
            #pragma unroll
            for (int d = 32; d; d >>= 1) {
                float ov = __shfl_xor(v, d); int oi = __shfl_xor(idx, d);
                if (ov > v || (ov == v && oi < idx)) { v = ov; idx = oi; }
            }
            if (lane == 0) lastt = idx;
        }
        __syncthreads();
        unsigned char* bpl = (unsigned char*)tT;
        for (int o = tid; o < (S_-1)*TAGS_; o += 512)
            bpl[o] = BPg[bpb + o];
        __syncthreads();
        if (tid == 0) {
            int tag = lastt;
            outf[1 + (size_t)b*S_ + (S_-1)] = (float)tag;
            for (int t = S_-1; t >= 1; t--) {
                tag = bpl[(t-1)*TAGS_ + tag];
                outf[1 + (size_t)b*S_ + (t-1)] = (float)tag;
            }
        }
    }
}

// ===================== final joint loss =====================
__global__ void combine_kernel(const float* __restrict__ iloss,
                               const float* __restrict__ crfv,
                               const float* __restrict__ lv,
                               float* __restrict__ outf)
{
    if (threadIdx.x == 0 && blockIdx.x == 0) {
        float si = 0.f, sc = 0.f;
        for (int b = 0; b < B_; b++) { si += iloss[b]; sc += crfv[b]; }
        float p1 = expf(-lv[0]), p2 = expf(-lv[1]);
        float slots_loss = -sc;
        outf[0] = p1*si + (float)B_*lv[0] + p2*slots_loss + lv[1];
    }
}

// ===================== host launch =====================
extern "C" void kernel_launch(void* const* d_in, const int* in_sizes, int n_in,
                              void* d_out, int out_size, void* d_ws, size_t ws_size,
                              hipStream_t stream) {
    const int*   ids   = (const int*)  d_in[0];
    const int*   amask = (const int*)  d_in[1];
    const int*   itgt  = (const int*)  d_in[2];
    const int*   stgt  = (const int*)  d_in[3];
    const int*   smask = (const int*)  d_in[4];
    const float* we    = (const float*)d_in[5];
    const float* pe    = (const float*)d_in[6];
    const float* embs  = (const float*)d_in[7];
    const float* embb  = (const float*)d_in[8];
    const float* Wq    = (const float*)d_in[9];
    const float* bq    = (const float*)d_in[10];
    const float* Wk    = (const float*)d_in[11];
    const float* bk    = (const float*)d_in[12];
    const float* Wv    = (const float*)d_in[13];
    const float* bv    = (const float*)d_in[14];
    const float* Wo    = (const float*)d_in[15];
    const float* bo    = (const float*)d_in[16];
    const float* sas   = (const float*)d_in[17];
    const float* sab   = (const float*)d_in[18];
    const float* W1f   = (const float*)d_in[19];
    const float* b1f   = (const float*)d_in[20];
    const float* W2f   = (const float*)d_in[21];
    const float* b2f   = (const float*)d_in[22];
    const float* ols   = (const float*)d_in[23];
    const float* olb   = (const float*)d_in[24];
    const float* iW1   = (const float*)d_in[25];
    const float* ib1   = (const float*)d_in[26];
    const float* iW2   = (const float*)d_in[27];
    const float* ib2   = (const float*)d_in[28];
    const float* sW1   = (const float*)d_in[29];
    const float* sb1   = (const float*)d_in[30];
    const float* sW2   = (const float*)d_in[31];
    const float* sb2   = (const float*)d_in[32];
    const float* crfs  = (const float*)d_in[33];
    const float* crfe  = (const float*)d_in[34];
    const float* crft  = (const float*)d_in[35];
    const float* lv    = (const float*)d_in[36];

    float* outf = (float*)d_out;
    float* wsf  = (float*)d_ws;
    const long NTHh = (long)NT_ * H_;        // 6,291,456 (halves per tensor)
    const long NBf  = NTHh;                  // floats per fp32-equivalent tensor
    const long HH   = (long)H_ * H_;         // 589,824

    // layout (floats): [XhXl: NBf][P: 3*NBf][ChCl: NBf][WA][WB1][WB2][misc]
    _Float16* Xh = (_Float16*)wsf;
    _Float16* Xl = Xh + NTHh;
    float*    Pf = wsf + NBf;
    _Float16* Ph = (_Float16*)Pf;
    _Float16 *Qh = Ph, *Ql = Ph + NTHh, *Kh = Ph + 2*NTHh, *Kl = Ph + 3*NTHh,
             *Vh = Ph + 4*NTHh, *Vl = Ph + 5*NTHh;
    _Float16 *Sh = Ph, *Sl = Ph + NTHh;                 // sum halves (reuse Q slot)
    _Float16* Fh = (_Float16*)(wsf + 2*NBf);            // FF intermediate hi
    _Float16* Fl = (_Float16*)(wsf + 3*NBf);            // FF intermediate lo
    _Float16* Ch = (_Float16*)(wsf + 4*NBf);
    _Float16* Cl = Ch + NTHh;
    const long wa0 = 5*NBf;
    _Float16* WAh = (_Float16*)(wsf + wa0);             // 8*HH halves (QKVO hi+lo)
    _Float16* WAl = WAh + 4*HH;
    const long wb1 = wa0 + 2359296;
    _Float16* WB1h = (_Float16*)(wsf + wb1);
    _Float16* WB1l = WB1h + 2359296;
    const long wb2 = wb1 + 2359296;
    _Float16* WB2h = (_Float16*)(wsf + wb2);
    _Float16* WB2l = WB2h + 2359296;
    float* iloss = wsf + wb2 + 2359296;
    float* crfv  = iloss + 64;
    // heads scratch in P region (free after encoder)
    float* H1 = Pf;                                     // 8192*256
    float* logits = Pf + 2097152;                       // 8192*122
    unsigned char* BPg = (unsigned char*)(Pf + 2097152 + 999424);

    auto g3 = [&](int gy, int gz,
                  const _Float16* A_h, const _Float16* A_l, int lda,
                  const _Float16* WtH, const _Float16* WtL, int ldw, long wz,
                  float* C, _Float16* OH, _Float16* OL, int ldc, long oz,
                  const _Float16* Rh, const _Float16* Rl,
                  const float* b0, const float* b1_, const float* b2_,
                  int K, int flags) {
        hipLaunchKernelGGL(gemm3_kernel, dim3(NT_/128, gy, gz), dim3(256), 0, stream,
                           A_h, A_l, lda, WtH, WtL, ldw, wz,
                           C, OH, OL, ldc, oz, Rh, Rl, H_, b0, b1_, b2_, K, flags);
    };

    hipLaunchKernelGGL(embed_ln_kernel, dim3(NT_), dim3(256), 0, stream,
                       ids, we, pe, embs, embb, Xh, Xl);

    for (int i = 0; i < L_; i++) {
        const long WO = (long)i*HH;
        // QKV+O weights -> WA (z=4)
        hipLaunchKernelGGL(wconv_kernel, dim3(12,12,4), dim3(256), 0, stream,
                           Wq+WO, Wk+WO, Wv+WO, Wo+WO, H_, H_, WAh, WAl, HH);
        // QKV (z=3)
        g3(6, 3, Xh, Xl, H_, WAh, WAl, H_, HH,
           nullptr, Ph, Ph+NTHh, H_, 2*NTHh, nullptr, nullptr,
           bq+i*H_, bk+i*H_, bv+i*H_, H_, 0);
        // attention
        hipLaunchKernelGGL(attn2_kernel, dim3(B_*NH_*2), dim3(256), 0, stream,
                           Qh, Ql, Kh, Kl, Vh, Vl, amask, Ch, Cl);
        // O-proj + residual -> sum halves (Sh/Sl)
        g3(6, 1, Ch, Cl, H_, WAh+3*HH, WAl+3*HH, H_, 0,
           nullptr, Sh, Sl, H_, 0, Xh, Xl,
           bo+i*H_, nullptr, nullptr, H_, GF_ADDRES);
        hipLaunchKernelGGL(ln2_kernel, dim3(NT_), dim3(384), 0, stream,
                           Sh, Sl, sas+i*H_, sab+i*H_, Xh, Xl,
                           (_Float16*)nullptr, (_Float16*)nullptr);
        // FF weights
        hipLaunchKernelGGL(wconv_kernel, dim3(12,48,1), dim3(256), 0, stream,
                           W1f+(long)i*H_*FF_, nullptr, nullptr, nullptr,
                           H_, FF_, WB1h, WB1l, 0);
        hipLaunchKernelGGL(wconv_kernel, dim3(48,12,1), dim3(256), 0, stream,
                           W2f+(long)i*FF_*H_, nullptr, nullptr, nullptr,
                           FF_, H_, WB2h, WB2l, 0);
        for (int c = 0; c < 2; c++) {
            const int CW = FF_/2;  // 1536
            g3(12, 1, Xh, Xl, H_,
               WB1h+(long)c*CW*H_, WB1l+(long)c*CW*H_, H_, 0,
               nullptr, Fh, Fl, CW, 0, nullptr, nullptr,
               b1f+(long)i*FF_+c*CW, nullptr, nullptr, H_, GF_GELU_OUT);
            g3(6, 1, Fh, Fl, CW,
               WB2h+(long)c*CW, WB2l+(long)c*CW, FF_, 0,
               nullptr, Sh, Sl, H_, 0, Xh, Xl,
               (c==0) ? (b2f+i*H_) : nullptr, nullptr, nullptr,
               CW, (c==0) ? GF_ADDRES : GF_ACCH);
        }
        hipLaunchKernelGGL(ln2_kernel, dim3(NT_), dim3(384), 0, stream,
                           Sh, Sl, ols+i*H_, olb+i*H_, Xh, Xl,
                           (i==L_-1) ? Ch : (_Float16*)nullptr,
                           (i==L_-1) ? Cl : (_Float16*)nullptr);
    }

    hipLaunchKernelGGL(intent_kernel, dim3(B_), dim3(64), 0, stream,
                       Xh, Xl, iW1, ib1, iW2, ib2, itgt, iloss, outf);

    // slots head: H1 = relu(relu(x)@sW1 + sb1)  (relu(x) halves are in Ch/Cl)
    hipLaunchKernelGGL(wconv_kernel, dim3(12,4,1), dim3(256), 0, stream,
                       sW1, nullptr, nullptr, nullptr, H_, 256,
                       WAh, WAh + (long)256*H_, 0);
    g3(2, 1, Ch, Cl, H_, WAh, WAh + (long)256*H_, H_, 0,
       H1, nullptr, nullptr, 256, 0, nullptr, nullptr,
       sb1, nullptr, nullptr, H_, GF_RELU_OUT);
    hipLaunchKernelGGL(gemm_kernel, dim3(NT_/BM, 2), dim3(256), 0, stream,
                       H1, 256, sW2, TAGS_, logits, TAGS_, sb2, NT_, TAGS_, 256);

    hipLaunchKernelGGL(crf_vit_kernel, dim3(B_, 2), dim3(512), 0, stream,
                       logits, stgt, smask, crfs, crfe, crft, crfv, BPg, outf);

    hipLaunchKernelGGL(combine_kernel, dim3(1), dim3(64), 0, stream,
                       iloss, crfv, lv, outf);
}

// Round 6
// 4700.916 us; speedup vs baseline: 1.0790x; 1.0227x over previous
//
#include <hip/hip_runtime.h>
#include <math.h>
#include <stdint.h>

// ---- problem constants ----
#define B_      64
#define S_      128
#define H_      768
#define L_      6
#define NH_     12
#define DH_     64
#define FF_     3072
#define INTENT_ 22
#define TAGS_   122
#define NT_     (B_*S_)          // 8192 tokens
#define LN_EPS  1e-12f
#define INV_SQRT_DH 0.125f

#define GF_RELU_OUT 2
#define GF_GELU_OUT 4
#define GF_ADDRES   16   // add residual from Rh/Rl halves
#define GF_ACCH     32   // accumulate from current OH/OL contents

typedef _Float16 half8 __attribute__((ext_vector_type(8)));
typedef float    f32x4 __attribute__((ext_vector_type(4)));

// ===================== async global->LDS 16B =====================
__device__ __forceinline__ void gld16(const _Float16* g, _Float16* l) {
    __builtin_amdgcn_global_load_lds(
        (const __attribute__((address_space(1))) unsigned int*)(uintptr_t)g,
        (__attribute__((address_space(3))) unsigned int*)(unsigned int)(uintptr_t)l,
        16, 0, 0);
}

__device__ inline float wave_max(float v){
    #pragma unroll
    for (int d = 32; d; d >>= 1) v = fmaxf(v, __shfl_xor(v, d));
    return v;
}
__device__ inline float wave_sum(float v){
    #pragma unroll
    for (int d = 32; d; d >>= 1) v += __shfl_xor(v, d);
    return v;
}

// ===================== embedding + LN -> split halves =====================
// 256 threads = 4 waves; shuffle reduction, 2 barriers total.
__global__ __launch_bounds__(256) void embed_ln_kernel(
    const int* __restrict__ ids, const float* __restrict__ we,
    const float* __restrict__ pe, const float* __restrict__ gs,
    const float* __restrict__ gb, _Float16* __restrict__ Xh,
    _Float16* __restrict__ Xl)
{
    __shared__ float red[16];
    int bs = blockIdx.x;
    int sq = bs % S_;
    int id = ids[bs];
    int tid = threadIdx.x;
    int lane = tid & 63, wid = tid >> 6;
    const float* wrow = we + (size_t)id * H_;
    const float* prow = pe + (size_t)sq * H_;
    float z[3];
    #pragma unroll
    for (int r = 0; r < 3; r++) {
        int h = tid + 256*r;
        z[r] = wrow[h] + prow[h];
    }
    float s1 = wave_sum(z[0]+z[1]+z[2]);
    if (lane == 0) red[wid] = s1;
    __syncthreads();
    float m = (red[0]+red[1]+red[2]+red[3]) * (1.0f/H_);
    float vs = 0.f;
    #pragma unroll
    for (int r = 0; r < 3; r++) { float d = z[r]-m; vs += d*d; }
    float s2 = wave_sum(vs);
    if (lane == 0) red[8+wid] = s2;
    __syncthreads();
    float rstd = 1.0f / sqrtf((red[8]+red[9]+red[10]+red[11])*(1.0f/H_) + LN_EPS);
    #pragma unroll
    for (int r = 0; r < 3; r++) {
        int h = tid + 256*r;
        float val = (z[r]-m)*rstd*gs[h] + gb[h];
        _Float16 hv = (_Float16)val;
        Xh[(size_t)bs*H_ + h] = hv;
        Xl[(size_t)bs*H_ + h] = (_Float16)(val - (float)hv);
    }
}

// ===================== LN over sum-halves -> split halves (+relu copy) ====
// 384 threads = 6 waves; shuffle reduction, 2 barriers total.
__global__ __launch_bounds__(384) void ln2_kernel(
    const _Float16* __restrict__ Sh, const _Float16* __restrict__ Sl,
    const float* __restrict__ gs, const float* __restrict__ gb,
    _Float16* __restrict__ Xh, _Float16* __restrict__ Xl,
    _Float16* __restrict__ Rh, _Float16* __restrict__ Rl)
{
    __shared__ float red[16];
    int bs = blockIdx.x, tid = threadIdx.x;
    int lane = tid & 63, wid = tid >> 6;
    size_t base = (size_t)bs*H_ + tid*2;
    union UU { _Float16 h[2]; unsigned u; };
    UU uh, ul;
    uh.u = *(const unsigned*)(Sh + base);
    ul.u = *(const unsigned*)(Sl + base);
    float z0 = (float)uh.h[0] + (float)ul.h[0];
    float z1 = (float)uh.h[1] + (float)ul.h[1];
    float s1 = wave_sum(z0 + z1);
    if (lane == 0) red[wid] = s1;
    __syncthreads();
    float m = (red[0]+red[1]+red[2]+red[3]+red[4]+red[5]) * (1.0f/H_);
    float d0 = z0-m, d1 = z1-m;
    float s2 = wave_sum(d0*d0 + d1*d1);
    if (lane == 0) red[8+wid] = s2;
    __syncthreads();
    float var = (red[8]+red[9]+red[10]+red[11]+red[12]+red[13]) * (1.0f/H_);
    float rstd = 1.0f / sqrtf(var + LN_EPS);
    float2 gv = *(const float2*)(gs + tid*2);
    float2 bv = *(const float2*)(gb + tid*2);
    float v0 = d0*rstd*gv.x + bv.x;
    float v1 = d1*rstd*gv.y + bv.y;
    UU oh, ol;
    oh.h[0] = (_Float16)v0; ol.h[0] = (_Float16)(v0 - (float)oh.h[0]);
    oh.h[1] = (_Float16)v1; ol.h[1] = (_Float16)(v1 - (float)oh.h[1]);
    *(unsigned*)(Xh + base) = oh.u;
    *(unsigned*)(Xl + base) = ol.u;
    if (Rh) {
        float r0 = fmaxf(v0, 0.f), r1 = fmaxf(v1, 0.f);
        UU rh, rl;
        rh.h[0] = (_Float16)r0; rl.h[0] = (_Float16)(r0 - (float)rh.h[0]);
        rh.h[1] = (_Float16)r1; rl.h[1] = (_Float16)(r1 - (float)rh.h[1]);
        *(unsigned*)(Rh + base) = rh.u;
        *(unsigned*)(Rl + base) = rl.u;
    }
}

// ===================== weight transpose + fp16 hi/lo split =====================
// W [K][N] fp32 row-major -> Wt hi/lo [N][K] halves. grid (K/64, N/64, nz)
__global__ __launch_bounds__(256) void wconv_kernel(
    const float* __restrict__ W0, const float* __restrict__ W1,
    const float* __restrict__ W2, const float* __restrict__ W3,
    int K, int N, _Float16* __restrict__ OH, _Float16* __restrict__ OL, long zoff)
{
    __shared__ float t[64][65];
    int z = blockIdx.z;
    const float* W = (z==0) ? W0 : ((z==1) ? W1 : ((z==2) ? W2 : W3));
    OH += (long)z*zoff; OL += (long)z*zoff;
    int k0 = blockIdx.x*64, n0 = blockIdx.y*64;
    int tid = threadIdx.x;
    int lr = tid>>4, lc = (tid&15)*4;
    #pragma unroll
    for (int p = 0; p < 4; p++) {
        float4 v = *(const float4*)&W[(size_t)(k0+lr+16*p)*N + n0 + lc];
        t[lr+16*p][lc]   = v.x; t[lr+16*p][lc+1] = v.y;
        t[lr+16*p][lc+2] = v.z; t[lr+16*p][lc+3] = v.w;
    }
    __syncthreads();
    int n = tid>>2, kb = (tid&3)*16;
    union U { _Float16 h[8]; uint4 u; } h0, h1, l0, l1;
    #pragma unroll
    for (int e = 0; e < 8; e++) {
        float x = t[kb+e][n];
        _Float16 hv = (_Float16)x;
        h0.h[e] = hv; l0.h[e] = (_Float16)(x - (float)hv);
    }
    #pragma unroll
    for (int e = 0; e < 8; e++) {
        float x = t[kb+8+e][n];
        _Float16 hv = (_Float16)x;
        h1.h[e] = hv; l1.h[e] = (_Float16)(x - (float)hv);
    }
    size_t ob = (size_t)(n0+n)*K + k0 + kb;
    *(uint4*)&OH[ob]   = h0.u;
    *(uint4*)&OH[ob+8] = h1.u;
    *(uint4*)&OL[ob]   = l0.u;
    *(uint4*)&OL[ob+8] = l1.u;
}

// ===================== MFMA fp16-split GEMM v3 (global_load_lds staging) ====
// All inputs pre-split halves. M fixed by grid.x*128, N by grid.y*128, K param.
// Staging keeps the COALESCED global pattern (4 consecutive lanes cover one
// contiguous 64B row segment) but XOR-permutes the 16B k-chunk WITHIN each
// row: slot = kchunk ^ ((row>>1)&3). global_load_lds writes LDS linearly
// (rule #21), so the LDS layout inherits the permutation; the fragment
// ds_read_b128 applies the same XOR and lands 2 lanes/bank (free).
__global__ __launch_bounds__(256) void gemm3_kernel(
    const _Float16* __restrict__ AhG, const _Float16* __restrict__ AlG, int lda,
    const _Float16* __restrict__ WtHb, const _Float16* __restrict__ WtLb,
    int ldw, long wz,
    float* __restrict__ C, _Float16* __restrict__ OHb, _Float16* __restrict__ OLb,
    int ldc, long oz,
    const _Float16* __restrict__ Rh, const _Float16* __restrict__ Rl, int ldr,
    const float* __restrict__ bias0, const float* __restrict__ bias1,
    const float* __restrict__ bias2,
    int K, int flags)
{
    __shared__ __align__(16) _Float16 Ah[128*32], Al[128*32];
    __shared__ __align__(16) _Float16 Bh[128*32], Bl[128*32];
    const int z = blockIdx.z;
    const _Float16* WtH = WtHb + (long)z*wz;
    const _Float16* WtL = WtLb + (long)z*wz;
    _Float16* oh = OHb ? OHb + (long)z*oz : (_Float16*)0;
    _Float16* ol = OLb ? OLb + (long)z*oz : (_Float16*)0;
    const float* bias = (z==0) ? bias0 : ((z==1) ? bias1 : bias2);
    const int tid = threadIdx.x, lane = tid&63, wid = tid>>6;
    const int wm = wid&1, wn = wid>>1;
    const int l15 = lane&15, quad = lane>>4;
    const int m0 = blockIdx.x*128, n0 = blockIdx.y*128;

    // staging assignment: wave 0->Ah, 1->Al, 2->Bh, 3->Bl
    const _Float16* gsrc; _Float16* lbuf; int ld_s; int r0;
    if (wid == 0)      { gsrc = AhG; lbuf = Ah; ld_s = lda; r0 = m0; }
    else if (wid == 1) { gsrc = AlG; lbuf = Al; ld_s = lda; r0 = m0; }
    else if (wid == 2) { gsrc = WtH; lbuf = Bh; ld_s = ldw; r0 = n0; }
    else               { gsrc = WtL; lbuf = Bl; ld_s = ldw; r0 = n0; }
    // coalesced rows (lane>>2) with per-row k-chunk XOR swizzle.
    const int kch = (lane&3) ^ ((lane>>3)&3);
    const _Float16* gbase = gsrc + (size_t)(r0 + (lane>>2))*ld_s + kch*8;

    // fragment-read slot: stored slot = quad ^ ((l15>>1)&3)
    const int slot = quad ^ ((l15>>1)&3);

    f32x4 acc[4][4];
    #pragma unroll
    for (int i = 0; i < 4; i++)
        #pragma unroll
        for (int j = 0; j < 4; j++)
            acc[i][j] = (f32x4){0.f,0.f,0.f,0.f};

    for (int k0 = 0; k0 < K; k0 += 32) {
        #pragma unroll
        for (int q = 0; q < 8; q++)
            gld16(gbase + (size_t)(q*16)*ld_s + k0, lbuf + q*512);
        __syncthreads();
        half8 afh[4], afl[4], bfh[4], bfl[4];
        #pragma unroll
        for (int i = 0; i < 4; i++) {
            int m = wm*64 + i*16 + l15;
            afh[i] = *(const half8*)&Ah[m*32 + slot*8];
            afl[i] = *(const half8*)&Al[m*32 + slot*8];
            int n = wn*64 + i*16 + l15;
            bfh[i] = *(const half8*)&Bh[n*32 + slot*8];
            bfl[i] = *(const half8*)&Bl[n*32 + slot*8];
        }
        #pragma unroll
        for (int i = 0; i < 4; i++)
            #pragma unroll
            for (int j = 0; j < 4; j++) {
                acc[i][j] = __builtin_amdgcn_mfma_f32_16x16x32_f16(afh[i], bfh[j], acc[i][j], 0,0,0);
                acc[i][j] = __builtin_amdgcn_mfma_f32_16x16x32_f16(afh[i], bfl[j], acc[i][j], 0,0,0);
                acc[i][j] = __builtin_amdgcn_mfma_f32_16x16x32_f16(afl[i], bfh[j], acc[i][j], 0,0,0);
            }
        __syncthreads();
    }
    // ---- epilogue: C/D layout col=lane&15, row=quad*4+reg ----
    #pragma unroll
    for (int i = 0; i < 4; i++)
        #pragma unroll
        for (int j = 0; j < 4; j++)
            #pragma unroll
            for (int r = 0; r < 4; r++) {
                int gm = m0 + wm*64 + i*16 + quad*4 + r;
                int gn = n0 + wn*64 + j*16 + l15;
                float v = acc[i][j][r];
                if (bias) v += bias[gn];
                size_t ox = (size_t)gm*ldc + gn;
                if (flags & GF_ADDRES) {
                    size_t rx = (size_t)gm*ldr + gn;
                    v += (float)Rh[rx] + (float)Rl[rx];
                }
                if (flags & GF_ACCH)
                    v += (float)oh[ox] + (float)ol[ox];
                if (flags & GF_RELU_OUT) v = fmaxf(v, 0.f);
                if (flags & GF_GELU_OUT) v = 0.5f*v*(1.0f + erff(v*0.70710678118654752f));
                if (oh) {
                    _Float16 hv = (_Float16)v;
                    oh[ox] = hv;
                    ol[ox] = (_Float16)(v - (float)hv);
                } else {
                    C[ox] = v;
                }
            }
}

// ===================== fp32 GEMM (small head GEMM, N=122) =====================
#define BM 64
#define BN 64
#define BK 16
__global__ __launch_bounds__(256) void gemm_kernel(
    const float* __restrict__ A, int lda,
    const float* __restrict__ W, int ldb,
    float* __restrict__ C, int ldc,
    const float* __restrict__ bias,
    int M, int N, int K)
{
    __shared__ __align__(16) float As[BK][BM+4];
    __shared__ __align__(16) float Bs[BK][BN+4];
    int tid = threadIdx.x;
    int tx = tid & 15, ty = tid >> 4;
    int m0 = blockIdx.x * BM;
    int n0 = blockIdx.y * BN;
    float acc[4][4] = {};
    for (int k0 = 0; k0 < K; k0 += BK) {
        #pragma unroll
        for (int r = 0; r < 4; r++) {
            int li = tid + 256*r;
            int m  = li >> 4;
            int kk = li & 15;
            int gm = m0 + m, gk = k0 + kk;
            As[kk][m] = (gm < M && gk < K) ? A[(size_t)gm*lda + gk] : 0.f;
        }
        #pragma unroll
        for (int r = 0; r < 4; r++) {
            int li = tid + 256*r;
            int kk = li >> 6;
            int n  = li & 63;
            int gk = k0 + kk, gn = n0 + n;
            Bs[kk][n] = (gk < K && gn < N) ? W[(size_t)gk*ldb + gn] : 0.f;
        }
        __syncthreads();
        #pragma unroll
        for (int kk = 0; kk < BK; kk++) {
            float4 a  = *(const float4*)&As[kk][ty*4];
            float4 bb = *(const float4*)&Bs[kk][tx*4];
            float av[4] = {a.x, a.y, a.z, a.w};
            float bv[4] = {bb.x, bb.y, bb.z, bb.w};
            #pragma unroll
            for (int i = 0; i < 4; i++)
                #pragma unroll
                for (int j = 0; j < 4; j++)
                    acc[i][j] += av[i] * bv[j];
        }
        __syncthreads();
    }
    #pragma unroll
    for (int i = 0; i < 4; i++) {
        int gm = m0 + ty*4 + i;
        if (gm >= M) continue;
        #pragma unroll
        for (int j = 0; j < 4; j++) {
            int gn = n0 + tx*4 + j;
            if (gn >= N) continue;
            float v = acc[i][j];
            if (bias) v += bias[gn];
            C[(size_t)gm*ldc + gn] = v;
        }
    }
}

// ===================== MFMA attention =====================
__device__ inline int scidx(int row, int col) {
    return row*128 + (((col>>2) ^ (row&7))<<2) + (col&3);
}
__global__ __launch_bounds__(256) void attn2_kernel(
    const _Float16* __restrict__ QhG, const _Float16* __restrict__ QlG,
    const _Float16* __restrict__ KhG, const _Float16* __restrict__ KlG,
    const _Float16* __restrict__ VhG, const _Float16* __restrict__ VlG,
    const int* __restrict__ amask,
    _Float16* __restrict__ Ch, _Float16* __restrict__ Cl)
{
    __shared__ __align__(16) char smem[65536];
    _Float16* Qh_s = (_Float16*)smem;            // [64][72]
    _Float16* Ql_s = Qh_s + 64*72;
    _Float16* Kh_s = Ql_s + 64*72;               // [128][72]
    _Float16* Kl_s = Kh_s + 128*72;
    float*    Sc   = (float*)smem;               // [64][128] swizzled (phase 2)
    _Float16* Vth  = (_Float16*)(smem + 32768);  // [64][128] swizzled
    _Float16* Vtl  = Vth + 64*128;

    int blk = blockIdx.x;
    int qh2 = blk & 1;
    int bh  = blk >> 1;
    int b = bh / NH_, hh = bh % NH_;
    const int tid = threadIdx.x, lane = tid&63, wid = tid>>6;
    const int l15 = lane&15, quad = lane>>4;
    const int qr = wid*16;
    size_t tokb = (size_t)b*S_*H_ + (size_t)hh*DH_;

    float nmask[8];
    #pragma unroll
    for (int j = 0; j < 8; j++)
        nmask[j] = (amask[b*S_ + j*16 + l15] > 0) ? 0.f : -1e9f;

    {
        int row = tid>>2, part = (tid&3)*16;
        size_t qg = tokb + (size_t)(qh2*64 + row)*H_ + part;
        *(uint4*)&Qh_s[row*72 + part] = *(const uint4*)(QhG + qg);
        *(uint4*)&Ql_s[row*72 + part] = *(const uint4*)(QlG + qg);
        #pragma unroll
        for (int p = 0; p < 2; p++) {
            int krow = row + p*64;
            size_t kg = tokb + (size_t)krow*H_ + part;
            *(uint4*)&Kh_s[krow*72 + part] = *(const uint4*)(KhG + kg);
            *(uint4*)&Kl_s[krow*72 + part] = *(const uint4*)(KlG + kg);
        }
    }
    __syncthreads();

    f32x4 acc1[8];
    #pragma unroll
    for (int j = 0; j < 8; j++) acc1[j] = (f32x4){0.f,0.f,0.f,0.f};
    half8 aqh[2], aql[2];
    #pragma unroll
    for (int kc = 0; kc < 2; kc++) {
        aqh[kc] = *(const half8*)&Qh_s[(qr + l15)*72 + kc*32 + quad*8];
        aql[kc] = *(const half8*)&Ql_s[(qr + l15)*72 + kc*32 + quad*8];
    }
    #pragma unroll
    for (int j = 0; j < 8; j++) {
        #pragma unroll
        for (int kc = 0; kc < 2; kc++) {
            half8 bkh = *(const half8*)&Kh_s[(j*16 + l15)*72 + kc*32 + quad*8];
            half8 bkl = *(const half8*)&Kl_s[(j*16 + l15)*72 + kc*32 + quad*8];
            acc1[j] = __builtin_amdgcn_mfma_f32_16x16x32_f16(aqh[kc], bkh, acc1[j], 0,0,0);
            acc1[j] = __builtin_amdgcn_mfma_f32_16x16x32_f16(aqh[kc], bkl, acc1[j], 0,0,0);
            acc1[j] = __builtin_amdgcn_mfma_f32_16x16x32_f16(aql[kc], bkh, acc1[j], 0,0,0);
        }
    }
    __syncthreads();

    #pragma unroll
    for (int j = 0; j < 8; j++)
        #pragma unroll
        for (int r = 0; r < 4; r++) {
            int row = qr + quad*4 + r;
            int col = j*16 + l15;
            Sc[scidx(row, col)] = acc1[j][r]*INV_SQRT_DH + nmask[j];
        }
    {
        int key = tid>>1, dh = (tid&1)*32;
        union V32 { _Float16 h[32]; uint4 u[4]; } bufh, bufl;
        #pragma unroll
        for (int e = 0; e < 4; e++) {
            bufh.u[e] = *(const uint4*)(VhG + tokb + (size_t)key*H_ + dh + e*8);
            bufl.u[e] = *(const uint4*)(VlG + tokb + (size_t)key*H_ + dh + e*8);
        }
        int kg = key>>3, kr = key&7;
        #pragma unroll
        for (int e = 0; e < 32; e++) {
            int d = dh + e;
            int pos = kg ^ (d & 7);
            Vth[d*128 + pos*8 + kr] = bufh.h[e];
            Vtl[d*128 + pos*8 + kr] = bufl.h[e];
        }
    }
    __syncthreads();

    {
        int row = tid>>2, part = (tid&3)*32;
        float mx = -INFINITY;
        #pragma unroll 8
        for (int e = 0; e < 32; e++)
            mx = fmaxf(mx, Sc[scidx(row, part+e)]);
        mx = fmaxf(mx, __shfl_xor(mx, 1));
        mx = fmaxf(mx, __shfl_xor(mx, 2));
        float s = 0.f;
        #pragma unroll 8
        for (int e = 0; e < 32; e++) {
            int idx = scidx(row, part+e);
            float ev = expf(Sc[idx] - mx);
            Sc[idx] = ev; s += ev;
        }
        s += __shfl_xor(s, 1);
        s += __shfl_xor(s, 2);
        float inv = 1.0f / s;
        #pragma unroll 8
        for (int e = 0; e < 32; e++)
            Sc[scidx(row, part+e)] *= inv;
    }
    __syncthreads();

    f32x4 acc2[4];
    #pragma unroll
    for (int jd = 0; jd < 4; jd++) acc2[jd] = (f32x4){0.f,0.f,0.f,0.f};
    #pragma unroll
    for (int kc = 0; kc < 4; kc++) {
        int q = qr + l15;
        int g16 = kc*8 + quad*2;
        float4 p0 = *(const float4*)&Sc[q*128 + ((g16   ^ (q&7))<<2)];
        float4 p1 = *(const float4*)&Sc[q*128 + (((g16+1) ^ (q&7))<<2)];
        float pv[8] = {p0.x,p0.y,p0.z,p0.w, p1.x,p1.y,p1.z,p1.w};
        union U { _Float16 h[8]; half8 v; } ph, pl;
        #pragma unroll
        for (int e = 0; e < 8; e++) {
            _Float16 hv = (_Float16)pv[e];
            ph.h[e] = hv; pl.h[e] = (_Float16)(pv[e] - (float)hv);
        }
        #pragma unroll
        for (int jd = 0; jd < 4; jd++) {
            int n = jd*16 + l15;
            int pos = (kc*4 + quad) ^ (n & 7);
            half8 vh = *(const half8*)&Vth[n*128 + pos*8];
            half8 vl = *(const half8*)&Vtl[n*128 + pos*8];
            acc2[jd] = __builtin_amdgcn_mfma_f32_16x16x32_f16(ph.v, vh, acc2[jd], 0,0,0);
            acc2[jd] = __builtin_amdgcn_mfma_f32_16x16x32_f16(ph.v, vl, acc2[jd], 0,0,0);
            acc2[jd] = __builtin_amdgcn_mfma_f32_16x16x32_f16(pl.v, vh, acc2[jd], 0,0,0);
        }
    }
    #pragma unroll
    for (int jd = 0; jd < 4; jd++)
        #pragma unroll
        for (int r = 0; r < 4; r++) {
            int row = qr + quad*4 + r;
            int token = b*S_ + qh2*64 + row;
            int d = jd*16 + l15;
            float v = acc2[jd][r];
            _Float16 hv = (_Float16)v;
            Ch[(size_t)token*H_ + hh*DH_ + d] = hv;
            Cl[(size_t)token*H_ + hh*DH_ + d] = (_Float16)(v - (float)hv);
        }
}

// ===================== intent head =====================
__global__ __launch_bounds__(64) void intent_kernel(
    const _Float16* __restrict__ Xh, const _Float16* __restrict__ Xl,
    const float* __restrict__ iW1,
    const float* __restrict__ ib1, const float* __restrict__ iW2,
    const float* __restrict__ ib2, const int* __restrict__ tgt,
    float* __restrict__ iloss, float* __restrict__ outf)
{
    int b = blockIdx.x; int j = threadIdx.x;
    __shared__ float h1[64];
    __shared__ float lg[32];
    const _Float16* x0h = Xh + (size_t)b*S_*H_;
    const _Float16* x0l = Xl + (size_t)b*S_*H_;
    float acc = ib1[j];
    for (int h = 0; h < H_; h++) {
        float x = (float)x0h[h] + (float)x0l[h];
        acc += fmaxf(x, 0.f) * iW1[(size_t)h*64 + j];
    }
    h1[j] = fmaxf(acc, 0.f);
    __syncthreads();
    if (j < INTENT_) {
        float l = ib2[j];
        for (int k = 0; k < 64; k++) l += h1[k]*iW2[k*INTENT_ + j];
        lg[j] = l;
    }
    __syncthreads();
    if (j == 0) {
        float mx = -INFINITY; int bi = 0;
        for (int c = 0; c < INTENT_; c++) if (lg[c] > mx) { mx = lg[c]; bi = c; }
        float sm = 0.f;
        for (int c = 0; c < INTENT_; c++) sm += expf(lg[c]-mx);
        float lse = mx + logf(sm);
        iloss[b] = lse - lg[tgt[b]];
        outf[1 + (size_t)NT_ + b] = (float)bi;
    }
}

// ===================== fused CRF-llh + Viterbi (512 thr, float4 dot) =======
// grid (64, 2): y=0 -> CRF llh ; y=1 -> Viterbi.
// 512 threads: j = tid>>2 (tag), p = tid&3 covers CONTIGUOUS i-range
// [32p, 32p+32). tT[j][i] stride VST=124 (cols 122,123 zero-padded).
// Each thread does 8 unrolled ds_read_b128 per step (was ~31 scalar b32)
// -> 4x fewer LDS instructions on the access-count-bound scan.
// Bank math: word addr = 124j+32p+4e -> window 4(e-j) mod 32 -> 8 lanes per
// 4-bank window, uniform (b128 minimum). p=3's e=7 read touches words
// 124..127 of the row = next row's first words (finite); its products are
// zero-weighted (llh: eal[124..127]=0) or -3e38-dominated (viterbi).
// alpha in registers + parity double-buffer exchange -> ONE barrier/step.
// Deferred-subtractor logsumexp (exact math, any X).
#define VST 124
__global__ __launch_bounds__(512) void crf_vit_kernel(
    const float* __restrict__ E_, const int* __restrict__ tags,
    const int* __restrict__ mask, const float* __restrict__ start,
    const float* __restrict__ endv, const float* __restrict__ trans,
    float* __restrict__ crfv, unsigned char* __restrict__ BPg,
    float* __restrict__ outf)
{
    __shared__ __align__(16) float tT[TAGS_*VST];   // 60,512 B [j][i]
    __shared__ __align__(16) float eal[2][128];     // parity exchange buffer
    __shared__ float mxw[2][8];                     // per-wave max, by parity
    __shared__ float mxbuf[16];
    __shared__ int lastt;
    int b = blockIdx.x;
    int mode = blockIdx.y;
    int tid = threadIdx.x, lane = tid&63, wid = tid>>6;
    int j = tid>>2, p = tid&3;
    bool vj = (j < TAGS_);
    const float* E = E_ + (size_t)b*S_*TAGS_;

    // load tT[j][i]: exp-domain for llh, raw for viterbi; pad cols = 0
    for (int o = tid; o < TAGS_*VST; o += 512) {
        int jj = o / VST, i = o - jj*VST;
        float v;
        if (i < TAGS_) {
            float tv = trans[i*TAGS_ + jj];
            v = mode ? tv : expf(tv);
        } else v = 0.f;
        tT[o] = v;
    }
    float aj = vj ? (start[j] + E[j]) : -3e38f;
    const int ibase = 32*p;

    if (mode == 0) {
        // ---------- CRF log-likelihood ----------
        {
            float wm = wave_max(aj);
            if (lane == 0) mxw[0][wid] = wm;
        }
        __syncthreads();                    // also covers tT load
        float gm = mxw[0][0];
        #pragma unroll
        for (int w = 1; w < 8; w++) gm = fmaxf(gm, mxw[0][w]);
        float xc = gm;                      // subtractor of eal[cur]
        if (p == 0) eal[0][j] = vj ? expf(aj - xc) : 0.f;
        __syncthreads();
        int cur = 0;
        float eC = vj ? E[(size_t)TAGS_ + j] : 0.f;   // E[1][j]
        int   mC = mask[b*S_ + 1];
        for (int t = 1; t < S_; t++) {
            float e = eC; int m_t = mC;
            if (t + 1 < S_) {               // prefetch next step
                eC = vj ? E[(size_t)(t+1)*TAGS_ + j] : 0.f;
                mC = mask[b*S_ + t + 1];
            }
            float s = 0.f;
            if (vj) {
                const float4* tr = (const float4*)&tT[j*VST + ibase];
                const float4* eb = (const float4*)&eal[cur][ibase];
                float s0 = 0.f, s1 = 0.f, s2 = 0.f, s3 = 0.f;
                #pragma unroll
                for (int q = 0; q < 8; q++) {
                    float4 av = eb[q];
                    float4 tv = tr[q];
                    s0 += av.x*tv.x; s1 += av.y*tv.y;
                    s2 += av.z*tv.z; s3 += av.w*tv.w;
                }
                s = (s0 + s1) + (s2 + s3);
            }
            s += __shfl_xor(s, 1);
            s += __shfl_xor(s, 2);
            if (m_t && vj) aj = xc + logf(s) + e;
            int nxt = cur ^ 1;
            float xn = gm;                  // deferred subtractor (exact math)
            if (p == 0) eal[nxt][j] = vj ? expf(aj - xn) : 0.f;
            float wm2 = wave_max(aj);
            if (lane == 0) mxw[nxt][wid] = wm2;
            __syncthreads();                // ONE barrier per step
            float nm = mxw[nxt][0];
            #pragma unroll
            for (int w = 1; w < 8; w++) nm = fmaxf(nm, mxw[nxt][w]);
            gm = nm;
            xc = xn;
            cur = nxt;
        }
        // dump alpha to LDS for the final reduction (reuse eal[0])
        if (p == 0) eal[0][j] = aj;
        // numerator over timesteps (threads 0..127 handle t)
        float term = 0.f, mkf = 0.f;
        if (tid < S_) {
            int mk = mask[b*S_ + tid]; mkf = (float)mk;
            if (tid >= 1 && mk) {
                int tg = tags[b*S_ + tid], tgp = tags[b*S_ + tid - 1];
                term = trans[tgp*TAGS_ + tg] + E[(size_t)tid*TAGS_ + tg];
            }
        }
        if (wid < 2) {
            float ts = wave_sum(term);
            float ms = wave_sum(mkf);
            if (lane == 0) { mxbuf[2+wid] = ts; mxbuf[4+wid] = ms; }
        }
        __syncthreads();
        if (wid == 0) {
            const float* alp = &eal[0][0];
            float v1 = (lane < TAGS_) ? alp[lane] + endv[lane] : -3e38f;
            float v2 = (lane+64 < TAGS_) ? alp[lane+64] + endv[lane+64] : -3e38f;
            float m = wave_max(fmaxf(v1, v2));
            float sd = ((lane < TAGS_) ? expf(v1 - m) : 0.f)
                     + ((lane+64 < TAGS_) ? expf(v2 - m) : 0.f);
            sd = wave_sum(sd);
            if (lane == 0) {
                float denom = m + logf(sd);
                float numsum = mxbuf[2] + mxbuf[3];
                int msum = (int)(mxbuf[4] + mxbuf[5]);
                int tag0 = tags[b*S_];
                int last_tag = tags[b*S_ + (msum - 1)];
                float num = start[tag0] + E[tag0] + numsum + endv[last_tag];
                crfv[b] = num - denom;
            }
        }
    } else {
        // ---------- Viterbi ----------
        if (p == 0) eal[0][j] = aj;         // -3e38 for invalid j
        __syncthreads();                    // covers tT load + alpha0
        int cur = 0;
        size_t bpb = (size_t)b*(S_-1)*TAGS_;
        float eC = vj ? E[(size_t)TAGS_ + j] : 0.f;
        int   mC = mask[b*S_ + 1];
        for (int t = 1; t < S_; t++) {
            float ee = eC; int m_t = mC;
            if (t + 1 < S_) {
                eC = vj ? E[(size_t)(t+1)*TAGS_ + j] : 0.f;
                mC = mask[b*S_ + t + 1];
            }
            float best = -3e38f; int bi = 0;
            if (vj) {
                const float4* tr = (const float4*)&tT[j*VST + ibase];
                const float4* ab = (const float4*)&eal[cur][ibase];
                float b0 = -3e38f, b1 = -3e38f, b2 = -3e38f, b3 = -3e38f;
                int i0 = ibase, i1 = ibase+1, i2 = ibase+2, i3 = ibase+3;
                #pragma unroll
                for (int q = 0; q < 8; q++) {
                    float4 av = ab[q];
                    float4 tv = tr[q];
                    float c;
                    c = av.x + tv.x; if (c > b0) { b0 = c; i0 = ibase+4*q; }
                    c = av.y + tv.y; if (c > b1) { b1 = c; i1 = ibase+4*q+1; }
                    c = av.z + tv.z; if (c > b2) { b2 = c; i2 = ibase+4*q+2; }
                    c = av.w + tv.w; if (c > b3) { b3 = c; i3 = ibase+4*q+3; }
                }
                best = b0; bi = i0;
                if (b1 > best || (b1 == best && i1 < bi)) { best = b1; bi = i1; }
                if (b2 > best || (b2 == best && i2 < bi)) { best = b2; bi = i2; }
                if (b3 > best || (b3 == best && i3 < bi)) { best = b3; bi = i3; }
            }
            {
                float ov = __shfl_xor(best, 1); int oi = __shfl_xor(bi, 1);
                if (ov > best || (ov == best && oi < bi)) { best = ov; bi = oi; }
                ov = __shfl_xor(best, 2); oi = __shfl_xor(bi, 2);
                if (ov > best || (ov == best && oi < bi)) { best = ov; bi = oi; }
            }
            float nv; int nb;
            if (m_t) { nv = best + ee; nb = bi; }
            else     { nv = aj; nb = j; }
            int nxt = cur ^ 1;
            if (vj) aj = nv;
            if (p == 0) eal[nxt][j] = aj;   // -3e38 for invalid j
            if (vj && p == 0)
                BPg[bpb + (size_t)(t-1)*TAGS_ + j] = (unsigned char)nb;
            __syncthreads();                // ONE barrier per step
            cur = nxt;
        }
        // dump alpha for final argmax
        if (p == 0) eal[0][j] = aj;
        __syncthreads();
        if (wid == 0) {
            const float* alp = &eal[0][0];
            float v; int idx;
            float v1 = (lane < TAGS_) ? alp[lane] + endv[lane] : -3e38f;
            float v2 = (lane+64 < TAGS_) ? alp[lane+64] + endv[lane+64] : -3e38f;
            if (v2 > v1) { v = v2; idx = lane+64; } else { v = v1; idx = lane; }
            #pragma unroll
            for (int d = 32; d; d >>= 1) {
                float ov = __shfl_xor(v, d); int oi = __shfl_xor(idx, d);
                if (ov > v || (ov == v && oi < idx)) { v = ov; idx = oi; }
            }
            if (lane == 0) lastt = idx;
        }
        __syncthreads();
        unsigned char* bpl = (unsigned char*)tT;
        for (int o = tid; o < (S_-1)*TAGS_; o += 512)
            bpl[o] = BPg[bpb + o];
        __syncthreads();
        if (tid == 0) {
            int tag = lastt;
            outf[1 + (size_t)b*S_ + (S_-1)] = (float)tag;
            for (int t = S_-1; t >= 1; t--) {
                tag = bpl[(t-1)*TAGS_ + tag];
                outf[1 + (size_t)b*S_ + (t-1)] = (float)tag;
            }
        }
    }
}

// ===================== final joint loss =====================
__global__ void combine_kernel(const float* __restrict__ iloss,
                               const float* __restrict__ crfv,
                               const float* __restrict__ lv,
                               float* __restrict__ outf)
{
    if (threadIdx.x == 0 && blockIdx.x == 0) {
        float si = 0.f, sc = 0.f;
        for (int b = 0; b < B_; b++) { si += iloss[b]; sc += crfv[b]; }
        float p1 = expf(-lv[0]), p2 = expf(-lv[1]);
        float slots_loss = -sc;
        outf[0] = p1*si + (float)B_*lv[0] + p2*slots_loss + lv[1];
    }
}

// ===================== host launch =====================
extern "C" void kernel_launch(void* const* d_in, const int* in_sizes, int n_in,
                              void* d_out, int out_size, void* d_ws, size_t ws_size,
                              hipStream_t stream) {
    const int*   ids   = (const int*)  d_in[0];
    const int*   amask = (const int*)  d_in[1];
    const int*   itgt  = (const int*)  d_in[2];
    const int*   stgt  = (const int*)  d_in[3];
    const int*   smask = (const int*)  d_in[4];
    const float* we    = (const float*)d_in[5];
    const float* pe    = (const float*)d_in[6];
    const float* embs  = (const float*)d_in[7];
    const float* embb  = (const float*)d_in[8];
    const float* Wq    = (const float*)d_in[9];
    const float* bq    = (const float*)d_in[10];
    const float* Wk    = (const float*)d_in[11];
    const float* bk    = (const float*)d_in[12];
    const float* Wv    = (const float*)d_in[13];
    const float* bv    = (const float*)d_in[14];
    const float* Wo    = (const float*)d_in[15];
    const float* bo    = (const float*)d_in[16];
    const float* sas   = (const float*)d_in[17];
    const float* sab   = (const float*)d_in[18];
    const float* W1f   = (const float*)d_in[19];
    const float* b1f   = (const float*)d_in[20];
    const float* W2f   = (const float*)d_in[21];
    const float* b2f   = (const float*)d_in[22];
    const float* ols   = (const float*)d_in[23];
    const float* olb   = (const float*)d_in[24];
    const float* iW1   = (const float*)d_in[25];
    const float* ib1   = (const float*)d_in[26];
    const float* iW2   = (const float*)d_in[27];
    const float* ib2   = (const float*)d_in[28];
    const float* sW1   = (const float*)d_in[29];
    const float* sb1   = (const float*)d_in[30];
    const float* sW2   = (const float*)d_in[31];
    const float* sb2   = (const float*)d_in[32];
    const float* crfs  = (const float*)d_in[33];
    const float* crfe  = (const float*)d_in[34];
    const float* crft  = (const float*)d_in[35];
    const float* lv    = (const float*)d_in[36];

    float* outf = (float*)d_out;
    float* wsf  = (float*)d_ws;
    const long NTHh = (long)NT_ * H_;        // 6,291,456 (halves per tensor)
    const long NBf  = NTHh;                  // floats per fp32-equivalent tensor
    const long HH   = (long)H_ * H_;         // 589,824

    // layout (floats): [XhXl: NBf][P: 3*NBf][ChCl: NBf][WA][WB1][WB2][misc]
    _Float16* Xh = (_Float16*)wsf;
    _Float16* Xl = Xh + NTHh;
    float*    Pf = wsf + NBf;
    _Float16* Ph = (_Float16*)Pf;
    _Float16 *Qh = Ph, *Ql = Ph + NTHh, *Kh = Ph + 2*NTHh, *Kl = Ph + 3*NTHh,
             *Vh = Ph + 4*NTHh, *Vl = Ph + 5*NTHh;
    _Float16 *Sh = Ph, *Sl = Ph + NTHh;                 // sum halves (reuse Q slot)
    _Float16* Fh = (_Float16*)(wsf + 2*NBf);            // FF intermediate hi
    _Float16* Fl = (_Float16*)(wsf + 3*NBf);            // FF intermediate lo
    _Float16* Ch = (_Float16*)(wsf + 4*NBf);
    _Float16* Cl = Ch + NTHh;
    const long wa0 = 5*NBf;
    _Float16* WAh = (_Float16*)(wsf + wa0);             // 8*HH halves (QKVO hi+lo)
    _Float16* WAl = WAh + 4*HH;
    const long wb1 = wa0 + 2359296;
    _Float16* WB1h = (_Float16*)(wsf + wb1);
    _Float16* WB1l = WB1h + 2359296;
    const long wb2 = wb1 + 2359296;
    _Float16* WB2h = (_Float16*)(wsf + wb2);
    _Float16* WB2l = WB2h + 2359296;
    float* iloss = wsf + wb2 + 2359296;
    float* crfv  = iloss + 64;
    // heads scratch in P region (free after encoder)
    float* H1 = Pf;                                     // 8192*256
    float* logits = Pf + 2097152;                       // 8192*122
    unsigned char* BPg = (unsigned char*)(Pf + 2097152 + 999424);

    auto g3 = [&](int gy, int gz,
                  const _Float16* A_h, const _Float16* A_l, int lda,
                  const _Float16* WtH, const _Float16* WtL, int ldw, long wz,
                  float* C, _Float16* OH, _Float16* OL, int ldc, long oz,
                  const _Float16* Rh, const _Float16* Rl,
                  const float* b0, const float* b1_, const float* b2_,
                  int K, int flags) {
        hipLaunchKernelGGL(gemm3_kernel, dim3(NT_/128, gy, gz), dim3(256), 0, stream,
                           A_h, A_l, lda, WtH, WtL, ldw, wz,
                           C, OH, OL, ldc, oz, Rh, Rl, H_, b0, b1_, b2_, K, flags);
    };

    hipLaunchKernelGGL(embed_ln_kernel, dim3(NT_), dim3(256), 0, stream,
                       ids, we, pe, embs, embb, Xh, Xl);

    for (int i = 0; i < L_; i++) {
        const long WO = (long)i*HH;
        // QKV+O weights -> WA (z=4)
        hipLaunchKernelGGL(wconv_kernel, dim3(12,12,4), dim3(256), 0, stream,
                           Wq+WO, Wk+WO, Wv+WO, Wo+WO, H_, H_, WAh, WAl, HH);
        // QKV (z=3)
        g3(6, 3, Xh, Xl, H_, WAh, WAl, H_, HH,
           nullptr, Ph, Ph+NTHh, H_, 2*NTHh, nullptr, nullptr,
           bq+i*H_, bk+i*H_, bv+i*H_, H_, 0);
        // attention
        hipLaunchKernelGGL(attn2_kernel, dim3(B_*NH_*2), dim3(256), 0, stream,
                           Qh, Ql, Kh, Kl, Vh, Vl, amask, Ch, Cl);
        // O-proj + residual -> sum halves (Sh/Sl)
        g3(6, 1, Ch, Cl, H_, WAh+3*HH, WAl+3*HH, H_, 0,
           nullptr, Sh, Sl, H_, 0, Xh, Xl,
           bo+i*H_, nullptr, nullptr, H_, GF_ADDRES);
        hipLaunchKernelGGL(ln2_kernel, dim3(NT_), dim3(384), 0, stream,
                           Sh, Sl, sas+i*H_, sab+i*H_, Xh, Xl,
                           (_Float16*)nullptr, (_Float16*)nullptr);
        // FF weights
        hipLaunchKernelGGL(wconv_kernel, dim3(12,48,1), dim3(256), 0, stream,
                           W1f+(long)i*H_*FF_, nullptr, nullptr, nullptr,
                           H_, FF_, WB1h, WB1l, 0);
        hipLaunchKernelGGL(wconv_kernel, dim3(48,12,1), dim3(256), 0, stream,
                           W2f+(long)i*FF_*H_, nullptr, nullptr, nullptr,
                           FF_, H_, WB2h, WB2l, 0);
        for (int c = 0; c < 2; c++) {
            const int CW = FF_/2;  // 1536
            g3(12, 1, Xh, Xl, H_,
               WB1h+(long)c*CW*H_, WB1l+(long)c*CW*H_, H_, 0,
               nullptr, Fh, Fl, CW, 0, nullptr, nullptr,
               b1f+(long)i*FF_+c*CW, nullptr, nullptr, H_, GF_GELU_OUT);
            g3(6, 1, Fh, Fl, CW,
               WB2h+(long)c*CW, WB2l+(long)c*CW, FF_, 0,
               nullptr, Sh, Sl, H_, 0, Xh, Xl,
               (c==0) ? (b2f+i*H_) : nullptr, nullptr, nullptr,
               CW, (c==0) ? GF_ADDRES : GF_ACCH);
        }
        hipLaunchKernelGGL(ln2_kernel, dim3(NT_), dim3(384), 0, stream,
                           Sh, Sl, ols+i*H_, olb+i*H_, Xh, Xl,
                           (i==L_-1) ? Ch : (_Float16*)nullptr,
                           (i==L_-1) ? Cl : (_Float16*)nullptr);
    }

    hipLaunchKernelGGL(intent_kernel, dim3(B_), dim3(64), 0, stream,
                       Xh, Xl, iW1, ib1, iW2, ib2, itgt, iloss, outf);

    // slots head: H1 = relu(relu(x)@sW1 + sb1)  (relu(x) halves are in Ch/Cl)
    hipLaunchKernelGGL(wconv_kernel, dim3(12,4,1), dim3(256), 0, stream,
                       sW1, nullptr, nullptr, nullptr, H_, 256,
                       WAh, WAh + (long)256*H_, 0);
    g3(2, 1, Ch, Cl, H_, WAh, WAh + (long)256*H_, H_, 0,
       H1, nullptr, nullptr, 256, 0, nullptr, nullptr,
       sb1, nullptr, nullptr, H_, GF_RELU_OUT);
    hipLaunchKernelGGL(gemm_kernel, dim3(NT_/BM, 2), dim3(256), 0, stream,
                       H1, 256, sW2, TAGS_, logits, TAGS_, sb2, NT_, TAGS_, 256);

    hipLaunchKernelGGL(crf_vit_kernel, dim3(B_, 2), dim3(512), 0, stream,
                       logits, stgt, smask, crfs, crfe, crft, crfv, BPg, outf);

    hipLaunchKernelGGL(combine_kernel, dim3(1), dim3(64), 0, stream,
                       iloss, crfv, lv, outf);
}

// Round 7
// 4256.828 us; speedup vs baseline: 1.1915x; 1.1043x over previous
//
#include <hip/hip_runtime.h>
#include <math.h>
#include <stdint.h>

// ---- problem constants ----
#define B_      64
#define S_      128
#define H_      768
#define L_      6
#define NH_     12
#define DH_     64
#define FF_     3072
#define INTENT_ 22
#define TAGS_   122
#define NT_     (B_*S_)          // 8192 tokens
#define LN_EPS  1e-12f
#define INV_SQRT_DH 0.125f

#define GF_RELU_OUT 2
#define GF_GELU_OUT 4
#define GF_ADDRES   16   // add residual from Rh/Rl halves
#define GF_ACCH     32   // accumulate from current OH/OL contents

typedef _Float16 half8 __attribute__((ext_vector_type(8)));
typedef float    f32x4 __attribute__((ext_vector_type(4)));

// ===================== async global->LDS 16B =====================
__device__ __forceinline__ void gld16(const _Float16* g, _Float16* l) {
    __builtin_amdgcn_global_load_lds(
        (const __attribute__((address_space(1))) unsigned int*)(uintptr_t)g,
        (__attribute__((address_space(3))) unsigned int*)(unsigned int)(uintptr_t)l,
        16, 0, 0);
}

__device__ inline float wave_max(float v){
    #pragma unroll
    for (int d = 32; d; d >>= 1) v = fmaxf(v, __shfl_xor(v, d));
    return v;
}
__device__ inline float wave_sum(float v){
    #pragma unroll
    for (int d = 32; d; d >>= 1) v += __shfl_xor(v, d);
    return v;
}

// ===================== embedding + LN -> split halves =====================
// 256 threads = 4 waves; shuffle reduction, 2 barriers total.
__global__ __launch_bounds__(256) void embed_ln_kernel(
    const int* __restrict__ ids, const float* __restrict__ we,
    const float* __restrict__ pe, const float* __restrict__ gs,
    const float* __restrict__ gb, _Float16* __restrict__ Xh,
    _Float16* __restrict__ Xl)
{
    __shared__ float red[16];
    int bs = blockIdx.x;
    int sq = bs % S_;
    int id = ids[bs];
    int tid = threadIdx.x;
    int lane = tid & 63, wid = tid >> 6;
    const float* wrow = we + (size_t)id * H_;
    const float* prow = pe + (size_t)sq * H_;
    float z[3];
    #pragma unroll
    for (int r = 0; r < 3; r++) {
        int h = tid + 256*r;
        z[r] = wrow[h] + prow[h];
    }
    float s1 = wave_sum(z[0]+z[1]+z[2]);
    if (lane == 0) red[wid] = s1;
    __syncthreads();
    float m = (red[0]+red[1]+red[2]+red[3]) * (1.0f/H_);
    float vs = 0.f;
    #pragma unroll
    for (int r = 0; r < 3; r++) { float d = z[r]-m; vs += d*d; }
    float s2 = wave_sum(vs);
    if (lane == 0) red[8+wid] = s2;
    __syncthreads();
    float rstd = 1.0f / sqrtf((red[8]+red[9]+red[10]+red[11])*(1.0f/H_) + LN_EPS);
    #pragma unroll
    for (int r = 0; r < 3; r++) {
        int h = tid + 256*r;
        float val = (z[r]-m)*rstd*gs[h] + gb[h];
        _Float16 hv = (_Float16)val;
        Xh[(size_t)bs*H_ + h] = hv;
        Xl[(size_t)bs*H_ + h] = (_Float16)(val - (float)hv);
    }
}

// ===================== LN over sum-halves -> split halves (+relu copy) ====
// 384 threads = 6 waves; shuffle reduction, 2 barriers total.
__global__ __launch_bounds__(384) void ln2_kernel(
    const _Float16* __restrict__ Sh, const _Float16* __restrict__ Sl,
    const float* __restrict__ gs, const float* __restrict__ gb,
    _Float16* __restrict__ Xh, _Float16* __restrict__ Xl,
    _Float16* __restrict__ Rh, _Float16* __restrict__ Rl)
{
    __shared__ float red[16];
    int bs = blockIdx.x, tid = threadIdx.x;
    int lane = tid & 63, wid = tid >> 6;
    size_t base = (size_t)bs*H_ + tid*2;
    union UU { _Float16 h[2]; unsigned u; };
    UU uh, ul;
    uh.u = *(const unsigned*)(Sh + base);
    ul.u = *(const unsigned*)(Sl + base);
    float z0 = (float)uh.h[0] + (float)ul.h[0];
    float z1 = (float)uh.h[1] + (float)ul.h[1];
    float s1 = wave_sum(z0 + z1);
    if (lane == 0) red[wid] = s1;
    __syncthreads();
    float m = (red[0]+red[1]+red[2]+red[3]+red[4]+red[5]) * (1.0f/H_);
    float d0 = z0-m, d1 = z1-m;
    float s2 = wave_sum(d0*d0 + d1*d1);
    if (lane == 0) red[8+wid] = s2;
    __syncthreads();
    float var = (red[8]+red[9]+red[10]+red[11]+red[12]+red[13]) * (1.0f/H_);
    float rstd = 1.0f / sqrtf(var + LN_EPS);
    float2 gv = *(const float2*)(gs + tid*2);
    float2 bv = *(const float2*)(gb + tid*2);
    float v0 = d0*rstd*gv.x + bv.x;
    float v1 = d1*rstd*gv.y + bv.y;
    UU oh, ol;
    oh.h[0] = (_Float16)v0; ol.h[0] = (_Float16)(v0 - (float)oh.h[0]);
    oh.h[1] = (_Float16)v1; ol.h[1] = (_Float16)(v1 - (float)oh.h[1]);
    *(unsigned*)(Xh + base) = oh.u;
    *(unsigned*)(Xl + base) = ol.u;
    if (Rh) {
        float r0 = fmaxf(v0, 0.f), r1 = fmaxf(v1, 0.f);
        UU rh, rl;
        rh.h[0] = (_Float16)r0; rl.h[0] = (_Float16)(r0 - (float)rh.h[0]);
        rh.h[1] = (_Float16)r1; rl.h[1] = (_Float16)(r1 - (float)rh.h[1]);
        *(unsigned*)(Rh + base) = rh.u;
        *(unsigned*)(Rl + base) = rl.u;
    }
}

// ===================== weight transpose + fp16 hi/lo split =====================
// W [K][N] fp32 row-major -> Wt hi/lo [N][K] halves. grid (K/64, N/64, nz)
__global__ __launch_bounds__(256) void wconv_kernel(
    const float* __restrict__ W0, const float* __restrict__ W1,
    const float* __restrict__ W2, const float* __restrict__ W3,
    int K, int N, _Float16* __restrict__ OH, _Float16* __restrict__ OL, long zoff)
{
    __shared__ float t[64][65];
    int z = blockIdx.z;
    const float* W = (z==0) ? W0 : ((z==1) ? W1 : ((z==2) ? W2 : W3));
    OH += (long)z*zoff; OL += (long)z*zoff;
    int k0 = blockIdx.x*64, n0 = blockIdx.y*64;
    int tid = threadIdx.x;
    int lr = tid>>4, lc = (tid&15)*4;
    #pragma unroll
    for (int p = 0; p < 4; p++) {
        float4 v = *(const float4*)&W[(size_t)(k0+lr+16*p)*N + n0 + lc];
        t[lr+16*p][lc]   = v.x; t[lr+16*p][lc+1] = v.y;
        t[lr+16*p][lc+2] = v.z; t[lr+16*p][lc+3] = v.w;
    }
    __syncthreads();
    int n = tid>>2, kb = (tid&3)*16;
    union U { _Float16 h[8]; uint4 u; } h0, h1, l0, l1;
    #pragma unroll
    for (int e = 0; e < 8; e++) {
        float x = t[kb+e][n];
        _Float16 hv = (_Float16)x;
        h0.h[e] = hv; l0.h[e] = (_Float16)(x - (float)hv);
    }
    #pragma unroll
    for (int e = 0; e < 8; e++) {
        float x = t[kb+8+e][n];
        _Float16 hv = (_Float16)x;
        h1.h[e] = hv; l1.h[e] = (_Float16)(x - (float)hv);
    }
    size_t ob = (size_t)(n0+n)*K + k0 + kb;
    *(uint4*)&OH[ob]   = h0.u;
    *(uint4*)&OH[ob+8] = h1.u;
    *(uint4*)&OL[ob]   = l0.u;
    *(uint4*)&OL[ob+8] = l1.u;
}

// ===================== MFMA fp16-split GEMM v3 (global_load_lds staging) ====
// All inputs pre-split halves. M fixed by grid.x*128, N by grid.y*BN, K param.
// Templated on BN (128 or 64): BN=64 doubles the grid for N=768 GEMMs
// (O-proj/FF2: 384 -> 768 blocks = 3 blocks/CU) so the vmcnt(0)-drain stall
// of the 2-barrier structure is hidden by co-resident waves (m114 regime).
// Staging keeps the COALESCED global pattern (4 consecutive lanes cover one
// contiguous 64B row segment) but XOR-permutes the 16B k-chunk WITHIN each
// row: slot = kchunk ^ ((row>>1)&3) (invariant under row+16q). The fragment
// ds_read_b128 applies the same XOR and lands 2 lanes/bank (free).
template<int BN>
__global__ __launch_bounds__(256) void gemm3_kernel(
    const _Float16* __restrict__ AhG, const _Float16* __restrict__ AlG, int lda,
    const _Float16* __restrict__ WtHb, const _Float16* __restrict__ WtLb,
    int ldw, long wz,
    float* __restrict__ C, _Float16* __restrict__ OHb, _Float16* __restrict__ OLb,
    int ldc, long oz,
    const _Float16* __restrict__ Rh, const _Float16* __restrict__ Rl, int ldr,
    const float* __restrict__ bias0, const float* __restrict__ bias1,
    const float* __restrict__ bias2,
    int K, int flags)
{
    constexpr int NSPAN = BN/2;     // per-wave N span
    constexpr int JCNT  = NSPAN/16; // fragments per wave in N
    constexpr int QB    = BN/16;    // staging iterations for B waves
    __shared__ __align__(16) _Float16 Ah[128*32], Al[128*32];
    __shared__ __align__(16) _Float16 Bh[BN*32], Bl[BN*32];
    const int z = blockIdx.z;
    const _Float16* WtH = WtHb + (long)z*wz;
    const _Float16* WtL = WtLb + (long)z*wz;
    _Float16* oh = OHb ? OHb + (long)z*oz : (_Float16*)0;
    _Float16* ol = OLb ? OLb + (long)z*oz : (_Float16*)0;
    const float* bias = (z==0) ? bias0 : ((z==1) ? bias1 : bias2);
    const int tid = threadIdx.x, lane = tid&63, wid = tid>>6;
    const int wm = wid&1, wn = wid>>1;
    const int l15 = lane&15, quad = lane>>4;
    const int m0 = blockIdx.x*128, n0 = blockIdx.y*BN;

    // staging assignment: wave 0->Ah, 1->Al, 2->Bh, 3->Bl
    const _Float16* gsrc; _Float16* lbuf; int ld_s; int r0;
    if (wid == 0)      { gsrc = AhG; lbuf = Ah; ld_s = lda; r0 = m0; }
    else if (wid == 1) { gsrc = AlG; lbuf = Al; ld_s = lda; r0 = m0; }
    else if (wid == 2) { gsrc = WtH; lbuf = Bh; ld_s = ldw; r0 = n0; }
    else               { gsrc = WtL; lbuf = Bl; ld_s = ldw; r0 = n0; }
    // coalesced rows (lane>>2) with per-row k-chunk XOR swizzle.
    const int kch = (lane&3) ^ ((lane>>3)&3);
    const _Float16* gbase = gsrc + (size_t)(r0 + (lane>>2))*ld_s + kch*8;

    // fragment-read slot: stored slot = quad ^ ((l15>>1)&3)
    const int slot = quad ^ ((l15>>1)&3);

    f32x4 acc[4][JCNT];
    #pragma unroll
    for (int i = 0; i < 4; i++)
        #pragma unroll
        for (int j = 0; j < JCNT; j++)
            acc[i][j] = (f32x4){0.f,0.f,0.f,0.f};

    for (int k0 = 0; k0 < K; k0 += 32) {
        if (wid < 2) {
            #pragma unroll
            for (int q = 0; q < 8; q++)
                gld16(gbase + (size_t)(q*16)*ld_s + k0, lbuf + q*512);
        } else {
            #pragma unroll
            for (int q = 0; q < QB; q++)
                gld16(gbase + (size_t)(q*16)*ld_s + k0, lbuf + q*512);
        }
        __syncthreads();
        half8 afh[4], afl[4], bfh[JCNT], bfl[JCNT];
        #pragma unroll
        for (int i = 0; i < 4; i++) {
            int m = wm*64 + i*16 + l15;
            afh[i] = *(const half8*)&Ah[m*32 + slot*8];
            afl[i] = *(const half8*)&Al[m*32 + slot*8];
        }
        #pragma unroll
        for (int j = 0; j < JCNT; j++) {
            int n = wn*NSPAN + j*16 + l15;
            bfh[j] = *(const half8*)&Bh[n*32 + slot*8];
            bfl[j] = *(const half8*)&Bl[n*32 + slot*8];
        }
        #pragma unroll
        for (int i = 0; i < 4; i++)
            #pragma unroll
            for (int j = 0; j < JCNT; j++) {
                acc[i][j] = __builtin_amdgcn_mfma_f32_16x16x32_f16(afh[i], bfh[j], acc[i][j], 0,0,0);
                acc[i][j] = __builtin_amdgcn_mfma_f32_16x16x32_f16(afh[i], bfl[j], acc[i][j], 0,0,0);
                acc[i][j] = __builtin_amdgcn_mfma_f32_16x16x32_f16(afl[i], bfh[j], acc[i][j], 0,0,0);
            }
        __syncthreads();
    }
    // ---- epilogue: C/D layout col=lane&15, row=quad*4+reg ----
    #pragma unroll
    for (int i = 0; i < 4; i++)
        #pragma unroll
        for (int j = 0; j < JCNT; j++)
            #pragma unroll
            for (int r = 0; r < 4; r++) {
                int gm = m0 + wm*64 + i*16 + quad*4 + r;
                int gn = n0 + wn*NSPAN + j*16 + l15;
                float v = acc[i][j][r];
                if (bias) v += bias[gn];
                size_t ox = (size_t)gm*ldc + gn;
                if (flags & GF_ADDRES) {
                    size_t rx = (size_t)gm*ldr + gn;
                    v += (float)Rh[rx] + (float)Rl[rx];
                }
                if (flags & GF_ACCH)
                    v += (float)oh[ox] + (float)ol[ox];
                if (flags & GF_RELU_OUT) v = fmaxf(v, 0.f);
                if (flags & GF_GELU_OUT) v = 0.5f*v*(1.0f + erff(v*0.70710678118654752f));
                if (oh) {
                    _Float16 hv = (_Float16)v;
                    oh[ox] = hv;
                    ol[ox] = (_Float16)(v - (float)hv);
                } else {
                    C[ox] = v;
                }
            }
}

// ===================== fp32 GEMM (small head GEMM, N=122) =====================
#define BM 64
#define BNW 64
#define BK 16
__global__ __launch_bounds__(256) void gemm_kernel(
    const float* __restrict__ A, int lda,
    const float* __restrict__ W, int ldb,
    float* __restrict__ C, int ldc,
    const float* __restrict__ bias,
    int M, int N, int K)
{
    __shared__ __align__(16) float As[BK][BM+4];
    __shared__ __align__(16) float Bs[BK][BNW+4];
    int tid = threadIdx.x;
    int tx = tid & 15, ty = tid >> 4;
    int m0 = blockIdx.x * BM;
    int n0 = blockIdx.y * BNW;
    float acc[4][4] = {};
    for (int k0 = 0; k0 < K; k0 += BK) {
        #pragma unroll
        for (int r = 0; r < 4; r++) {
            int li = tid + 256*r;
            int m  = li >> 4;
            int kk = li & 15;
            int gm = m0 + m, gk = k0 + kk;
            As[kk][m] = (gm < M && gk < K) ? A[(size_t)gm*lda + gk] : 0.f;
        }
        #pragma unroll
        for (int r = 0; r < 4; r++) {
            int li = tid + 256*r;
            int kk = li >> 6;
            int n  = li & 63;
            int gk = k0 + kk, gn = n0 + n;
            Bs[kk][n] = (gk < K && gn < N) ? W[(size_t)gk*ldb + gn] : 0.f;
        }
        __syncthreads();
        #pragma unroll
        for (int kk = 0; kk < BK; kk++) {
            float4 a  = *(const float4*)&As[kk][ty*4];
            float4 bb = *(const float4*)&Bs[kk][tx*4];
            float av[4] = {a.x, a.y, a.z, a.w};
            float bv[4] = {bb.x, bb.y, bb.z, bb.w};
            #pragma unroll
            for (int i = 0; i < 4; i++)
                #pragma unroll
                for (int j = 0; j < 4; j++)
                    acc[i][j] += av[i] * bv[j];
        }
        __syncthreads();
    }
    #pragma unroll
    for (int i = 0; i < 4; i++) {
        int gm = m0 + ty*4 + i;
        if (gm >= M) continue;
        #pragma unroll
        for (int j = 0; j < 4; j++) {
            int gn = n0 + tx*4 + j;
            if (gn >= N) continue;
            float v = acc[i][j];
            if (bias) v += bias[gn];
            C[(size_t)gm*ldc + gn] = v;
        }
    }
}

// ===================== MFMA attention =====================
__device__ inline int scidx(int row, int col) {
    return row*128 + (((col>>2) ^ (row&7))<<2) + (col&3);
}
__global__ __launch_bounds__(256) void attn2_kernel(
    const _Float16* __restrict__ QhG, const _Float16* __restrict__ QlG,
    const _Float16* __restrict__ KhG, const _Float16* __restrict__ KlG,
    const _Float16* __restrict__ VhG, const _Float16* __restrict__ VlG,
    const int* __restrict__ amask,
    _Float16* __restrict__ Ch, _Float16* __restrict__ Cl)
{
    __shared__ __align__(16) char smem[65536];
    _Float16* Qh_s = (_Float16*)smem;            // [64][72]
    _Float16* Ql_s = Qh_s + 64*72;
    _Float16* Kh_s = Ql_s + 64*72;               // [128][72]
    _Float16* Kl_s = Kh_s + 128*72;
    float*    Sc   = (float*)smem;               // [64][128] swizzled (phase 2)
    _Float16* Vth  = (_Float16*)(smem + 32768);  // [64][128] swizzled
    _Float16* Vtl  = Vth + 64*128;

    int blk = blockIdx.x;
    int qh2 = blk & 1;
    int bh  = blk >> 1;
    int b = bh / NH_, hh = bh % NH_;
    const int tid = threadIdx.x, lane = tid&63, wid = tid>>6;
    const int l15 = lane&15, quad = lane>>4;
    const int qr = wid*16;
    size_t tokb = (size_t)b*S_*H_ + (size_t)hh*DH_;

    float nmask[8];
    #pragma unroll
    for (int j = 0; j < 8; j++)
        nmask[j] = (amask[b*S_ + j*16 + l15] > 0) ? 0.f : -1e9f;

    {
        int row = tid>>2, part = (tid&3)*16;
        size_t qg = tokb + (size_t)(qh2*64 + row)*H_ + part;
        *(uint4*)&Qh_s[row*72 + part] = *(const uint4*)(QhG + qg);
        *(uint4*)&Ql_s[row*72 + part] = *(const uint4*)(QlG + qg);
        #pragma unroll
        for (int p = 0; p < 2; p++) {
            int krow = row + p*64;
            size_t kg = tokb + (size_t)krow*H_ + part;
            *(uint4*)&Kh_s[krow*72 + part] = *(const uint4*)(KhG + kg);
            *(uint4*)&Kl_s[krow*72 + part] = *(const uint4*)(KlG + kg);
        }
    }
    __syncthreads();

    f32x4 acc1[8];
    #pragma unroll
    for (int j = 0; j < 8; j++) acc1[j] = (f32x4){0.f,0.f,0.f,0.f};
    half8 aqh[2], aql[2];
    #pragma unroll
    for (int kc = 0; kc < 2; kc++) {
        aqh[kc] = *(const half8*)&Qh_s[(qr + l15)*72 + kc*32 + quad*8];
        aql[kc] = *(const half8*)&Ql_s[(qr + l15)*72 + kc*32 + quad*8];
    }
    #pragma unroll
    for (int j = 0; j < 8; j++) {
        #pragma unroll
        for (int kc = 0; kc < 2; kc++) {
            half8 bkh = *(const half8*)&Kh_s[(j*16 + l15)*72 + kc*32 + quad*8];
            half8 bkl = *(const half8*)&Kl_s[(j*16 + l15)*72 + kc*32 + quad*8];
            acc1[j] = __builtin_amdgcn_mfma_f32_16x16x32_f16(aqh[kc], bkh, acc1[j], 0,0,0);
            acc1[j] = __builtin_amdgcn_mfma_f32_16x16x32_f16(aqh[kc], bkl, acc1[j], 0,0,0);
            acc1[j] = __builtin_amdgcn_mfma_f32_16x16x32_f16(aql[kc], bkh, acc1[j], 0,0,0);
        }
    }
    __syncthreads();

    #pragma unroll
    for (int j = 0; j < 8; j++)
        #pragma unroll
        for (int r = 0; r < 4; r++) {
            int row = qr + quad*4 + r;
            int col = j*16 + l15;
            Sc[scidx(row, col)] = acc1[j][r]*INV_SQRT_DH + nmask[j];
        }
    {
        int key = tid>>1, dh = (tid&1)*32;
        union V32 { _Float16 h[32]; uint4 u[4]; } bufh, bufl;
        #pragma unroll
        for (int e = 0; e < 4; e++) {
            bufh.u[e] = *(const uint4*)(VhG + tokb + (size_t)key*H_ + dh + e*8);
            bufl.u[e] = *(const uint4*)(VlG + tokb + (size_t)key*H_ + dh + e*8);
        }
        int kg = key>>3, kr = key&7;
        #pragma unroll
        for (int e = 0; e < 32; e++) {
            int d = dh + e;
            int pos = kg ^ (d & 7);
            Vth[d*128 + pos*8 + kr] = bufh.h[e];
            Vtl[d*128 + pos*8 + kr] = bufl.h[e];
        }
    }
    __syncthreads();

    {
        int row = tid>>2, part = (tid&3)*32;
        float mx = -INFINITY;
        #pragma unroll 8
        for (int e = 0; e < 32; e++)
            mx = fmaxf(mx, Sc[scidx(row, part+e)]);
        mx = fmaxf(mx, __shfl_xor(mx, 1));
        mx = fmaxf(mx, __shfl_xor(mx, 2));
        float s = 0.f;
        #pragma unroll 8
        for (int e = 0; e < 32; e++) {
            int idx = scidx(row, part+e);
            float ev = expf(Sc[idx] - mx);
            Sc[idx] = ev; s += ev;
        }
        s += __shfl_xor(s, 1);
        s += __shfl_xor(s, 2);
        float inv = 1.0f / s;
        #pragma unroll 8
        for (int e = 0; e < 32; e++)
            Sc[scidx(row, part+e)] *= inv;
    }
    __syncthreads();

    f32x4 acc2[4];
    #pragma unroll
    for (int jd = 0; jd < 4; jd++) acc2[jd] = (f32x4){0.f,0.f,0.f,0.f};
    #pragma unroll
    for (int kc = 0; kc < 4; kc++) {
        int q = qr + l15;
        int g16 = kc*8 + quad*2;
        float4 p0 = *(const float4*)&Sc[q*128 + ((g16   ^ (q&7))<<2)];
        float4 p1 = *(const float4*)&Sc[q*128 + (((g16+1) ^ (q&7))<<2)];
        float pv[8] = {p0.x,p0.y,p0.z,p0.w, p1.x,p1.y,p1.z,p1.w};
        union U { _Float16 h[8]; half8 v; } ph, pl;
        #pragma unroll
        for (int e = 0; e < 8; e++) {
            _Float16 hv = (_Float16)pv[e];
            ph.h[e] = hv; pl.h[e] = (_Float16)(pv[e] - (float)hv);
        }
        #pragma unroll
        for (int jd = 0; jd < 4; jd++) {
            int n = jd*16 + l15;
            int pos = (kc*4 + quad) ^ (n & 7);
            half8 vh = *(const half8*)&Vth[n*128 + pos*8];
            half8 vl = *(const half8*)&Vtl[n*128 + pos*8];
            acc2[jd] = __builtin_amdgcn_mfma_f32_16x16x32_f16(ph.v, vh, acc2[jd], 0,0,0);
            acc2[jd] = __builtin_amdgcn_mfma_f32_16x16x32_f16(ph.v, vl, acc2[jd], 0,0,0);
            acc2[jd] = __builtin_amdgcn_mfma_f32_16x16x32_f16(pl.v, vh, acc2[jd], 0,0,0);
        }
    }
    #pragma unroll
    for (int jd = 0; jd < 4; jd++)
        #pragma unroll
        for (int r = 0; r < 4; r++) {
            int row = qr + quad*4 + r;
            int token = b*S_ + qh2*64 + row;
            int d = jd*16 + l15;
            float v = acc2[jd][r];
            _Float16 hv = (_Float16)v;
            Ch[(size_t)token*H_ + hh*DH_ + d] = hv;
            Cl[(size_t)token*H_ + hh*DH_ + d] = (_Float16)(v - (float)hv);
        }
}

// ===================== intent head =====================
__global__ __launch_bounds__(64) void intent_kernel(
    const _Float16* __restrict__ Xh, const _Float16* __restrict__ Xl,
    const float* __restrict__ iW1,
    const float* __restrict__ ib1, const float* __restrict__ iW2,
    const float* __restrict__ ib2, const int* __restrict__ tgt,
    float* __restrict__ iloss, float* __restrict__ outf)
{
    int b = blockIdx.x; int j = threadIdx.x;
    __shared__ float h1[64];
    __shared__ float lg[32];
    const _Float16* x0h = Xh + (size_t)b*S_*H_;
    const _Float16* x0l = Xl + (size_t)b*S_*H_;
    float acc = ib1[j];
    for (int h = 0; h < H_; h++) {
        float x = (float)x0h[h] + (float)x0l[h];
        acc += fmaxf(x, 0.f) * iW1[(size_t)h*64 + j];
    }
    h1[j] = fmaxf(acc, 0.f);
    __syncthreads();
    if (j < INTENT_) {
        float l = ib2[j];
        for (int k = 0; k < 64; k++) l += h1[k]*iW2[k*INTENT_ + j];
        lg[j] = l;
    }
    __syncthreads();
    if (j == 0) {
        float mx = -INFINITY; int bi = 0;
        for (int c = 0; c < INTENT_; c++) if (lg[c] > mx) { mx = lg[c]; bi = c; }
        float sm = 0.f;
        for (int c = 0; c < INTENT_; c++) sm += expf(lg[c]-mx);
        float lse = mx + logf(sm);
        iloss[b] = lse - lg[tgt[b]];
        outf[1 + (size_t)NT_ + b] = (float)bi;
    }
}

// ===================== fused CRF-llh + Viterbi (512 thr, float4 dot) =======
// grid (64, 2): y=0 -> CRF llh ; y=1 -> Viterbi.
// 512 threads: j = tid>>2 (tag), p = tid&3 covers CONTIGUOUS i-range
// [32p, 32p+32). tT[j][i] stride VST=124 (cols 122,123 zero-padded).
// Each thread does 8 unrolled ds_read_b128 per step. alpha in registers +
// parity double-buffer exchange -> ONE barrier/step. Deferred-subtractor
// logsumexp (exact math, any X).
#define VST 124
__global__ __launch_bounds__(512) void crf_vit_kernel(
    const float* __restrict__ E_, const int* __restrict__ tags,
    const int* __restrict__ mask, const float* __restrict__ start,
    const float* __restrict__ endv, const float* __restrict__ trans,
    float* __restrict__ crfv, unsigned char* __restrict__ BPg,
    float* __restrict__ outf)
{
    __shared__ __align__(16) float tT[TAGS_*VST];   // 60,512 B [j][i]
    __shared__ __align__(16) float eal[2][128];     // parity exchange buffer
    __shared__ float mxw[2][8];                     // per-wave max, by parity
    __shared__ float mxbuf[16];
    __shared__ int lastt;
    int b = blockIdx.x;
    int mode = blockIdx.y;
    int tid = threadIdx.x, lane = tid&63, wid = tid>>6;
    int j = tid>>2, p = tid&3;
    bool vj = (j < TAGS_);
    const float* E = E_ + (size_t)b*S_*TAGS_;

    // load tT[j][i]: exp-domain for llh, raw for viterbi; pad cols = 0
    for (int o = tid; o < TAGS_*VST; o += 512) {
        int jj = o / VST, i = o - jj*VST;
        float v;
        if (i < TAGS_) {
            float tv = trans[i*TAGS_ + jj];
            v = mode ? tv : expf(tv);
        } else v = 0.f;
        tT[o] = v;
    }
    float aj = vj ? (start[j] + E[j]) : -3e38f;
    const int ibase = 32*p;

    if (mode == 0) {
        // ---------- CRF log-likelihood ----------
        {
            float wm = wave_max(aj);
            if (lane == 0) mxw[0][wid] = wm;
        }
        __syncthreads();                    // also covers tT load
        float gm = mxw[0][0];
        #pragma unroll
        for (int w = 1; w < 8; w++) gm = fmaxf(gm, mxw[0][w]);
        float xc = gm;                      // subtractor of eal[cur]
        if (p == 0) eal[0][j] = vj ? expf(aj - xc) : 0.f;
        __syncthreads();
        int cur = 0;
        float eC = vj ? E[(size_t)TAGS_ + j] : 0.f;   // E[1][j]
        int   mC = mask[b*S_ + 1];
        for (int t = 1; t < S_; t++) {
            float e = eC; int m_t = mC;
            if (t + 1 < S_) {               // prefetch next step
                eC = vj ? E[(size_t)(t+1)*TAGS_ + j] : 0.f;
                mC = mask[b*S_ + t + 1];
            }
            float s = 0.f;
            if (vj) {
                const float4* tr = (const float4*)&tT[j*VST + ibase];
                const float4* eb = (const float4*)&eal[cur][ibase];
                float s0 = 0.f, s1 = 0.f, s2 = 0.f, s3 = 0.f;
                #pragma unroll
                for (int q = 0; q < 8; q++) {
                    float4 av = eb[q];
                    float4 tv = tr[q];
                    s0 += av.x*tv.x; s1 += av.y*tv.y;
                    s2 += av.z*tv.z; s3 += av.w*tv.w;
                }
                s = (s0 + s1) + (s2 + s3);
            }
            s += __shfl_xor(s, 1);
            s += __shfl_xor(s, 2);
            if (m_t && vj) aj = xc + logf(s) + e;
            int nxt = cur ^ 1;
            float xn = gm;                  // deferred subtractor (exact math)
            if (p == 0) eal[nxt][j] = vj ? expf(aj - xn) : 0.f;
            float wm2 = wave_max(aj);
            if (lane == 0) mxw[nxt][wid] = wm2;
            __syncthreads();                // ONE barrier per step
            float nm = mxw[nxt][0];
            #pragma unroll
            for (int w = 1; w < 8; w++) nm = fmaxf(nm, mxw[nxt][w]);
            gm = nm;
            xc = xn;
            cur = nxt;
        }
        // dump alpha to LDS for the final reduction (reuse eal[0])
        if (p == 0) eal[0][j] = aj;
        // numerator over timesteps (threads 0..127 handle t)
        float term = 0.f, mkf = 0.f;
        if (tid < S_) {
            int mk = mask[b*S_ + tid]; mkf = (float)mk;
            if (tid >= 1 && mk) {
                int tg = tags[b*S_ + tid], tgp = tags[b*S_ + tid - 1];
                term = trans[tgp*TAGS_ + tg] + E[(size_t)tid*TAGS_ + tg];
            }
        }
        if (wid < 2) {
            float ts = wave_sum(term);
            float ms = wave_sum(mkf);
            if (lane == 0) { mxbuf[2+wid] = ts; mxbuf[4+wid] = ms; }
        }
        __syncthreads();
        if (wid == 0) {
            const float* alp = &eal[0][0];
            float v1 = (lane < TAGS_) ? alp[lane] + endv[lane] : -3e38f;
            float v2 = (lane+64 < TAGS_) ? alp[lane+64] + endv[lane+64] : -3e38f;
            float m = wave_max(fmaxf(v1, v2));
            float sd = ((lane < TAGS_) ? expf(v1 - m) : 0.f)
                     + ((lane+64 < TAGS_) ? expf(v2 - m) : 0.f);
            sd = wave_sum(sd);
            if (lane == 0) {
                float denom = m + logf(sd);
                float numsum = mxbuf[2] + mxbuf[3];
                int msum = (int)(mxbuf[4] + mxbuf[5]);
                int tag0 = tags[b*S_];
                int last_tag = tags[b*S_ + (msum - 1)];
                float num = start[tag0] + E[tag0] + numsum + endv[last_tag];
                crfv[b] = num - denom;
            }
        }
    } else {
        // ---------- Viterbi ----------
        if (p == 0) eal[0][j] = aj;         // -3e38 for invalid j
        __syncthreads();                    // covers tT load + alpha0
        int cur = 0;
        size_t bpb = (size_t)b*(S_-1)*TAGS_;
        float eC = vj ? E[(size_t)TAGS_ + j] : 0.f;
        int   mC = mask[b*S_ + 1];
        for (int t = 1; t < S_; t++) {
            float ee = eC; int m_t = mC;
            if (t + 1 < S_) {
                eC = vj ? E[(size_t)(t+1)*TAGS_ + j] : 0.f;
                mC = mask[b*S_ + t + 1];
            }
            float best = -3e38f; int bi = 0;
            if (vj) {
                const float4* tr = (const float4*)&tT[j*VST + ibase];
                const float4* ab = (const float4*)&eal[cur][ibase];
                float b0 = -3e38f, b1 = -3e38f, b2 = -3e38f, b3 = -3e38f;
                int i0 = ibase, i1 = ibase+1, i2 = ibase+2, i3 = ibase+3;
                #pragma unroll
                for (int q = 0; q < 8; q++) {
                    float4 av = ab[q];
                    float4 tv = tr[q];
                    float c;
                    c = av.x + tv.x; if (c > b0) { b0 = c; i0 = ibase+4*q; }
                    c = av.y + tv.y; if (c > b1) { b1 = c; i1 = ibase+4*q+1; }
                    c = av.z + tv.z; if (c > b2) { b2 = c; i2 = ibase+4*q+2; }
                    c = av.w + tv.w; if (c > b3) { b3 = c; i3 = ibase+4*q+3; }
                }
                best = b0; bi = i0;
                if (b1 > best || (b1 == best && i1 < bi)) { best = b1; bi = i1; }
                if (b2 > best || (b2 == best && i2 < bi)) { best = b2; bi = i2; }
                if (b3 > best || (b3 == best && i3 < bi)) { best = b3; bi = i3; }
            }
            {
                float ov = __shfl_xor(best, 1); int oi = __shfl_xor(bi, 1);
                if (ov > best || (ov == best && oi < bi)) { best = ov; bi = oi; }
                ov = __shfl_xor(best, 2); oi = __shfl_xor(bi, 2);
                if (ov > best || (ov == best && oi < bi)) { best = ov; bi = oi; }
            }
            float nv; int nb;
            if (m_t) { nv = best + ee; nb = bi; }
            else     { nv = aj; nb = j; }
            int nxt = cur ^ 1;
            if (vj) aj = nv;
            if (p == 0) eal[nxt][j] = aj;   // -3e38 for invalid j
            if (vj && p == 0)
                BPg[bpb + (size_t)(t-1)*TAGS_ + j] = (unsigned char)nb;
            __syncthreads();                // ONE barrier per step
            cur = nxt;
        }
        // dump alpha for final argmax
        if (p == 0) eal[0][j] = aj;
        __syncthreads();
        if (wid == 0) {
            const float* alp = &eal[0][0];
            float v; int idx;
            float v1 = (lane < TAGS_) ? alp[lane] + endv[lane] : -3e38f;
            float v2 = (lane+64 < TAGS_) ? alp[lane+64] + endv[lane+64] : -3e38f;
            if (v2 > v1) { v = v2; idx = lane+64; } else { v = v1; idx = lane; }
            #pragma unroll
            for (int d = 32; d; d >>= 1) {
                float ov = __shfl_xor(v, d); int oi = __shfl_xor(idx, d);
                if (ov > v || (ov == v && oi < idx)) { v = ov; idx = oi; }
            }
            if (lane == 0) lastt = idx;
        }
        __syncthreads();
        unsigned char* bpl = (unsigned char*)tT;
        for (int o = tid; o < (S_-1)*TAGS_; o += 512)
            bpl[o] = BPg[bpb + o];
        __syncthreads();
        if (tid == 0) {
            int tag = lastt;
            outf[1 + (size_t)b*S_ + (S_-1)] = (float)tag;
            for (int t = S_-1; t >= 1; t--) {
                tag = bpl[(t-1)*TAGS_ + tag];
                outf[1 + (size_t)b*S_ + (t-1)] = (float)tag;
            }
        }
    }
}

// ===================== final joint loss =====================
__global__ void combine_kernel(const float* __restrict__ iloss,
                               const float* __restrict__ crfv,
                               const float* __restrict__ lv,
                               float* __restrict__ outf)
{
    if (threadIdx.x == 0 && blockIdx.x == 0) {
        float si = 0.f, sc = 0.f;
        for (int b = 0; b < B_; b++) { si += iloss[b]; sc += crfv[b]; }
        float p1 = expf(-lv[0]), p2 = expf(-lv[1]);
        float slots_loss = -sc;
        outf[0] = p1*si + (float)B_*lv[0] + p2*slots_loss + lv[1];
    }
}

// ===================== host launch =====================
extern "C" void kernel_launch(void* const* d_in, const int* in_sizes, int n_in,
                              void* d_out, int out_size, void* d_ws, size_t ws_size,
                              hipStream_t stream) {
    const int*   ids   = (const int*)  d_in[0];
    const int*   amask = (const int*)  d_in[1];
    const int*   itgt  = (const int*)  d_in[2];
    const int*   stgt  = (const int*)  d_in[3];
    const int*   smask = (const int*)  d_in[4];
    const float* we    = (const float*)d_in[5];
    const float* pe    = (const float*)d_in[6];
    const float* embs  = (const float*)d_in[7];
    const float* embb  = (const float*)d_in[8];
    const float* Wq    = (const float*)d_in[9];
    const float* bq    = (const float*)d_in[10];
    const float* Wk    = (const float*)d_in[11];
    const float* bk    = (const float*)d_in[12];
    const float* Wv    = (const float*)d_in[13];
    const float* bv    = (const float*)d_in[14];
    const float* Wo    = (const float*)d_in[15];
    const float* bo    = (const float*)d_in[16];
    const float* sas   = (const float*)d_in[17];
    const float* sab   = (const float*)d_in[18];
    const float* W1f   = (const float*)d_in[19];
    const float* b1f   = (const float*)d_in[20];
    const float* W2f   = (const float*)d_in[21];
    const float* b2f   = (const float*)d_in[22];
    const float* ols   = (const float*)d_in[23];
    const float* olb   = (const float*)d_in[24];
    const float* iW1   = (const float*)d_in[25];
    const float* ib1   = (const float*)d_in[26];
    const float* iW2   = (const float*)d_in[27];
    const float* ib2   = (const float*)d_in[28];
    const float* sW1   = (const float*)d_in[29];
    const float* sb1   = (const float*)d_in[30];
    const float* sW2   = (const float*)d_in[31];
    const float* sb2   = (const float*)d_in[32];
    const float* crfs  = (const float*)d_in[33];
    const float* crfe  = (const float*)d_in[34];
    const float* crft  = (const float*)d_in[35];
    const float* lv    = (const float*)d_in[36];

    float* outf = (float*)d_out;
    float* wsf  = (float*)d_ws;
    const long NTHh = (long)NT_ * H_;        // 6,291,456 (halves per tensor)
    const long NBf  = NTHh;                  // floats per fp32-equivalent tensor
    const long HH   = (long)H_ * H_;         // 589,824

    // layout (floats): [XhXl: NBf][P: 3*NBf][ChCl: NBf][WA][WB1][WB2][misc]
    _Float16* Xh = (_Float16*)wsf;
    _Float16* Xl = Xh + NTHh;
    float*    Pf = wsf + NBf;
    _Float16* Ph = (_Float16*)Pf;
    _Float16 *Qh = Ph, *Ql = Ph + NTHh, *Kh = Ph + 2*NTHh, *Kl = Ph + 3*NTHh,
             *Vh = Ph + 4*NTHh, *Vl = Ph + 5*NTHh;
    _Float16 *Sh = Ph, *Sl = Ph + NTHh;                 // sum halves (reuse Q slot)
    _Float16* Fh = (_Float16*)(wsf + 2*NBf);            // FF intermediate hi
    _Float16* Fl = (_Float16*)(wsf + 3*NBf);            // FF intermediate lo
    _Float16* Ch = (_Float16*)(wsf + 4*NBf);
    _Float16* Cl = Ch + NTHh;
    const long wa0 = 5*NBf;
    _Float16* WAh = (_Float16*)(wsf + wa0);             // 8*HH halves (QKVO hi+lo)
    _Float16* WAl = WAh + 4*HH;
    const long wb1 = wa0 + 2359296;
    _Float16* WB1h = (_Float16*)(wsf + wb1);
    _Float16* WB1l = WB1h + 2359296;
    const long wb2 = wb1 + 2359296;
    _Float16* WB2h = (_Float16*)(wsf + wb2);
    _Float16* WB2l = WB2h + 2359296;
    float* iloss = wsf + wb2 + 2359296;
    float* crfv  = iloss + 64;
    // heads scratch in P region (free after encoder)
    float* H1 = Pf;                                     // 8192*256
    float* logits = Pf + 2097152;                       // 8192*122
    unsigned char* BPg = (unsigned char*)(Pf + 2097152 + 999424);

    auto g3 = [&](int BNsel, int gy, int gz,
                  const _Float16* A_h, const _Float16* A_l, int lda,
                  const _Float16* WtH, const _Float16* WtL, int ldw, long wz,
                  float* C, _Float16* OH, _Float16* OL, int ldc, long oz,
                  const _Float16* Rh, const _Float16* Rl,
                  const float* b0, const float* b1_, const float* b2_,
                  int K, int flags) {
        if (BNsel == 128)
            hipLaunchKernelGGL((gemm3_kernel<128>), dim3(NT_/128, gy, gz), dim3(256), 0, stream,
                               A_h, A_l, lda, WtH, WtL, ldw, wz,
                               C, OH, OL, ldc, oz, Rh, Rl, H_, b0, b1_, b2_, K, flags);
        else
            hipLaunchKernelGGL((gemm3_kernel<64>), dim3(NT_/128, gy, gz), dim3(256), 0, stream,
                               A_h, A_l, lda, WtH, WtL, ldw, wz,
                               C, OH, OL, ldc, oz, Rh, Rl, H_, b0, b1_, b2_, K, flags);
    };

    hipLaunchKernelGGL(embed_ln_kernel, dim3(NT_), dim3(256), 0, stream,
                       ids, we, pe, embs, embb, Xh, Xl);

    for (int i = 0; i < L_; i++) {
        const long WO = (long)i*HH;
        // QKV+O weights -> WA (z=4)
        hipLaunchKernelGGL(wconv_kernel, dim3(12,12,4), dim3(256), 0, stream,
                           Wq+WO, Wk+WO, Wv+WO, Wo+WO, H_, H_, WAh, WAl, HH);
        // QKV (z=3), N=768 each: BN=128, grid 64x6x3 = 1152 blocks (4.5/CU)
        g3(128, 6, 3, Xh, Xl, H_, WAh, WAl, H_, HH,
           nullptr, Ph, Ph+NTHh, H_, 2*NTHh, nullptr, nullptr,
           bq+i*H_, bk+i*H_, bv+i*H_, H_, 0);
        // attention
        hipLaunchKernelGGL(attn2_kernel, dim3(B_*NH_*2), dim3(256), 0, stream,
                           Qh, Ql, Kh, Kl, Vh, Vl, amask, Ch, Cl);
        // O-proj + residual -> sum halves (Sh/Sl): BN=64 -> 768 blocks (3/CU)
        g3(64, 12, 1, Ch, Cl, H_, WAh+3*HH, WAl+3*HH, H_, 0,
           nullptr, Sh, Sl, H_, 0, Xh, Xl,
           bo+i*H_, nullptr, nullptr, H_, GF_ADDRES);
        hipLaunchKernelGGL(ln2_kernel, dim3(NT_), dim3(384), 0, stream,
                           Sh, Sl, sas+i*H_, sab+i*H_, Xh, Xl,
                           (_Float16*)nullptr, (_Float16*)nullptr);
        // FF weights
        hipLaunchKernelGGL(wconv_kernel, dim3(12,48,1), dim3(256), 0, stream,
                           W1f+(long)i*H_*FF_, nullptr, nullptr, nullptr,
                           H_, FF_, WB1h, WB1l, 0);
        hipLaunchKernelGGL(wconv_kernel, dim3(48,12,1), dim3(256), 0, stream,
                           W2f+(long)i*FF_*H_, nullptr, nullptr, nullptr,
                           FF_, H_, WB2h, WB2l, 0);
        for (int c = 0; c < 2; c++) {
            const int CW = FF_/2;  // 1536
            // FF1 chunk: N=1536 -> BN=64, 24 N-tiles (1536 blocks, 6/CU)
            g3(64, 24, 1, Xh, Xl, H_,
               WB1h+(long)c*CW*H_, WB1l+(long)c*CW*H_, H_, 0,
               nullptr, Fh, Fl, CW, 0, nullptr, nullptr,
               b1f+(long)i*FF_+c*CW, nullptr, nullptr, H_, GF_GELU_OUT);
            // FF2 chunk: N=768 -> BN=64, 12 N-tiles (768 blocks, 3/CU)
            g3(64, 12, 1, Fh, Fl, CW,
               WB2h+(long)c*CW, WB2l+(long)c*CW, FF_, 0,
               nullptr, Sh, Sl, H_, 0, Xh, Xl,
               (c==0) ? (b2f+i*H_) : nullptr, nullptr, nullptr,
               CW, (c==0) ? GF_ADDRES : GF_ACCH);
        }
        hipLaunchKernelGGL(ln2_kernel, dim3(NT_), dim3(384), 0, stream,
                           Sh, Sl, ols+i*H_, olb+i*H_, Xh, Xl,
                           (i==L_-1) ? Ch : (_Float16*)nullptr,
                           (i==L_-1) ? Cl : (_Float16*)nullptr);
    }

    hipLaunchKernelGGL(intent_kernel, dim3(B_), dim3(64), 0, stream,
                       Xh, Xl, iW1, ib1, iW2, ib2, itgt, iloss, outf);

    // slots head: H1 = relu(relu(x)@sW1 + sb1)  (relu(x) halves are in Ch/Cl)
    hipLaunchKernelGGL(wconv_kernel, dim3(12,4,1), dim3(256), 0, stream,
                       sW1, nullptr, nullptr, nullptr, H_, 256,
                       WAh, WAh + (long)256*H_, 0);
    // N=256 -> BN=64, 4 N-tiles (256 blocks, 1/CU; was 0.5/CU)
    g3(64, 4, 1, Ch, Cl, H_, WAh, WAh + (long)256*H_, H_, 0,
       H1, nullptr, nullptr, 256, 0, nullptr, nullptr,
       sb1, nullptr, nullptr, H_, GF_RELU_OUT);
    hipLaunchKernelGGL(gemm_kernel, dim3(NT_/BM, 2), dim3(256), 0, stream,
                       H1, 256, sW2, TAGS_, logits, TAGS_, sb2, NT_, TAGS_, 256);

    hipLaunchKernelGGL(crf_vit_kernel, dim3(B_, 2), dim3(512), 0, stream,
                       logits, stgt, smask, crfs, crfe, crft, crfv, BPg, outf);

    hipLaunchKernelGGL(combine_kernel, dim3(1), dim3(64), 0, stream,
                       iloss, crfv, lv, outf);
}